// Round 7
// baseline (746.526 us; speedup 1.0000x reference)
//
#include <hip/hip_runtime.h>
#include <hip/hip_fp16.h>
#include <math.h>

// ---------------------------------------------------------------------------
// SovereignLeviathanV2  round 7 = round 6 with:
//  - k_phi: spill-free 128x128 / 8x8 micro, n-major [k][132] LDS for BOTH
//    operands (conflict-free staging), split-half frag reads {t*4, 64+t*4}
//    (2-way = free). launch_bounds(256,2). Fixes r6's 1.1GB scratch spills
//    and 2.4e7 bank conflicts.
//  - k_ffn: 1-D grid, expert = bid&7 -> expert's tiles pinned to one XCD so
//    its 4MB packed weights stay L2-resident (was: every XCD read all 32MB).
// Everything else byte-identical to the passing round-6 kernel.
// ---------------------------------------------------------------------------

#define PI_F 3.14159265358979323846f
#define HARM_F 1.04719755119659774615f
#define INV_HARM_F 0.95492965855137201461f
#define TOL_F 0.15f

typedef float f32x16 __attribute__((ext_vector_type(16)));
typedef __bf16 bf16x8 __attribute__((ext_vector_type(8)));
typedef unsigned int u32x4 __attribute__((ext_vector_type(4)));
typedef unsigned int u32x2 __attribute__((ext_vector_type(2)));

__device__ __forceinline__ float gelu_tanh(float x) {
  float x3 = x * x * x;
  return 0.5f * x * (1.f + tanhf(0.79788456080286535588f * (x + 0.044715f * x3)));
}
__device__ __forceinline__ unsigned short f2bf(float x) {
  unsigned u = __float_as_uint(x);
  unsigned r = (u + 0x7FFFu + ((u >> 16) & 1u)) >> 16;
  return (unsigned short)r;
}
__device__ __forceinline__ float bflo(unsigned u) { return __uint_as_float(u << 16); }
__device__ __forceinline__ float bfhi(unsigned u) { return __uint_as_float(u & 0xFFFF0000u); }
__device__ __forceinline__ bf16x8 ld_frag(const void* p) {
  u32x4 v = *(const u32x4*)p;
  return __builtin_bit_cast(bf16x8, v);
}

// K1: X[n][c] = emb[seq[n]][c]
__global__ void k_embed(const int* __restrict__ seq, const float* __restrict__ emb,
                        float* __restrict__ X) {
  int i = blockIdx.x * 256 + threadIdx.x;
  int n = i >> 7, c4 = i & 127;
  int tok = seq[n];
  ((float4*)X)[(size_t)n * 128 + c4] = ((const float4*)emb)[(size_t)tok * 128 + c4];
}

// ---------------------------------------------------------------------------
// Generic B-operand frag pack (unchanged)
// ---------------------------------------------------------------------------
__global__ __launch_bounds__(256) void k_pack_b(const float* __restrict__ src, int ld,
                                                size_t srcE, unsigned short* __restrict__ dst,
                                                size_t dstE, int fragKtot) {
  __shared__ float Ls[512 * 33];
  int nb = blockIdx.x, kseg = blockIdx.y, e = blockIdx.z;
  const float* s = src + (size_t)e * srcE + (size_t)kseg * 512 * ld + nb * 32;
  unsigned short* d = dst + (size_t)e * dstE + ((size_t)(nb * fragKtot + kseg * 32)) * 512;
  int tid = threadIdx.x;
#pragma unroll
  for (int q = 0; q < 16; ++q) {
    int i = tid + q * 256;
    int row = i >> 3, c4 = i & 7;
    float4 v = *(const float4*)(s + (size_t)row * ld + c4 * 4);
    Ls[row * 33 + c4 * 4 + 0] = v.x;
    Ls[row * 33 + c4 * 4 + 1] = v.y;
    Ls[row * 33 + c4 * 4 + 2] = v.z;
    Ls[row * 33 + c4 * 4 + 3] = v.w;
  }
  __syncthreads();
#pragma unroll
  for (int q = 0; q < 8; ++q) {
    int i = tid + q * 256;
    int ks = i >> 6, l = i & 63;
    int col = l & 31, kb = (l >> 5) * 8 + ks * 16;
    u32x4 o;
    o.x = (unsigned)f2bf(Ls[(kb + 0) * 33 + col]) | ((unsigned)f2bf(Ls[(kb + 1) * 33 + col]) << 16);
    o.y = (unsigned)f2bf(Ls[(kb + 2) * 33 + col]) | ((unsigned)f2bf(Ls[(kb + 3) * 33 + col]) << 16);
    o.z = (unsigned)f2bf(Ls[(kb + 4) * 33 + col]) | ((unsigned)f2bf(Ls[(kb + 5) * 33 + col]) << 16);
    o.w = (unsigned)f2bf(Ls[(kb + 6) * 33 + col]) | ((unsigned)f2bf(Ls[(kb + 7) * 33 + col]) << 16);
    *(u32x4*)(d + (size_t)ks * 512 + l * 8) = o;
  }
}

// ---------------------------------------------------------------------------
// K2: fused phi+amp fp32 GEMM. M=8192, K=512, N=1024 (by<4: phi, else amp).
// 128x128 tile, BK=16, 8x8 micro with split halves:
//   rows m = bm + rh*64 + ty*4 + rr, cols = cb + ch*64 + tx*4 + cc.
// LDS n-major [k][128+4] both operands; frag reads at {t*4, 64+t*4}:
//   banks (t*4)%32 -> 2-way aliasing only (free). Staging conflict-free.
// ---------------------------------------------------------------------------
__global__ __launch_bounds__(256, 2) void k_phi(const float* __restrict__ A,
                                                const float* __restrict__ phiW,
                                                const float* __restrict__ phiB,
                                                const float* __restrict__ ampW,
                                                const float* __restrict__ ampB,
                                                float* __restrict__ cosO,
                                                float* __restrict__ sinO,
                                                float* __restrict__ sigO) {
  __shared__ float As[2][16 * 132];
  __shared__ float Bs[2][16 * 132];
  int tid = threadIdx.x;
  int tx = tid & 15, ty = tid >> 4;
  int bm = blockIdx.x * 128;
  int by = blockIdx.y;
  const float* Bsrc = (by < 4) ? phiW : ampW;
  const float* bias = (by < 4) ? phiB : ampB;
  int cb = (by & 3) * 128;
  float acc[8][8];
#pragma unroll
  for (int r = 0; r < 8; ++r)
#pragma unroll
    for (int c = 0; c < 8; ++c) acc[r][c] = 0.f;

#define STAGE_PHI(BUF, KT)                                                     \
  {                                                                            \
    _Pragma("unroll") for (int s = 0; s < 2; ++s) {                            \
      int i = tid + s * 256;                                                   \
      int row = i >> 2, kq = i & 3;                                            \
      float4 v = *(const float4*)(A + (size_t)(bm + row) * 512 + (KT)*16 + kq * 4); \
      As[BUF][(kq * 4 + 0) * 132 + row] = v.x;                                 \
      As[BUF][(kq * 4 + 1) * 132 + row] = v.y;                                 \
      As[BUF][(kq * 4 + 2) * 132 + row] = v.z;                                 \
      As[BUF][(kq * 4 + 3) * 132 + row] = v.w;                                 \
    }                                                                          \
    _Pragma("unroll") for (int s = 0; s < 2; ++s) {                            \
      int i = tid + s * 256;                                                   \
      int kk = i >> 5, g = i & 31;                                             \
      float4 v = *(const float4*)(Bsrc + (size_t)((KT)*16 + kk) * 512 + cb + g * 4); \
      *(float4*)(&Bs[BUF][kk * 132 + g * 4]) = v;                              \
    }                                                                          \
  }

  STAGE_PHI(0, 0);
  for (int kt = 0; kt < 32; ++kt) {
    __syncthreads();
    if (kt + 1 < 32) {
      if ((kt & 1) == 0) STAGE_PHI(1, kt + 1) else STAGE_PHI(0, kt + 1)
    }
    const float* Ab = As[kt & 1];
    const float* Bb = Bs[kt & 1];
#pragma unroll
    for (int kk = 0; kk < 16; ++kk) {
      float4 a0 = *(const float4*)(&Ab[kk * 132 + ty * 4]);
      float4 a1 = *(const float4*)(&Ab[kk * 132 + 64 + ty * 4]);
      float4 b0 = *(const float4*)(&Bb[kk * 132 + tx * 4]);
      float4 b1 = *(const float4*)(&Bb[kk * 132 + 64 + tx * 4]);
      float ar[8] = {a0.x, a0.y, a0.z, a0.w, a1.x, a1.y, a1.z, a1.w};
      float br[8] = {b0.x, b0.y, b0.z, b0.w, b1.x, b1.y, b1.z, b1.w};
#pragma unroll
      for (int r = 0; r < 8; ++r)
#pragma unroll
        for (int c = 0; c < 8; ++c) acc[r][c] = fmaf(ar[r], br[c], acc[r][c]);
    }
  }
  // epilogue: rows m = bm + rh*64 + ty*4 + rr; cols cb + ch*64 + tx*4 + cc
#pragma unroll
  for (int rh = 0; rh < 2; ++rh) {
#pragma unroll
    for (int rr = 0; rr < 4; ++rr) {
      int r = rh * 4 + rr;
      int m = bm + rh * 64 + ty * 4 + rr;
      if (by < 4) {
#pragma unroll
        for (int ch = 0; ch < 2; ++ch) {
          float o0[4], o1[4];
#pragma unroll
          for (int cc = 0; cc < 4; ++cc) {
            float z = acc[r][ch * 4 + cc] + bias[cb + ch * 64 + tx * 4 + cc];
            float a = tanhf(z) * PI_F;
            float nr = rintf(a * INV_HARM_F) * HARM_F;
            if (fabsf(a - nr) < TOL_F) a = nr;
            float sn, cs;
            sincosf(a, &sn, &cs);
            o0[cc] = cs;
            o1[cc] = sn;
          }
          float* cp = cosO + (size_t)m * 512 + cb + ch * 64 + tx * 4;
          float* sp = sinO + (size_t)m * 512 + cb + ch * 64 + tx * 4;
          *(float4*)cp = make_float4(o0[0], o0[1], o0[2], o0[3]);
          *(float4*)sp = make_float4(o1[0], o1[1], o1[2], o1[3]);
        }
      } else {
#pragma unroll
        for (int ch = 0; ch < 2; ++ch) {
          float o0[4];
#pragma unroll
          for (int cc = 0; cc < 4; ++cc) {
            float z = acc[r][ch * 4 + cc] + bias[cb + ch * 64 + tx * 4 + cc];
            o0[cc] = 1.f / (1.f + expf(-z));
          }
          float* gp = sigO + (size_t)m * 512 + cb + ch * 64 + tx * 4;
          *(float4*)gp = make_float4(o0[0], o0[1], o0[2], o0[3]);
        }
      }
    }
  }
}

// K3: toroidal scan, 4-buffer rotating prefetch. 32 blocks x 64 threads.
__global__ void k_scan(const float* __restrict__ cosb, const float* __restrict__ sinb,
                       const float* __restrict__ sigb, float* __restrict__ xmoe,
                       float* __restrict__ nstate) {
  int gid = blockIdx.x * 64 + threadIdx.x;  // 0..2047
  size_t b = gid >> 9, c = gid & 511;
  size_t base = (b * 2048) * 512 + c;
  float state = 0.f;
  float C0[8], S0[8], G0[8], C1[8], S1[8], G1[8];
  float C2[8], S2[8], G2[8], C3[8], S3[8], G3[8];
#define LOADB(CB, SB, GB, blk)                                                  \
  {                                                                             \
    int bb = (blk) < 255 ? (blk) : 255;                                         \
    size_t o = base + (size_t)bb * 8 * 512;                                     \
    _Pragma("unroll") for (int j = 0; j < 8; ++j) {                             \
      size_t oo = o + (size_t)j * 512;                                          \
      CB[j] = cosb[oo]; SB[j] = sinb[oo]; GB[j] = sigb[oo];                     \
    }                                                                           \
  }
#define COMPB(CB, SB, GB, blk)                                                  \
  {                                                                             \
    size_t o = base + (size_t)(blk)*8 * 512;                                    \
    _Pragma("unroll") for (int j = 0; j < 8; ++j) {                             \
      float st = fmaf(SB[j], state, -SB[j]);                                    \
      st = fmaf(CB[j], state, st);                                              \
      st = fminf(1.f, fmaxf(-1.f, st));                                         \
      state = st;                                                               \
      xmoe[o + (size_t)j * 512] = GB[j] * st;                                   \
    }                                                                           \
  }
  LOADB(C0, S0, G0, 0);
  LOADB(C1, S1, G1, 1);
  LOADB(C2, S2, G2, 2);
  for (int i = 0; i < 64; ++i) {
    LOADB(C3, S3, G3, 4 * i + 3);
    COMPB(C0, S0, G0, 4 * i);
    LOADB(C0, S0, G0, 4 * i + 4);
    COMPB(C1, S1, G1, 4 * i + 1);
    LOADB(C1, S1, G1, 4 * i + 5);
    COMPB(C2, S2, G2, 4 * i + 2);
    LOADB(C2, S2, G2, 4 * i + 6);
    COMPB(C3, S3, G3, 4 * i + 3);
  }
  nstate[gid] = state;
}

// K4: gate logits + softmax + top2 -> packed e01p/w01p
__global__ __launch_bounds__(256) void k_gate(const float* __restrict__ xmoe,
                                              const float* __restrict__ gw_g,
                                              const float* __restrict__ gb,
                                              int* __restrict__ e01p,
                                              unsigned* __restrict__ w01p) {
  __shared__ float gw[4096];
  int tid = threadIdx.x;
  for (int i = tid; i < 4096; i += 256) gw[i] = gw_g[i];
  __syncthreads();
  int tok = blockIdx.x * 32 + (tid >> 3);
  int e = tid & 7;
  float acc = gb[e];
  const float4* xr = (const float4*)(xmoe + (size_t)tok * 512);
  for (int k4 = 0; k4 < 128; ++k4) {
    float4 x = xr[k4];
    acc += x.x * gw[(k4 * 4 + 0) * 8 + e];
    acc += x.y * gw[(k4 * 4 + 1) * 8 + e];
    acc += x.z * gw[(k4 * 4 + 2) * 8 + e];
    acc += x.w * gw[(k4 * 4 + 3) * 8 + e];
  }
  float m = acc;
  m = fmaxf(m, __shfl_xor(m, 1));
  m = fmaxf(m, __shfl_xor(m, 2));
  m = fmaxf(m, __shfl_xor(m, 4));
  float p = expf(acc - m);
  float ss = p;
  ss += __shfl_xor(ss, 1); ss += __shfl_xor(ss, 2); ss += __shfl_xor(ss, 4);
  p /= ss;
  float v1 = p; int i1 = e;
  {
    float ov; int oi;
    ov = __shfl_xor(v1, 1); oi = __shfl_xor(i1, 1);
    if (ov > v1 || (ov == v1 && oi < i1)) { v1 = ov; i1 = oi; }
    ov = __shfl_xor(v1, 2); oi = __shfl_xor(i1, 2);
    if (ov > v1 || (ov == v1 && oi < i1)) { v1 = ov; i1 = oi; }
    ov = __shfl_xor(v1, 4); oi = __shfl_xor(i1, 4);
    if (ov > v1 || (ov == v1 && oi < i1)) { v1 = ov; i1 = oi; }
  }
  float v2 = (e == i1) ? -1.f : p; int i2 = e;
  {
    float ov; int oi;
    ov = __shfl_xor(v2, 1); oi = __shfl_xor(i2, 1);
    if (ov > v2 || (ov == v2 && oi < i2)) { v2 = ov; i2 = oi; }
    ov = __shfl_xor(v2, 2); oi = __shfl_xor(i2, 2);
    if (ov > v2 || (ov == v2 && oi < i2)) { v2 = ov; i2 = oi; }
    ov = __shfl_xor(v2, 4); oi = __shfl_xor(i2, 4);
    if (ov > v2 || (ov == v2 && oi < i2)) { v2 = ov; i2 = oi; }
  }
  if (e == 0) {
    float s2 = v1 + v2;
    __half h1 = __float2half(v1 / s2), h2 = __float2half(v2 / s2);
    e01p[tok] = i1 | (i2 << 8);
    w01p[tok] = (unsigned)__half_as_ushort(h1) | ((unsigned)__half_as_ushort(h2) << 16);
  }
}

// K6: counts -> eoff prefix -> scatter (list/wlist/tokpos), 1 block
__global__ void k_build(const int* __restrict__ e01p, const unsigned* __restrict__ w01p,
                        int* __restrict__ list, float* __restrict__ wlist,
                        int* __restrict__ counts, int* __restrict__ eoff,
                        int* __restrict__ tokpos) {
  __shared__ int cnt[8], cur[8];
  int tid = threadIdx.x, lane = tid & 63;
  if (tid < 8) cnt[tid] = 0;
  __syncthreads();
  for (int i = tid; i < 16384; i += 256) {
    int tok = i >> 1, j = i & 1;
    int ee = (e01p[tok] >> (8 * j)) & 255;
#pragma unroll
    for (int x = 0; x < 8; ++x) {
      unsigned long long m = __ballot(ee == x);
      if (m != 0ull && lane == (__ffsll((long long)m) - 1)) atomicAdd(&cnt[x], __popcll(m));
    }
  }
  __syncthreads();
  if (tid == 0) {
    int s = 0;
#pragma unroll
    for (int x = 0; x < 8; ++x) {
      cur[x] = s; eoff[x] = s; counts[x] = cnt[x]; s += cnt[x];
    }
  }
  __syncthreads();
  for (int i = tid; i < 16384; i += 256) {
    int tok = i >> 1, j = i & 1;
    int ee = (e01p[tok] >> (8 * j)) & 255;
    unsigned wp = w01p[tok];
    unsigned short us = (unsigned short)(j ? (wp >> 16) : (wp & 0xFFFFu));
    float w = __half2float(__ushort_as_half(us));
    int pos = 0;
#pragma unroll
    for (int x = 0; x < 8; ++x) {
      unsigned long long m = __ballot(ee == x);
      if (m == 0ull) continue;
      int leader = __ffsll((long long)m) - 1;
      int bb = 0;
      if (lane == leader) bb = atomicAdd(&cur[x], __popcll(m));
      bb = __shfl(bb, leader);
      if (ee == x) pos = bb + __popcll(m & ((1ull << lane) - 1ull));
    }
    list[pos] = tok;
    wlist[pos] = w;
    tokpos[i] = pos;
  }
}

// ---------------------------------------------------------------------------
// K7: fused MoE FFN. 1-D grid: expert = bid&7 (pins expert to one XCD so its
// 4MB packed weights stay L2-resident), tile = bid>>3. 1024 thr / 16 waves.
// ---------------------------------------------------------------------------
#define HS_OFF 65536

__global__ __launch_bounds__(1024, 4) void k_ffn(
    const float* __restrict__ xmoe, const int* __restrict__ list,
    const float* __restrict__ wlist, const int* __restrict__ counts,
    const int* __restrict__ eoff,
    const unsigned short* __restrict__ W1Pk, const float* __restrict__ b1g,
    const unsigned short* __restrict__ W2Pk, const float* __restrict__ b2g,
    unsigned short* __restrict__ Yb) {
  int bid = blockIdx.x;
  int e = bid & 7, tile = bid >> 3;
  int cnt = counts[e];
  if (tile * 64 >= cnt) return;
  int base = eoff[e] + tile * 64;
  int valid = cnt - tile * 64;
  if (valid > 64) valid = 64;
  __shared__ __align__(16) char smem[131072];
  __shared__ int toks[64];
  __shared__ float wts[64];
  int tid = threadIdx.x;
  int w = tid >> 6, l = tid & 63;
  int l31 = l & 31, hi = l >> 5;
  int sw = (l31 & 7) << 4;
  if (tid < 64) {
    int idx = tile * 64 + tid;
    bool v = idx < cnt;
    toks[tid] = list[eoff[e] + (v ? idx : 0)];
    wts[tid] = v ? wlist[eoff[e] + idx] : 0.f;
  }
  __syncthreads();
#pragma unroll
  for (int s = 0; s < 4; ++s) {
    int i = tid + s * 1024;
    int row = i >> 6, g = i & 63;
    const float* src = xmoe + (size_t)toks[row] * 512 + g * 8;
    float4 v0 = *(const float4*)src;
    float4 v1 = *(const float4*)(src + 4);
    u32x4 u;
    u.x = (unsigned)f2bf(v0.x) | ((unsigned)f2bf(v0.y) << 16);
    u.y = (unsigned)f2bf(v0.z) | ((unsigned)f2bf(v0.w) << 16);
    u.z = (unsigned)f2bf(v1.x) | ((unsigned)f2bf(v1.y) << 16);
    u.w = (unsigned)f2bf(v1.z) | ((unsigned)f2bf(v1.w) << 16);
    *(u32x4*)(smem + row * 1024 + ((g * 16) ^ ((row & 7) << 4))) = u;
  }
  f32x16 acc0, acc1;
#pragma unroll
  for (int i = 0; i < 16; ++i) { acc0[i] = 0.f; acc1[i] = 0.f; }
  __syncthreads();

  for (int it = 0; it < 4; ++it) {
    f32x16 z0, z1;
#pragma unroll
    for (int i = 0; i < 16; ++i) { z0[i] = 0.f; z1[i] = 0.f; }
    const unsigned short* w1p =
        W1Pk + (((size_t)e * 64 + it * 16 + w) * 32) * 512 + l * 8;
#pragma unroll 8
    for (int ks = 0; ks < 32; ++ks) {
      bf16x8 a = *(const bf16x8*)(w1p + (size_t)ks * 512);
      int kb = ks * 32 + hi * 16;
      bf16x8 b0 = ld_frag(smem + l31 * 1024 + (kb ^ sw));
      bf16x8 b1 = ld_frag(smem + (l31 + 32) * 1024 + (kb ^ sw));
      z0 = __builtin_amdgcn_mfma_f32_32x32x16_bf16(a, b0, z0, 0, 0, 0);
      z1 = __builtin_amdgcn_mfma_f32_32x32x16_bf16(a, b1, z1, 0, 0, 0);
    }
#pragma unroll
    for (int rq = 0; rq < 4; ++rq) {
      int f0 = 8 * rq + 4 * hi;
      float4 bv = *(const float4*)(b1g + e * 2048 + it * 512 + w * 32 + f0);
      float g0 = gelu_tanh(z0[4 * rq + 0] + bv.x);
      float g1 = gelu_tanh(z0[4 * rq + 1] + bv.y);
      float g2 = gelu_tanh(z0[4 * rq + 2] + bv.z);
      float g3 = gelu_tanh(z0[4 * rq + 3] + bv.w);
      u32x2 p;
      p.x = (unsigned)f2bf(g0) | ((unsigned)f2bf(g1) << 16);
      p.y = (unsigned)f2bf(g2) | ((unsigned)f2bf(g3) << 16);
      *(u32x2*)(smem + HS_OFF + l31 * 1024 + (((w * 32 + f0) * 2) ^ sw)) = p;
      g0 = gelu_tanh(z1[4 * rq + 0] + bv.x);
      g1 = gelu_tanh(z1[4 * rq + 1] + bv.y);
      g2 = gelu_tanh(z1[4 * rq + 2] + bv.z);
      g3 = gelu_tanh(z1[4 * rq + 3] + bv.w);
      p.x = (unsigned)f2bf(g0) | ((unsigned)f2bf(g1) << 16);
      p.y = (unsigned)f2bf(g2) | ((unsigned)f2bf(g3) << 16);
      *(u32x2*)(smem + HS_OFF + (l31 + 32) * 1024 + (((w * 32 + f0) * 2) ^ sw)) = p;
    }
    __syncthreads();
    const unsigned short* w2p =
        W2Pk + (((size_t)e * 16 + w) * 128 + it * 32) * 512 + l * 8;
#pragma unroll 8
    for (int fs = 0; fs < 32; ++fs) {
      bf16x8 a = *(const bf16x8*)(w2p + (size_t)fs * 512);
      int fb = fs * 32 + hi * 16;
      bf16x8 h0 = ld_frag(smem + HS_OFF + l31 * 1024 + (fb ^ sw));
      bf16x8 h1 = ld_frag(smem + HS_OFF + (l31 + 32) * 1024 + (fb ^ sw));
      acc0 = __builtin_amdgcn_mfma_f32_32x32x16_bf16(a, h0, acc0, 0, 0, 0);
      acc1 = __builtin_amdgcn_mfma_f32_32x32x16_bf16(a, h1, acc1, 0, 0, 0);
    }
    __syncthreads();
  }
#pragma unroll
  for (int rq = 0; rq < 4; ++rq) {
    int c0 = w * 32 + 8 * rq + 4 * hi;
    float4 b2v = *(const float4*)(b2g + e * 512 + c0);
    {
      int tok = l31;
      float wt = wts[tok];
      u32x2 p;
      p.x = (unsigned)f2bf((acc0[4 * rq + 0] + b2v.x) * wt) |
            ((unsigned)f2bf((acc0[4 * rq + 1] + b2v.y) * wt) << 16);
      p.y = (unsigned)f2bf((acc0[4 * rq + 2] + b2v.z) * wt) |
            ((unsigned)f2bf((acc0[4 * rq + 3] + b2v.w) * wt) << 16);
      *(u32x2*)(smem + tok * 1024 + ((c0 * 2) ^ ((tok & 7) << 4))) = p;
    }
    {
      int tok = 32 + l31;
      float wt = wts[tok];
      u32x2 p;
      p.x = (unsigned)f2bf((acc1[4 * rq + 0] + b2v.x) * wt) |
            ((unsigned)f2bf((acc1[4 * rq + 1] + b2v.y) * wt) << 16);
      p.y = (unsigned)f2bf((acc1[4 * rq + 2] + b2v.z) * wt) |
            ((unsigned)f2bf((acc1[4 * rq + 3] + b2v.w) * wt) << 16);
      *(u32x2*)(smem + tok * 1024 + ((c0 * 2) ^ ((tok & 7) << 4))) = p;
    }
  }
  __syncthreads();
#pragma unroll
  for (int s = 0; s < 4; ++s) {
    int i = tid + s * 1024;
    int row = i >> 6, g = i & 63;
    if (row < valid) {
      u32x4 v = *(u32x4*)(smem + row * 1024 + ((g * 16) ^ ((row & 7) << 4)));
      *(u32x4*)(Yb + (size_t)(base + row) * 512 + g * 8) = v;
    }
  }
}

// ---------------------------------------------------------------------------
// K8: head bf16 MFMA GEMM (unchanged)
// ---------------------------------------------------------------------------
__global__ __launch_bounds__(256) void k_head(const unsigned short* __restrict__ Yb,
                                              const int* __restrict__ tokpos,
                                              const unsigned short* __restrict__ headPk,
                                              const float* __restrict__ headB,
                                              float* __restrict__ out) {
  __shared__ __align__(16) char As[16384];
  __shared__ int tp[256];
  int tid = threadIdx.x;
  int w = tid >> 6, l = tid & 63;
  int l31 = l & 31, hi = l >> 5;
  int mg = w & 1, ng = w >> 1;
  int bm = blockIdx.x * 128, by = blockIdx.y;
  tp[tid] = tokpos[bm * 2 + tid];
  f32x16 acc00, acc01, acc10, acc11;
#pragma unroll
  for (int i = 0; i < 16; ++i) { acc00[i] = 0.f; acc01[i] = 0.f; acc10[i] = 0.f; acc11[i] = 0.f; }
  int nblk0 = by * 4 + ng * 2;
  __syncthreads();
  for (int kb = 0; kb < 8; ++kb) {
#pragma unroll
    for (int s = 0; s < 4; ++s) {
      int i = tid + s * 256;
      int row = i >> 3, g = i & 7;
      int p1 = tp[row * 2], p2 = tp[row * 2 + 1];
      u32x4 va = *(const u32x4*)(Yb + (size_t)p1 * 512 + kb * 64 + g * 8);
      u32x4 vb = *(const u32x4*)(Yb + (size_t)p2 * 512 + kb * 64 + g * 8);
      u32x4 o;
      o.x = (unsigned)f2bf(bflo(va.x) + bflo(vb.x)) | ((unsigned)f2bf(bfhi(va.x) + bfhi(vb.x)) << 16);
      o.y = (unsigned)f2bf(bflo(va.y) + bflo(vb.y)) | ((unsigned)f2bf(bfhi(va.y) + bfhi(vb.y)) << 16);
      o.z = (unsigned)f2bf(bflo(va.z) + bflo(vb.z)) | ((unsigned)f2bf(bfhi(va.z) + bfhi(vb.z)) << 16);
      o.w = (unsigned)f2bf(bflo(va.w) + bflo(vb.w)) | ((unsigned)f2bf(bfhi(va.w) + bfhi(vb.w)) << 16);
      *(u32x4*)(As + row * 128 + ((g * 16) ^ ((row & 7) << 4))) = o;
    }
    __syncthreads();
#pragma unroll
    for (int ks = 0; ks < 4; ++ks) {
      int r0 = mg * 64 + l31, r1 = r0 + 32;
      int kbyte = ks * 32 + hi * 16;
      bf16x8 a0 = ld_frag(As + r0 * 128 + (kbyte ^ ((r0 & 7) << 4)));
      bf16x8 a1 = ld_frag(As + r1 * 128 + (kbyte ^ ((r1 & 7) << 4)));
      const unsigned short* hp = headPk + ((size_t)nblk0 * 32 + kb * 4 + ks) * 512 + l * 8;
      bf16x8 b0 = *(const bf16x8*)hp;
      bf16x8 b1 = *(const bf16x8*)(hp + 32 * 512);
      acc00 = __builtin_amdgcn_mfma_f32_32x32x16_bf16(a0, b0, acc00, 0, 0, 0);
      acc01 = __builtin_amdgcn_mfma_f32_32x32x16_bf16(a0, b1, acc01, 0, 0, 0);
      acc10 = __builtin_amdgcn_mfma_f32_32x32x16_bf16(a1, b0, acc10, 0, 0, 0);
      acc11 = __builtin_amdgcn_mfma_f32_32x32x16_bf16(a1, b1, acc11, 0, 0, 0);
    }
    __syncthreads();
  }
#pragma unroll
  for (int mf = 0; mf < 2; ++mf) {
#pragma unroll
    for (int nf = 0; nf < 2; ++nf) {
      int nc = by * 128 + ng * 64 + nf * 32 + l31;
      float hb = headB[nc];
#pragma unroll
      for (int r = 0; r < 16; ++r) {
        int m = bm + mg * 64 + mf * 32 + (r & 3) + 8 * (r >> 2) + 4 * hi;
        float v;
        if (mf == 0) v = (nf == 0) ? acc00[r] : acc01[r];
        else         v = (nf == 0) ? acc10[r] : acc11[r];
        out[(size_t)m * 256 + nc] = v + hb;
      }
    }
  }
}

extern "C" void kernel_launch(void* const* d_in, const int* in_sizes, int n_in,
                              void* d_out, int out_size, void* d_ws, size_t ws_size,
                              hipStream_t stream) {
  (void)in_sizes; (void)n_in; (void)out_size; (void)ws_size;
  const int* seq     = (const int*)d_in[0];
  const float* emb   = (const float*)d_in[1];
  const float* phi_w = (const float*)d_in[2];
  const float* phi_b = (const float*)d_in[3];
  const float* amp_w = (const float*)d_in[4];
  const float* amp_b = (const float*)d_in[5];
  const float* gate_w = (const float*)d_in[6];
  const float* gate_b = (const float*)d_in[7];
  const float* w1 = (const float*)d_in[8];
  const float* b1 = (const float*)d_in[9];
  const float* w2 = (const float*)d_in[10];
  const float* b2 = (const float*)d_in[11];
  const float* head_w = (const float*)d_in[12];
  const float* head_b = (const float*)d_in[13];
  float* out = (float*)d_out;

  char* ws = (char*)d_ws;
  const size_t BUF = 16777216;
  float* X    = (float*)(ws);                         // X -> xmoe (in place)
  float* COSb = (float*)(ws + BUF);                   // cos -> Yb (bf16)
  float* SINb = (float*)(ws + 2 * BUF);               // sin -> W1Pk (bf16)
  float* SIGb = (float*)(ws + 3 * BUF);               // sig -> W2Pk (bf16)
  unsigned short* Yb   = (unsigned short*)COSb;
  unsigned short* W1Pk = (unsigned short*)SINb;
  unsigned short* W2Pk = (unsigned short*)SIGb;
  char* sm = ws + 4 * BUF;
  int*      e01p   = (int*)(sm);                      // 32KB
  unsigned* w01p   = (unsigned*)(sm + 32768);         // 32KB
  int*      list   = (int*)(sm + 65536);              // 64KB
  float*    wlist  = (float*)(sm + 131072);           // 64KB
  int*      tokpos = (int*)(sm + 196608);             // 64KB
  int*      counts = (int*)(sm + 262144);
  int*      eoff   = (int*)(sm + 262144 + 64);
  unsigned short* headPk = (unsigned short*)(sm + 266240);  // 256KB

  k_embed<<<4096, 256, 0, stream>>>(seq, emb, X);
  k_pack_b<<<dim3(8, 1, 1), 256, 0, stream>>>(head_w, 256, 0, headPk, 0, 32);
  k_phi<<<dim3(64, 8), 256, 0, stream>>>(X, phi_w, phi_b, amp_w, amp_b, COSb, SINb, SIGb);
  k_scan<<<32, 64, 0, stream>>>(COSb, SINb, SIGb, X, out + 2097152);
  k_pack_b<<<dim3(64, 1, 8), 256, 0, stream>>>(w1, 2048, (size_t)512 * 2048, W1Pk,
                                               (size_t)64 * 32 * 512, 32);
  k_pack_b<<<dim3(16, 4, 8), 256, 0, stream>>>(w2, 512, (size_t)2048 * 512, W2Pk,
                                               (size_t)16 * 128 * 512, 128);
  k_gate<<<256, 256, 0, stream>>>(X, gate_w, gate_b, e01p, w01p);
  k_build<<<1, 256, 0, stream>>>(e01p, w01p, list, wlist, counts, eoff, tokpos);
  // 1-D grid: expert = bid&7 (XCD-pinned), tile = bid>>3 (full 8192 coverage)
  k_ffn<<<1024, 1024, 0, stream>>>(X, list, wlist, counts, eoff,
                                   W1Pk, b1, W2Pk, b2, Yb);
  k_head<<<dim3(64, 2), 256, 0, stream>>>(Yb, tokpos, headPk, head_b, out);
}

// Round 8
// 742.923 us; speedup vs baseline: 1.0049x; 1.0049x over previous
//
#include <hip/hip_runtime.h>
#include <hip/hip_fp16.h>
#include <math.h>

// ---------------------------------------------------------------------------
// SovereignLeviathanV2  round 8 = round 7 with k_ffn v3:
//  - frag-packed Xs/Hs LDS layouts (conflict-free ds_read_b128)
//  - 8 waves / 512 thr, 64f x 64tok & 64c x 64tok wave tiles (4 MFMA per
//    2 LDS reads), launch_bounds(512,2)
//  - exact tile map (tmap) built in k_build: <=263 real tiles, chunked
//    XCD-balanced; grid 272 (no 768 empty 128KB blocks)
// Everything else byte-identical to the passing round-7 kernel.
// ---------------------------------------------------------------------------

#define PI_F 3.14159265358979323846f
#define HARM_F 1.04719755119659774615f
#define INV_HARM_F 0.95492965855137201461f
#define TOL_F 0.15f

typedef float f32x16 __attribute__((ext_vector_type(16)));
typedef __bf16 bf16x8 __attribute__((ext_vector_type(8)));
typedef unsigned int u32x4 __attribute__((ext_vector_type(4)));
typedef unsigned int u32x2 __attribute__((ext_vector_type(2)));

__device__ __forceinline__ float gelu_tanh(float x) {
  float x3 = x * x * x;
  return 0.5f * x * (1.f + tanhf(0.79788456080286535588f * (x + 0.044715f * x3)));
}
__device__ __forceinline__ unsigned short f2bf(float x) {
  unsigned u = __float_as_uint(x);
  unsigned r = (u + 0x7FFFu + ((u >> 16) & 1u)) >> 16;
  return (unsigned short)r;
}
__device__ __forceinline__ float bflo(unsigned u) { return __uint_as_float(u << 16); }
__device__ __forceinline__ float bfhi(unsigned u) { return __uint_as_float(u & 0xFFFF0000u); }
__device__ __forceinline__ bf16x8 ld_frag(const void* p) {
  u32x4 v = *(const u32x4*)p;
  return __builtin_bit_cast(bf16x8, v);
}

// K1: X[n][c] = emb[seq[n]][c]
__global__ void k_embed(const int* __restrict__ seq, const float* __restrict__ emb,
                        float* __restrict__ X) {
  int i = blockIdx.x * 256 + threadIdx.x;
  int n = i >> 7, c4 = i & 127;
  int tok = seq[n];
  ((float4*)X)[(size_t)n * 128 + c4] = ((const float4*)emb)[(size_t)tok * 128 + c4];
}

// ---------------------------------------------------------------------------
// Generic B-operand frag pack (unchanged)
// ---------------------------------------------------------------------------
__global__ __launch_bounds__(256) void k_pack_b(const float* __restrict__ src, int ld,
                                                size_t srcE, unsigned short* __restrict__ dst,
                                                size_t dstE, int fragKtot) {
  __shared__ float Ls[512 * 33];
  int nb = blockIdx.x, kseg = blockIdx.y, e = blockIdx.z;
  const float* s = src + (size_t)e * srcE + (size_t)kseg * 512 * ld + nb * 32;
  unsigned short* d = dst + (size_t)e * dstE + ((size_t)(nb * fragKtot + kseg * 32)) * 512;
  int tid = threadIdx.x;
#pragma unroll
  for (int q = 0; q < 16; ++q) {
    int i = tid + q * 256;
    int row = i >> 3, c4 = i & 7;
    float4 v = *(const float4*)(s + (size_t)row * ld + c4 * 4);
    Ls[row * 33 + c4 * 4 + 0] = v.x;
    Ls[row * 33 + c4 * 4 + 1] = v.y;
    Ls[row * 33 + c4 * 4 + 2] = v.z;
    Ls[row * 33 + c4 * 4 + 3] = v.w;
  }
  __syncthreads();
#pragma unroll
  for (int q = 0; q < 8; ++q) {
    int i = tid + q * 256;
    int ks = i >> 6, l = i & 63;
    int col = l & 31, kb = (l >> 5) * 8 + ks * 16;
    u32x4 o;
    o.x = (unsigned)f2bf(Ls[(kb + 0) * 33 + col]) | ((unsigned)f2bf(Ls[(kb + 1) * 33 + col]) << 16);
    o.y = (unsigned)f2bf(Ls[(kb + 2) * 33 + col]) | ((unsigned)f2bf(Ls[(kb + 3) * 33 + col]) << 16);
    o.z = (unsigned)f2bf(Ls[(kb + 4) * 33 + col]) | ((unsigned)f2bf(Ls[(kb + 5) * 33 + col]) << 16);
    o.w = (unsigned)f2bf(Ls[(kb + 6) * 33 + col]) | ((unsigned)f2bf(Ls[(kb + 7) * 33 + col]) << 16);
    *(u32x4*)(d + (size_t)ks * 512 + l * 8) = o;
  }
}

// ---------------------------------------------------------------------------
// K2: fused phi+amp fp32 GEMM (unchanged from round 7)
// ---------------------------------------------------------------------------
__global__ __launch_bounds__(256, 2) void k_phi(const float* __restrict__ A,
                                                const float* __restrict__ phiW,
                                                const float* __restrict__ phiB,
                                                const float* __restrict__ ampW,
                                                const float* __restrict__ ampB,
                                                float* __restrict__ cosO,
                                                float* __restrict__ sinO,
                                                float* __restrict__ sigO) {
  __shared__ float As[2][16 * 132];
  __shared__ float Bs[2][16 * 132];
  int tid = threadIdx.x;
  int tx = tid & 15, ty = tid >> 4;
  int bm = blockIdx.x * 128;
  int by = blockIdx.y;
  const float* Bsrc = (by < 4) ? phiW : ampW;
  const float* bias = (by < 4) ? phiB : ampB;
  int cb = (by & 3) * 128;
  float acc[8][8];
#pragma unroll
  for (int r = 0; r < 8; ++r)
#pragma unroll
    for (int c = 0; c < 8; ++c) acc[r][c] = 0.f;

#define STAGE_PHI(BUF, KT)                                                     \
  {                                                                            \
    _Pragma("unroll") for (int s = 0; s < 2; ++s) {                            \
      int i = tid + s * 256;                                                   \
      int row = i >> 2, kq = i & 3;                                            \
      float4 v = *(const float4*)(A + (size_t)(bm + row) * 512 + (KT)*16 + kq * 4); \
      As[BUF][(kq * 4 + 0) * 132 + row] = v.x;                                 \
      As[BUF][(kq * 4 + 1) * 132 + row] = v.y;                                 \
      As[BUF][(kq * 4 + 2) * 132 + row] = v.z;                                 \
      As[BUF][(kq * 4 + 3) * 132 + row] = v.w;                                 \
    }                                                                          \
    _Pragma("unroll") for (int s = 0; s < 2; ++s) {                            \
      int i = tid + s * 256;                                                   \
      int kk = i >> 5, g = i & 31;                                             \
      float4 v = *(const float4*)(Bsrc + (size_t)((KT)*16 + kk) * 512 + cb + g * 4); \
      *(float4*)(&Bs[BUF][kk * 132 + g * 4]) = v;                              \
    }                                                                          \
  }

  STAGE_PHI(0, 0);
  for (int kt = 0; kt < 32; ++kt) {
    __syncthreads();
    if (kt + 1 < 32) {
      if ((kt & 1) == 0) STAGE_PHI(1, kt + 1) else STAGE_PHI(0, kt + 1)
    }
    const float* Ab = As[kt & 1];
    const float* Bb = Bs[kt & 1];
#pragma unroll
    for (int kk = 0; kk < 16; ++kk) {
      float4 a0 = *(const float4*)(&Ab[kk * 132 + ty * 4]);
      float4 a1 = *(const float4*)(&Ab[kk * 132 + 64 + ty * 4]);
      float4 b0 = *(const float4*)(&Bb[kk * 132 + tx * 4]);
      float4 b1 = *(const float4*)(&Bb[kk * 132 + 64 + tx * 4]);
      float ar[8] = {a0.x, a0.y, a0.z, a0.w, a1.x, a1.y, a1.z, a1.w};
      float br[8] = {b0.x, b0.y, b0.z, b0.w, b1.x, b1.y, b1.z, b1.w};
#pragma unroll
      for (int r = 0; r < 8; ++r)
#pragma unroll
        for (int c = 0; c < 8; ++c) acc[r][c] = fmaf(ar[r], br[c], acc[r][c]);
    }
  }
#pragma unroll
  for (int rh = 0; rh < 2; ++rh) {
#pragma unroll
    for (int rr = 0; rr < 4; ++rr) {
      int r = rh * 4 + rr;
      int m = bm + rh * 64 + ty * 4 + rr;
      if (by < 4) {
#pragma unroll
        for (int ch = 0; ch < 2; ++ch) {
          float o0[4], o1[4];
#pragma unroll
          for (int cc = 0; cc < 4; ++cc) {
            float z = acc[r][ch * 4 + cc] + bias[cb + ch * 64 + tx * 4 + cc];
            float a = tanhf(z) * PI_F;
            float nr = rintf(a * INV_HARM_F) * HARM_F;
            if (fabsf(a - nr) < TOL_F) a = nr;
            float sn, cs;
            sincosf(a, &sn, &cs);
            o0[cc] = cs;
            o1[cc] = sn;
          }
          float* cp = cosO + (size_t)m * 512 + cb + ch * 64 + tx * 4;
          float* sp = sinO + (size_t)m * 512 + cb + ch * 64 + tx * 4;
          *(float4*)cp = make_float4(o0[0], o0[1], o0[2], o0[3]);
          *(float4*)sp = make_float4(o1[0], o1[1], o1[2], o1[3]);
        }
      } else {
#pragma unroll
        for (int ch = 0; ch < 2; ++ch) {
          float o0[4];
#pragma unroll
          for (int cc = 0; cc < 4; ++cc) {
            float z = acc[r][ch * 4 + cc] + bias[cb + ch * 64 + tx * 4 + cc];
            o0[cc] = 1.f / (1.f + expf(-z));
          }
          float* gp = sigO + (size_t)m * 512 + cb + ch * 64 + tx * 4;
          *(float4*)gp = make_float4(o0[0], o0[1], o0[2], o0[3]);
        }
      }
    }
  }
}

// K3: toroidal scan (unchanged)
__global__ void k_scan(const float* __restrict__ cosb, const float* __restrict__ sinb,
                       const float* __restrict__ sigb, float* __restrict__ xmoe,
                       float* __restrict__ nstate) {
  int gid = blockIdx.x * 64 + threadIdx.x;
  size_t b = gid >> 9, c = gid & 511;
  size_t base = (b * 2048) * 512 + c;
  float state = 0.f;
  float C0[8], S0[8], G0[8], C1[8], S1[8], G1[8];
  float C2[8], S2[8], G2[8], C3[8], S3[8], G3[8];
#define LOADB(CB, SB, GB, blk)                                                  \
  {                                                                             \
    int bb = (blk) < 255 ? (blk) : 255;                                         \
    size_t o = base + (size_t)bb * 8 * 512;                                     \
    _Pragma("unroll") for (int j = 0; j < 8; ++j) {                             \
      size_t oo = o + (size_t)j * 512;                                          \
      CB[j] = cosb[oo]; SB[j] = sinb[oo]; GB[j] = sigb[oo];                     \
    }                                                                           \
  }
#define COMPB(CB, SB, GB, blk)                                                  \
  {                                                                             \
    size_t o = base + (size_t)(blk)*8 * 512;                                    \
    _Pragma("unroll") for (int j = 0; j < 8; ++j) {                             \
      float st = fmaf(SB[j], state, -SB[j]);                                    \
      st = fmaf(CB[j], state, st);                                              \
      st = fminf(1.f, fmaxf(-1.f, st));                                         \
      state = st;                                                               \
      xmoe[o + (size_t)j * 512] = GB[j] * st;                                   \
    }                                                                           \
  }
  LOADB(C0, S0, G0, 0);
  LOADB(C1, S1, G1, 1);
  LOADB(C2, S2, G2, 2);
  for (int i = 0; i < 64; ++i) {
    LOADB(C3, S3, G3, 4 * i + 3);
    COMPB(C0, S0, G0, 4 * i);
    LOADB(C0, S0, G0, 4 * i + 4);
    COMPB(C1, S1, G1, 4 * i + 1);
    LOADB(C1, S1, G1, 4 * i + 5);
    COMPB(C2, S2, G2, 4 * i + 2);
    LOADB(C2, S2, G2, 4 * i + 6);
    COMPB(C3, S3, G3, 4 * i + 3);
  }
  nstate[gid] = state;
}

// K4: gate logits + softmax + top2 (unchanged)
__global__ __launch_bounds__(256) void k_gate(const float* __restrict__ xmoe,
                                              const float* __restrict__ gw_g,
                                              const float* __restrict__ gb,
                                              int* __restrict__ e01p,
                                              unsigned* __restrict__ w01p) {
  __shared__ float gw[4096];
  int tid = threadIdx.x;
  for (int i = tid; i < 4096; i += 256) gw[i] = gw_g[i];
  __syncthreads();
  int tok = blockIdx.x * 32 + (tid >> 3);
  int e = tid & 7;
  float acc = gb[e];
  const float4* xr = (const float4*)(xmoe + (size_t)tok * 512);
  for (int k4 = 0; k4 < 128; ++k4) {
    float4 x = xr[k4];
    acc += x.x * gw[(k4 * 4 + 0) * 8 + e];
    acc += x.y * gw[(k4 * 4 + 1) * 8 + e];
    acc += x.z * gw[(k4 * 4 + 2) * 8 + e];
    acc += x.w * gw[(k4 * 4 + 3) * 8 + e];
  }
  float m = acc;
  m = fmaxf(m, __shfl_xor(m, 1));
  m = fmaxf(m, __shfl_xor(m, 2));
  m = fmaxf(m, __shfl_xor(m, 4));
  float p = expf(acc - m);
  float ss = p;
  ss += __shfl_xor(ss, 1); ss += __shfl_xor(ss, 2); ss += __shfl_xor(ss, 4);
  p /= ss;
  float v1 = p; int i1 = e;
  {
    float ov; int oi;
    ov = __shfl_xor(v1, 1); oi = __shfl_xor(i1, 1);
    if (ov > v1 || (ov == v1 && oi < i1)) { v1 = ov; i1 = oi; }
    ov = __shfl_xor(v1, 2); oi = __shfl_xor(i1, 2);
    if (ov > v1 || (ov == v1 && oi < i1)) { v1 = ov; i1 = oi; }
    ov = __shfl_xor(v1, 4); oi = __shfl_xor(i1, 4);
    if (ov > v1 || (ov == v1 && oi < i1)) { v1 = ov; i1 = oi; }
  }
  float v2 = (e == i1) ? -1.f : p; int i2 = e;
  {
    float ov; int oi;
    ov = __shfl_xor(v2, 1); oi = __shfl_xor(i2, 1);
    if (ov > v2 || (ov == v2 && oi < i2)) { v2 = ov; i2 = oi; }
    ov = __shfl_xor(v2, 2); oi = __shfl_xor(i2, 2);
    if (ov > v2 || (ov == v2 && oi < i2)) { v2 = ov; i2 = oi; }
    ov = __shfl_xor(v2, 4); oi = __shfl_xor(i2, 4);
    if (ov > v2 || (ov == v2 && oi < i2)) { v2 = ov; i2 = oi; }
  }
  if (e == 0) {
    float s2 = v1 + v2;
    __half h1 = __float2half(v1 / s2), h2 = __float2half(v2 / s2);
    e01p[tok] = i1 | (i2 << 8);
    w01p[tok] = (unsigned)__half_as_ushort(h1) | ((unsigned)__half_as_ushort(h2) << 16);
  }
}

// K6: counts -> eoff -> scatter -> tmap (chunked XCD-balanced tile map)
__global__ void k_build(const int* __restrict__ e01p, const unsigned* __restrict__ w01p,
                        int* __restrict__ list, float* __restrict__ wlist,
                        int* __restrict__ counts, int* __restrict__ eoff,
                        int* __restrict__ tokpos, int* __restrict__ tmap) {
  __shared__ int cnt[8], cur[8];
  int tid = threadIdx.x, lane = tid & 63;
  if (tid < 8) cnt[tid] = 0;
  __syncthreads();
  for (int i = tid; i < 16384; i += 256) {
    int tok = i >> 1, j = i & 1;
    int ee = (e01p[tok] >> (8 * j)) & 255;
#pragma unroll
    for (int x = 0; x < 8; ++x) {
      unsigned long long m = __ballot(ee == x);
      if (m != 0ull && lane == (__ffsll((long long)m) - 1)) atomicAdd(&cnt[x], __popcll(m));
    }
  }
  __syncthreads();
  if (tid == 0) {
    int s = 0;
#pragma unroll
    for (int x = 0; x < 8; ++x) {
      cur[x] = s; eoff[x] = s; counts[x] = cnt[x]; s += cnt[x];
    }
  }
  __syncthreads();
  for (int i = tid; i < 272; i += 256) tmap[i] = -1;
  __syncthreads();
  if (tid == 0) {
    // chunked XCD-balanced tile map: tiles in expert-major order, chunk c of
    // the list lands on slots s%8 == c (slot = 8*o + c)
    int ntiles = 0, tstart[8];
#pragma unroll
    for (int e = 0; e < 8; ++e) { tstart[e] = ntiles; ntiles += (cnt[e] + 63) >> 6; }
    int q = ntiles >> 3, r = ntiles & 7;
    for (int e = 0; e < 8; ++e) {
      int nt = (cnt[e] + 63) >> 6;
      for (int t = 0; t < nt; ++t) {
        int k = tstart[e] + t;
        int c, o;
        if (k < r * (q + 1)) { c = k / (q + 1); o = k - c * (q + 1); }
        else { int k2 = k - r * (q + 1); c = r + k2 / q; o = k2 - (k2 / q) * q; }
        tmap[8 * o + c] = (e << 16) | t;
      }
    }
  }
  __syncthreads();
  for (int i = tid; i < 16384; i += 256) {
    int tok = i >> 1, j = i & 1;
    int ee = (e01p[tok] >> (8 * j)) & 255;
    unsigned wp = w01p[tok];
    unsigned short us = (unsigned short)(j ? (wp >> 16) : (wp & 0xFFFFu));
    float w = __half2float(__ushort_as_half(us));
    int pos = 0;
#pragma unroll
    for (int x = 0; x < 8; ++x) {
      unsigned long long m = __ballot(ee == x);
      if (m == 0ull) continue;
      int leader = __ffsll((long long)m) - 1;
      int bb = 0;
      if (lane == leader) bb = atomicAdd(&cur[x], __popcll(m));
      bb = __shfl(bb, leader);
      if (ee == x) pos = bb + __popcll(m & ((1ull << lane) - 1ull));
    }
    list[pos] = tok;
    wlist[pos] = w;
    tokpos[i] = pos;
  }
}

// ---------------------------------------------------------------------------
// K7 v3: fused MoE FFN. Block = tmap tile (expert, 64 tokens), 512 thr /
// 8 waves (2/SIMD, 256-VGPR budget). F-strips of 512 (4 iters).
// Frag-packed LDS: Xs_packed[ks*2+t2][lane] (64KB), Hs_packed[fs*2+t2][lane]
// (64KB) -> all ds_read_b128 linear, conflict-free.
// GEMM1: wave = 2 f-tiles x 2 tok-tiles (4 MFMA per 2 LDS + 2 global reads).
// GEMM2: wave = 2 c-tiles x 2 tok-tiles, acc 4x f32x16.
// ---------------------------------------------------------------------------
#define HS_OFF 65536

__global__ __launch_bounds__(512, 2) void k_ffn(
    const float* __restrict__ xmoe, const int* __restrict__ list,
    const float* __restrict__ wlist, const int* __restrict__ counts,
    const int* __restrict__ eoff, const int* __restrict__ tmap,
    const unsigned short* __restrict__ W1Pk, const float* __restrict__ b1g,
    const unsigned short* __restrict__ W2Pk, const float* __restrict__ b2g,
    unsigned short* __restrict__ Yb) {
  int mp = tmap[blockIdx.x];
  if (mp < 0) return;
  int e = mp >> 16, tile = mp & 0xFFFF;
  int cnt = counts[e];
  int base = eoff[e] + tile * 64;
  int valid = cnt - tile * 64;
  if (valid > 64) valid = 64;
  __shared__ __align__(16) char smem[131072];
  __shared__ int toks[64];
  __shared__ float wts[64];
  int tid = threadIdx.x;
  int w = tid >> 6, l = tid & 63;
  int l31 = l & 31, hi = l >> 5;
  if (tid < 64) {
    int idx = tile * 64 + tid;
    bool v = idx < cnt;
    toks[tid] = list[eoff[e] + (v ? idx : 0)];
    wts[tid] = v ? wlist[eoff[e] + idx] : 0.f;
  }
  __syncthreads();
  // stage Xs_packed: 64 entries (ks*2+t2) x 64 lanes x 16B
#pragma unroll
  for (int s = 0; s < 8; ++s) {
    int sl = s * 512 + tid;
    int ent = sl >> 6, ll = sl & 63;
    int ks = ent >> 1, t2 = ent & 1;
    int tok = toks[t2 * 32 + (ll & 31)];
    const float* src = xmoe + (size_t)tok * 512 + ks * 16 + (ll >> 5) * 8;
    float4 v0 = *(const float4*)src;
    float4 v1 = *(const float4*)(src + 4);
    u32x4 u;
    u.x = (unsigned)f2bf(v0.x) | ((unsigned)f2bf(v0.y) << 16);
    u.y = (unsigned)f2bf(v0.z) | ((unsigned)f2bf(v0.w) << 16);
    u.z = (unsigned)f2bf(v1.x) | ((unsigned)f2bf(v1.y) << 16);
    u.w = (unsigned)f2bf(v1.z) | ((unsigned)f2bf(v1.w) << 16);
    *(u32x4*)(smem + ent * 1024 + ll * 16) = u;
  }
  f32x16 acc00, acc01, acc10, acc11;
#pragma unroll
  for (int i = 0; i < 16; ++i) { acc00[i] = 0.f; acc01[i] = 0.f; acc10[i] = 0.f; acc11[i] = 0.f; }
  __syncthreads();

  const size_t dstE1 = (size_t)64 * 32 * 512;
  const size_t dstE2 = (size_t)16 * 128 * 512;
  for (int it = 0; it < 4; ++it) {
    // ---- GEMM1: f-tiles it*16 + w*2 + {0,1}, all 64 tokens ----
    f32x16 z00, z01, z10, z11;
#pragma unroll
    for (int i = 0; i < 16; ++i) { z00[i] = 0.f; z01[i] = 0.f; z10[i] = 0.f; z11[i] = 0.f; }
    const unsigned short* w1a =
        W1Pk + (size_t)e * dstE1 + ((size_t)(it * 16 + w * 2) * 32) * 512 + l * 8;
    const unsigned short* w1b = w1a + (size_t)32 * 512;
#pragma unroll 4
    for (int ks = 0; ks < 32; ++ks) {
      bf16x8 a0 = *(const bf16x8*)(w1a + (size_t)ks * 512);
      bf16x8 a1 = *(const bf16x8*)(w1b + (size_t)ks * 512);
      bf16x8 b0 = ld_frag(smem + (ks * 2 + 0) * 1024 + l * 16);
      bf16x8 b1 = ld_frag(smem + (ks * 2 + 1) * 1024 + l * 16);
      z00 = __builtin_amdgcn_mfma_f32_32x32x16_bf16(a0, b0, z00, 0, 0, 0);
      z01 = __builtin_amdgcn_mfma_f32_32x32x16_bf16(a0, b1, z01, 0, 0, 0);
      z10 = __builtin_amdgcn_mfma_f32_32x32x16_bf16(a1, b0, z10, 0, 0, 0);
      z11 = __builtin_amdgcn_mfma_f32_32x32x16_bf16(a1, b1, z11, 0, 0, 0);
    }
    // bias + gelu -> Hs_packed
#define GELU_STORE(Z, JF, T2)                                                   \
  {                                                                             \
    _Pragma("unroll") for (int rq = 0; rq < 4; ++rq) {                          \
      int fb = (w * 2 + (JF)) * 32 + 8 * rq + 4 * hi;                           \
      float4 bv = *(const float4*)(b1g + e * 2048 + it * 512 + fb);             \
      float g0 = gelu_tanh(Z[4 * rq + 0] + bv.x);                               \
      float g1 = gelu_tanh(Z[4 * rq + 1] + bv.y);                               \
      float g2 = gelu_tanh(Z[4 * rq + 2] + bv.z);                               \
      float g3 = gelu_tanh(Z[4 * rq + 3] + bv.w);                               \
      u32x2 p;                                                                  \
      p.x = (unsigned)f2bf(g0) | ((unsigned)f2bf(g1) << 16);                    \
      p.y = (unsigned)f2bf(g2) | ((unsigned)f2bf(g3) << 16);                    \
      int ent = ((w * 2 + (JF)) * 2 + (rq >> 1)) * 2 + (T2);                    \
      int lanep = l31 + 32 * (rq & 1);                                          \
      *(u32x2*)(smem + HS_OFF + ent * 1024 + lanep * 16 + hi * 8) = p;          \
    }                                                                           \
  }
    GELU_STORE(z00, 0, 0)
    GELU_STORE(z01, 0, 1)
    GELU_STORE(z10, 1, 0)
    GELU_STORE(z11, 1, 1)
    __syncthreads();
    // ---- GEMM2: c-tiles w*2 + {0,1}, K = strip 512 ----
    const unsigned short* w2a =
        W2Pk + (size_t)e * dstE2 + ((size_t)(w * 2) * 128 + it * 32) * 512 + l * 8;
    const unsigned short* w2b = w2a + (size_t)128 * 512;
#pragma unroll 4
    for (int fs = 0; fs < 32; ++fs) {
      bf16x8 a0 = *(const bf16x8*)(w2a + (size_t)fs * 512);
      bf16x8 a1 = *(const bf16x8*)(w2b + (size_t)fs * 512);
      bf16x8 h0 = ld_frag(smem + HS_OFF + (fs * 2 + 0) * 1024 + l * 16);
      bf16x8 h1 = ld_frag(smem + HS_OFF + (fs * 2 + 1) * 1024 + l * 16);
      acc00 = __builtin_amdgcn_mfma_f32_32x32x16_bf16(a0, h0, acc00, 0, 0, 0);
      acc01 = __builtin_amdgcn_mfma_f32_32x32x16_bf16(a0, h1, acc01, 0, 0, 0);
      acc10 = __builtin_amdgcn_mfma_f32_32x32x16_bf16(a1, h0, acc10, 0, 0, 0);
      acc11 = __builtin_amdgcn_mfma_f32_32x32x16_bf16(a1, h1, acc11, 0, 0, 0);
    }
    __syncthreads();
  }
  // epilogue: (acc + b2) * wt -> bf16 -> LDS bounce (Xs area) [tok][c]
#define EPI_STORE(ACC, JC, T2)                                                  \
  {                                                                             \
    _Pragma("unroll") for (int rq = 0; rq < 4; ++rq) {                          \
      int c0 = (w * 2 + (JC)) * 32 + 8 * rq + 4 * hi;                           \
      float4 b2v = *(const float4*)(b2g + e * 512 + c0);                        \
      int tok = (T2)*32 + l31;                                                  \
      float wt = wts[tok];                                                      \
      u32x2 p;                                                                  \
      p.x = (unsigned)f2bf((ACC[4 * rq + 0] + b2v.x) * wt) |                    \
            ((unsigned)f2bf((ACC[4 * rq + 1] + b2v.y) * wt) << 16);             \
      p.y = (unsigned)f2bf((ACC[4 * rq + 2] + b2v.z) * wt) |                    \
            ((unsigned)f2bf((ACC[4 * rq + 3] + b2v.w) * wt) << 16);             \
      *(u32x2*)(smem + tok * 1024 + ((c0 * 2) ^ ((tok & 7) << 4))) = p;         \
    }                                                                           \
  }
  EPI_STORE(acc00, 0, 0)
  EPI_STORE(acc01, 0, 1)
  EPI_STORE(acc10, 1, 0)
  EPI_STORE(acc11, 1, 1)
  __syncthreads();
#pragma unroll
  for (int s = 0; s < 8; ++s) {
    int i = tid + s * 512;
    int row = i >> 6, g = i & 63;
    if (row < valid) {
      u32x4 v = *(u32x4*)(smem + row * 1024 + ((g * 16) ^ ((row & 7) << 4)));
      *(u32x4*)(Yb + (size_t)(base + row) * 512 + g * 8) = v;
    }
  }
}

// ---------------------------------------------------------------------------
// K8: head bf16 MFMA GEMM (unchanged)
// ---------------------------------------------------------------------------
__global__ __launch_bounds__(256) void k_head(const unsigned short* __restrict__ Yb,
                                              const int* __restrict__ tokpos,
                                              const unsigned short* __restrict__ headPk,
                                              const float* __restrict__ headB,
                                              float* __restrict__ out) {
  __shared__ __align__(16) char As[16384];
  __shared__ int tp[256];
  int tid = threadIdx.x;
  int w = tid >> 6, l = tid & 63;
  int l31 = l & 31, hi = l >> 5;
  int mg = w & 1, ng = w >> 1;
  int bm = blockIdx.x * 128, by = blockIdx.y;
  tp[tid] = tokpos[bm * 2 + tid];
  f32x16 acc00, acc01, acc10, acc11;
#pragma unroll
  for (int i = 0; i < 16; ++i) { acc00[i] = 0.f; acc01[i] = 0.f; acc10[i] = 0.f; acc11[i] = 0.f; }
  int nblk0 = by * 4 + ng * 2;
  __syncthreads();
  for (int kb = 0; kb < 8; ++kb) {
#pragma unroll
    for (int s = 0; s < 4; ++s) {
      int i = tid + s * 256;
      int row = i >> 3, g = i & 7;
      int p1 = tp[row * 2], p2 = tp[row * 2 + 1];
      u32x4 va = *(const u32x4*)(Yb + (size_t)p1 * 512 + kb * 64 + g * 8);
      u32x4 vb = *(const u32x4*)(Yb + (size_t)p2 * 512 + kb * 64 + g * 8);
      u32x4 o;
      o.x = (unsigned)f2bf(bflo(va.x) + bflo(vb.x)) | ((unsigned)f2bf(bfhi(va.x) + bfhi(vb.x)) << 16);
      o.y = (unsigned)f2bf(bflo(va.y) + bflo(vb.y)) | ((unsigned)f2bf(bfhi(va.y) + bfhi(vb.y)) << 16);
      o.z = (unsigned)f2bf(bflo(va.z) + bflo(vb.z)) | ((unsigned)f2bf(bfhi(va.z) + bfhi(vb.z)) << 16);
      o.w = (unsigned)f2bf(bflo(va.w) + bflo(vb.w)) | ((unsigned)f2bf(bfhi(va.w) + bfhi(vb.w)) << 16);
      *(u32x4*)(As + row * 128 + ((g * 16) ^ ((row & 7) << 4))) = o;
    }
    __syncthreads();
#pragma unroll
    for (int ks = 0; ks < 4; ++ks) {
      int r0 = mg * 64 + l31, r1 = r0 + 32;
      int kbyte = ks * 32 + hi * 16;
      bf16x8 a0 = ld_frag(As + r0 * 128 + (kbyte ^ ((r0 & 7) << 4)));
      bf16x8 a1 = ld_frag(As + r1 * 128 + (kbyte ^ ((r1 & 7) << 4)));
      const unsigned short* hp = headPk + ((size_t)nblk0 * 32 + kb * 4 + ks) * 512 + l * 8;
      bf16x8 b0 = *(const bf16x8*)hp;
      bf16x8 b1 = *(const bf16x8*)(hp + 32 * 512);
      acc00 = __builtin_amdgcn_mfma_f32_32x32x16_bf16(a0, b0, acc00, 0, 0, 0);
      acc01 = __builtin_amdgcn_mfma_f32_32x32x16_bf16(a0, b1, acc01, 0, 0, 0);
      acc10 = __builtin_amdgcn_mfma_f32_32x32x16_bf16(a1, b0, acc10, 0, 0, 0);
      acc11 = __builtin_amdgcn_mfma_f32_32x32x16_bf16(a1, b1, acc11, 0, 0, 0);
    }
    __syncthreads();
  }
#pragma unroll
  for (int mf = 0; mf < 2; ++mf) {
#pragma unroll
    for (int nf = 0; nf < 2; ++nf) {
      int nc = by * 128 + ng * 64 + nf * 32 + l31;
      float hb = headB[nc];
#pragma unroll
      for (int r = 0; r < 16; ++r) {
        int m = bm + mg * 64 + mf * 32 + (r & 3) + 8 * (r >> 2) + 4 * hi;
        float v;
        if (mf == 0) v = (nf == 0) ? acc00[r] : acc01[r];
        else         v = (nf == 0) ? acc10[r] : acc11[r];
        out[(size_t)m * 256 + nc] = v + hb;
      }
    }
  }
}

extern "C" void kernel_launch(void* const* d_in, const int* in_sizes, int n_in,
                              void* d_out, int out_size, void* d_ws, size_t ws_size,
                              hipStream_t stream) {
  (void)in_sizes; (void)n_in; (void)out_size; (void)ws_size;
  const int* seq     = (const int*)d_in[0];
  const float* emb   = (const float*)d_in[1];
  const float* phi_w = (const float*)d_in[2];
  const float* phi_b = (const float*)d_in[3];
  const float* amp_w = (const float*)d_in[4];
  const float* amp_b = (const float*)d_in[5];
  const float* gate_w = (const float*)d_in[6];
  const float* gate_b = (const float*)d_in[7];
  const float* w1 = (const float*)d_in[8];
  const float* b1 = (const float*)d_in[9];
  const float* w2 = (const float*)d_in[10];
  const float* b2 = (const float*)d_in[11];
  const float* head_w = (const float*)d_in[12];
  const float* head_b = (const float*)d_in[13];
  float* out = (float*)d_out;

  char* ws = (char*)d_ws;
  const size_t BUF = 16777216;
  float* X    = (float*)(ws);                         // X -> xmoe (in place)
  float* COSb = (float*)(ws + BUF);                   // cos -> Yb (bf16)
  float* SINb = (float*)(ws + 2 * BUF);               // sin -> W1Pk (bf16)
  float* SIGb = (float*)(ws + 3 * BUF);               // sig -> W2Pk (bf16)
  unsigned short* Yb   = (unsigned short*)COSb;
  unsigned short* W1Pk = (unsigned short*)SINb;
  unsigned short* W2Pk = (unsigned short*)SIGb;
  char* sm = ws + 4 * BUF;
  int*      e01p   = (int*)(sm);                      // 32KB
  unsigned* w01p   = (unsigned*)(sm + 32768);         // 32KB
  int*      list   = (int*)(sm + 65536);              // 64KB
  float*    wlist  = (float*)(sm + 131072);           // 64KB
  int*      tokpos = (int*)(sm + 196608);             // 64KB
  int*      counts = (int*)(sm + 262144);
  int*      eoff   = (int*)(sm + 262144 + 64);
  unsigned short* headPk = (unsigned short*)(sm + 266240);  // 256KB
  int*      tmap   = (int*)(sm + 266240 + 262144);          // 272 ints

  k_embed<<<4096, 256, 0, stream>>>(seq, emb, X);
  k_pack_b<<<dim3(8, 1, 1), 256, 0, stream>>>(head_w, 256, 0, headPk, 0, 32);
  k_phi<<<dim3(64, 8), 256, 0, stream>>>(X, phi_w, phi_b, amp_w, amp_b, COSb, SINb, SIGb);
  k_scan<<<32, 64, 0, stream>>>(COSb, SINb, SIGb, X, out + 2097152);
  k_pack_b<<<dim3(64, 1, 8), 256, 0, stream>>>(w1, 2048, (size_t)512 * 2048, W1Pk,
                                               (size_t)64 * 32 * 512, 32);
  k_pack_b<<<dim3(16, 4, 8), 256, 0, stream>>>(w2, 512, (size_t)2048 * 512, W2Pk,
                                               (size_t)16 * 128 * 512, 128);
  k_gate<<<256, 256, 0, stream>>>(X, gate_w, gate_b, e01p, w01p);
  k_build<<<1, 256, 0, stream>>>(e01p, w01p, list, wlist, counts, eoff, tokpos, tmap);
  k_ffn<<<272, 512, 0, stream>>>(X, list, wlist, counts, eoff, tmap,
                                 W1Pk, b1, W2Pk, b2, Yb);
  k_head<<<dim3(64, 2), 256, 0, stream>>>(Yb, tokpos, headPk, head_b, out);
}

// Round 9
// 665.362 us; speedup vs baseline: 1.1220x; 1.1166x over previous
//
#include <hip/hip_runtime.h>
#include <hip/hip_fp16.h>
#include <math.h>

// ---------------------------------------------------------------------------
// SovereignLeviathanV2  round 9 = round 8 with:
//  - k_phi epilogue: inline tanh (__expf-based), inline minimax sincos,
//    inline sigmoid. Kills the 1.1GB call-ABI spill writebacks (tanhf/
//    sincosf/expf were __ocml calls spilling 64 live acc VGPRs each).
//  - k_ffn: weight-load loops unroll 4->8 (latency-depth probe).
// Everything else byte-identical to the passing round-8 kernel.
// ---------------------------------------------------------------------------

#define PI_F 3.14159265358979323846f
#define HARM_F 1.04719755119659774615f
#define INV_HARM_F 0.95492965855137201461f
#define TOL_F 0.15f

typedef float f32x16 __attribute__((ext_vector_type(16)));
typedef __bf16 bf16x8 __attribute__((ext_vector_type(8)));
typedef unsigned int u32x4 __attribute__((ext_vector_type(4)));
typedef unsigned int u32x2 __attribute__((ext_vector_type(2)));

__device__ __forceinline__ float gelu_tanh(float x) {
  float x3 = x * x * x;
  return 0.5f * x * (1.f + tanhf(0.79788456080286535588f * (x + 0.044715f * x3)));
}
__device__ __forceinline__ unsigned short f2bf(float x) {
  unsigned u = __float_as_uint(x);
  unsigned r = (u + 0x7FFFu + ((u >> 16) & 1u)) >> 16;
  return (unsigned short)r;
}
__device__ __forceinline__ float bflo(unsigned u) { return __uint_as_float(u << 16); }
__device__ __forceinline__ float bfhi(unsigned u) { return __uint_as_float(u & 0xFFFF0000u); }
__device__ __forceinline__ bf16x8 ld_frag(const void* p) {
  u32x4 v = *(const u32x4*)p;
  return __builtin_bit_cast(bf16x8, v);
}

// inline tanh: (e^{2z}-1)/(e^{2z}+1), __expf = native v_exp (no ABI call)
__device__ __forceinline__ float tanh_fast(float z) {
  float zc = fminf(10.f, fmaxf(-10.f, z));
  float e2 = __expf(zc + zc);
  return (e2 - 1.f) / (e2 + 1.f);
}
// inline sigmoid
__device__ __forceinline__ float sigmoid_fast(float z) {
  return 1.f / (1.f + __expf(-z));
}
// inline sincos: quadrant reduction + minimax polys (pure FMA, no calls).
// valid for |a| <= pi (our angles are tanh*pi, optionally snapped to k*pi/3).
__device__ __forceinline__ void sincos_poly(float a, float* sn, float* cs) {
  float q = rintf(a * 0.63661977236758134f);  // 2/pi
  int iq = (int)q;
  float t = fmaf(-q, 1.57079637050628662f, a);   // hi(pi/2)
  t = fmaf(q, 4.37113883e-8f, t);                // - lo correction
  float t2 = t * t;
  float sp = fmaf(t2, fmaf(t2, fmaf(t2, -1.9515296e-4f, 8.3321609e-3f),
                           -1.6666654e-1f), 0.f);
  sp = fmaf(t * t2, sp / t2, t);  // t + t^3*(...)  (t2>0 except t==0)
  // safer exact form: sp = t * (1 + t2*(S1 + t2*(S2 + t2*S3)))
  sp = t * fmaf(t2, fmaf(t2, fmaf(t2, -1.9515296e-4f, 8.3321609e-3f),
                         -1.6666654e-1f), 1.f);
  float cp = fmaf(t2 * t2,
                  fmaf(t2, fmaf(t2, 2.4433158e-5f, -1.3887316e-3f), 4.1666646e-2f),
                  fmaf(t2, -0.5f, 1.f));
  int m = iq & 3;
  bool swap = (m & 1) != 0;
  float ss = swap ? cp : sp;
  float cc = swap ? sp : cp;
  *sn = (m & 2) ? -ss : ss;
  *cs = ((m + 1) & 2) ? -cc : cc;
}

// K1: X[n][c] = emb[seq[n]][c]
__global__ void k_embed(const int* __restrict__ seq, const float* __restrict__ emb,
                        float* __restrict__ X) {
  int i = blockIdx.x * 256 + threadIdx.x;
  int n = i >> 7, c4 = i & 127;
  int tok = seq[n];
  ((float4*)X)[(size_t)n * 128 + c4] = ((const float4*)emb)[(size_t)tok * 128 + c4];
}

// ---------------------------------------------------------------------------
// Generic B-operand frag pack (unchanged)
// ---------------------------------------------------------------------------
__global__ __launch_bounds__(256) void k_pack_b(const float* __restrict__ src, int ld,
                                                size_t srcE, unsigned short* __restrict__ dst,
                                                size_t dstE, int fragKtot) {
  __shared__ float Ls[512 * 33];
  int nb = blockIdx.x, kseg = blockIdx.y, e = blockIdx.z;
  const float* s = src + (size_t)e * srcE + (size_t)kseg * 512 * ld + nb * 32;
  unsigned short* d = dst + (size_t)e * dstE + ((size_t)(nb * fragKtot + kseg * 32)) * 512;
  int tid = threadIdx.x;
#pragma unroll
  for (int q = 0; q < 16; ++q) {
    int i = tid + q * 256;
    int row = i >> 3, c4 = i & 7;
    float4 v = *(const float4*)(s + (size_t)row * ld + c4 * 4);
    Ls[row * 33 + c4 * 4 + 0] = v.x;
    Ls[row * 33 + c4 * 4 + 1] = v.y;
    Ls[row * 33 + c4 * 4 + 2] = v.z;
    Ls[row * 33 + c4 * 4 + 3] = v.w;
  }
  __syncthreads();
#pragma unroll
  for (int q = 0; q < 8; ++q) {
    int i = tid + q * 256;
    int ks = i >> 6, l = i & 63;
    int col = l & 31, kb = (l >> 5) * 8 + ks * 16;
    u32x4 o;
    o.x = (unsigned)f2bf(Ls[(kb + 0) * 33 + col]) | ((unsigned)f2bf(Ls[(kb + 1) * 33 + col]) << 16);
    o.y = (unsigned)f2bf(Ls[(kb + 2) * 33 + col]) | ((unsigned)f2bf(Ls[(kb + 3) * 33 + col]) << 16);
    o.z = (unsigned)f2bf(Ls[(kb + 4) * 33 + col]) | ((unsigned)f2bf(Ls[(kb + 5) * 33 + col]) << 16);
    o.w = (unsigned)f2bf(Ls[(kb + 6) * 33 + col]) | ((unsigned)f2bf(Ls[(kb + 7) * 33 + col]) << 16);
    *(u32x4*)(d + (size_t)ks * 512 + l * 8) = o;
  }
}

// ---------------------------------------------------------------------------
// K2: fused phi+amp fp32 GEMM. Structure unchanged; epilogue now call-free.
// ---------------------------------------------------------------------------
__global__ __launch_bounds__(256, 2) void k_phi(const float* __restrict__ A,
                                                const float* __restrict__ phiW,
                                                const float* __restrict__ phiB,
                                                const float* __restrict__ ampW,
                                                const float* __restrict__ ampB,
                                                float* __restrict__ cosO,
                                                float* __restrict__ sinO,
                                                float* __restrict__ sigO) {
  __shared__ float As[2][16 * 132];
  __shared__ float Bs[2][16 * 132];
  int tid = threadIdx.x;
  int tx = tid & 15, ty = tid >> 4;
  int bm = blockIdx.x * 128;
  int by = blockIdx.y;
  const float* Bsrc = (by < 4) ? phiW : ampW;
  const float* bias = (by < 4) ? phiB : ampB;
  int cb = (by & 3) * 128;
  float acc[8][8];
#pragma unroll
  for (int r = 0; r < 8; ++r)
#pragma unroll
    for (int c = 0; c < 8; ++c) acc[r][c] = 0.f;

#define STAGE_PHI(BUF, KT)                                                     \
  {                                                                            \
    _Pragma("unroll") for (int s = 0; s < 2; ++s) {                            \
      int i = tid + s * 256;                                                   \
      int row = i >> 2, kq = i & 3;                                            \
      float4 v = *(const float4*)(A + (size_t)(bm + row) * 512 + (KT)*16 + kq * 4); \
      As[BUF][(kq * 4 + 0) * 132 + row] = v.x;                                 \
      As[BUF][(kq * 4 + 1) * 132 + row] = v.y;                                 \
      As[BUF][(kq * 4 + 2) * 132 + row] = v.z;                                 \
      As[BUF][(kq * 4 + 3) * 132 + row] = v.w;                                 \
    }                                                                          \
    _Pragma("unroll") for (int s = 0; s < 2; ++s) {                            \
      int i = tid + s * 256;                                                   \
      int kk = i >> 5, g = i & 31;                                             \
      float4 v = *(const float4*)(Bsrc + (size_t)((KT)*16 + kk) * 512 + cb + g * 4); \
      *(float4*)(&Bs[BUF][kk * 132 + g * 4]) = v;                              \
    }                                                                          \
  }

  STAGE_PHI(0, 0);
  for (int kt = 0; kt < 32; ++kt) {
    __syncthreads();
    if (kt + 1 < 32) {
      if ((kt & 1) == 0) STAGE_PHI(1, kt + 1) else STAGE_PHI(0, kt + 1)
    }
    const float* Ab = As[kt & 1];
    const float* Bb = Bs[kt & 1];
#pragma unroll
    for (int kk = 0; kk < 16; ++kk) {
      float4 a0 = *(const float4*)(&Ab[kk * 132 + ty * 4]);
      float4 a1 = *(const float4*)(&Ab[kk * 132 + 64 + ty * 4]);
      float4 b0 = *(const float4*)(&Bb[kk * 132 + tx * 4]);
      float4 b1 = *(const float4*)(&Bb[kk * 132 + 64 + tx * 4]);
      float ar[8] = {a0.x, a0.y, a0.z, a0.w, a1.x, a1.y, a1.z, a1.w};
      float br[8] = {b0.x, b0.y, b0.z, b0.w, b1.x, b1.y, b1.z, b1.w};
#pragma unroll
      for (int r = 0; r < 8; ++r)
#pragma unroll
        for (int c = 0; c < 8; ++c) acc[r][c] = fmaf(ar[r], br[c], acc[r][c]);
    }
  }
#pragma unroll
  for (int rh = 0; rh < 2; ++rh) {
#pragma unroll
    for (int rr = 0; rr < 4; ++rr) {
      int r = rh * 4 + rr;
      int m = bm + rh * 64 + ty * 4 + rr;
      if (by < 4) {
#pragma unroll
        for (int ch = 0; ch < 2; ++ch) {
          float o0[4], o1[4];
#pragma unroll
          for (int cc = 0; cc < 4; ++cc) {
            float z = acc[r][ch * 4 + cc] + bias[cb + ch * 64 + tx * 4 + cc];
            float a = tanh_fast(z) * PI_F;
            float nr = rintf(a * INV_HARM_F) * HARM_F;
            if (fabsf(a - nr) < TOL_F) a = nr;
            float sn, cs;
            sincos_poly(a, &sn, &cs);
            o0[cc] = cs;
            o1[cc] = sn;
          }
          float* cp = cosO + (size_t)m * 512 + cb + ch * 64 + tx * 4;
          float* sp = sinO + (size_t)m * 512 + cb + ch * 64 + tx * 4;
          *(float4*)cp = make_float4(o0[0], o0[1], o0[2], o0[3]);
          *(float4*)sp = make_float4(o1[0], o1[1], o1[2], o1[3]);
        }
      } else {
#pragma unroll
        for (int ch = 0; ch < 2; ++ch) {
          float o0[4];
#pragma unroll
          for (int cc = 0; cc < 4; ++cc) {
            float z = acc[r][ch * 4 + cc] + bias[cb + ch * 64 + tx * 4 + cc];
            o0[cc] = sigmoid_fast(z);
          }
          float* gp = sigO + (size_t)m * 512 + cb + ch * 64 + tx * 4;
          *(float4*)gp = make_float4(o0[0], o0[1], o0[2], o0[3]);
        }
      }
    }
  }
}

// K3: toroidal scan (unchanged)
__global__ void k_scan(const float* __restrict__ cosb, const float* __restrict__ sinb,
                       const float* __restrict__ sigb, float* __restrict__ xmoe,
                       float* __restrict__ nstate) {
  int gid = blockIdx.x * 64 + threadIdx.x;
  size_t b = gid >> 9, c = gid & 511;
  size_t base = (b * 2048) * 512 + c;
  float state = 0.f;
  float C0[8], S0[8], G0[8], C1[8], S1[8], G1[8];
  float C2[8], S2[8], G2[8], C3[8], S3[8], G3[8];
#define LOADB(CB, SB, GB, blk)                                                  \
  {                                                                             \
    int bb = (blk) < 255 ? (blk) : 255;                                         \
    size_t o = base + (size_t)bb * 8 * 512;                                     \
    _Pragma("unroll") for (int j = 0; j < 8; ++j) {                             \
      size_t oo = o + (size_t)j * 512;                                          \
      CB[j] = cosb[oo]; SB[j] = sinb[oo]; GB[j] = sigb[oo];                     \
    }                                                                           \
  }
#define COMPB(CB, SB, GB, blk)                                                  \
  {                                                                             \
    size_t o = base + (size_t)(blk)*8 * 512;                                    \
    _Pragma("unroll") for (int j = 0; j < 8; ++j) {                             \
      float st = fmaf(SB[j], state, -SB[j]);                                    \
      st = fmaf(CB[j], state, st);                                              \
      st = fminf(1.f, fmaxf(-1.f, st));                                         \
      state = st;                                                               \
      xmoe[o + (size_t)j * 512] = GB[j] * st;                                   \
    }                                                                           \
  }
  LOADB(C0, S0, G0, 0);
  LOADB(C1, S1, G1, 1);
  LOADB(C2, S2, G2, 2);
  for (int i = 0; i < 64; ++i) {
    LOADB(C3, S3, G3, 4 * i + 3);
    COMPB(C0, S0, G0, 4 * i);
    LOADB(C0, S0, G0, 4 * i + 4);
    COMPB(C1, S1, G1, 4 * i + 1);
    LOADB(C1, S1, G1, 4 * i + 5);
    COMPB(C2, S2, G2, 4 * i + 2);
    LOADB(C2, S2, G2, 4 * i + 6);
    COMPB(C3, S3, G3, 4 * i + 3);
  }
  nstate[gid] = state;
}

// K4: gate logits + softmax + top2 (unchanged)
__global__ __launch_bounds__(256) void k_gate(const float* __restrict__ xmoe,
                                              const float* __restrict__ gw_g,
                                              const float* __restrict__ gb,
                                              int* __restrict__ e01p,
                                              unsigned* __restrict__ w01p) {
  __shared__ float gw[4096];
  int tid = threadIdx.x;
  for (int i = tid; i < 4096; i += 256) gw[i] = gw_g[i];
  __syncthreads();
  int tok = blockIdx.x * 32 + (tid >> 3);
  int e = tid & 7;
  float acc = gb[e];
  const float4* xr = (const float4*)(xmoe + (size_t)tok * 512);
  for (int k4 = 0; k4 < 128; ++k4) {
    float4 x = xr[k4];
    acc += x.x * gw[(k4 * 4 + 0) * 8 + e];
    acc += x.y * gw[(k4 * 4 + 1) * 8 + e];
    acc += x.z * gw[(k4 * 4 + 2) * 8 + e];
    acc += x.w * gw[(k4 * 4 + 3) * 8 + e];
  }
  float m = acc;
  m = fmaxf(m, __shfl_xor(m, 1));
  m = fmaxf(m, __shfl_xor(m, 2));
  m = fmaxf(m, __shfl_xor(m, 4));
  float p = expf(acc - m);
  float ss = p;
  ss += __shfl_xor(ss, 1); ss += __shfl_xor(ss, 2); ss += __shfl_xor(ss, 4);
  p /= ss;
  float v1 = p; int i1 = e;
  {
    float ov; int oi;
    ov = __shfl_xor(v1, 1); oi = __shfl_xor(i1, 1);
    if (ov > v1 || (ov == v1 && oi < i1)) { v1 = ov; i1 = oi; }
    ov = __shfl_xor(v1, 2); oi = __shfl_xor(i1, 2);
    if (ov > v1 || (ov == v1 && oi < i1)) { v1 = ov; i1 = oi; }
    ov = __shfl_xor(v1, 4); oi = __shfl_xor(i1, 4);
    if (ov > v1 || (ov == v1 && oi < i1)) { v1 = ov; i1 = oi; }
  }
  float v2 = (e == i1) ? -1.f : p; int i2 = e;
  {
    float ov; int oi;
    ov = __shfl_xor(v2, 1); oi = __shfl_xor(i2, 1);
    if (ov > v2 || (ov == v2 && oi < i2)) { v2 = ov; i2 = oi; }
    ov = __shfl_xor(v2, 2); oi = __shfl_xor(i2, 2);
    if (ov > v2 || (ov == v2 && oi < i2)) { v2 = ov; i2 = oi; }
    ov = __shfl_xor(v2, 4); oi = __shfl_xor(i2, 4);
    if (ov > v2 || (ov == v2 && oi < i2)) { v2 = ov; i2 = oi; }
  }
  if (e == 0) {
    float s2 = v1 + v2;
    __half h1 = __float2half(v1 / s2), h2 = __float2half(v2 / s2);
    e01p[tok] = i1 | (i2 << 8);
    w01p[tok] = (unsigned)__half_as_ushort(h1) | ((unsigned)__half_as_ushort(h2) << 16);
  }
}

// K6: counts -> eoff -> scatter -> tmap (unchanged)
__global__ void k_build(const int* __restrict__ e01p, const unsigned* __restrict__ w01p,
                        int* __restrict__ list, float* __restrict__ wlist,
                        int* __restrict__ counts, int* __restrict__ eoff,
                        int* __restrict__ tokpos, int* __restrict__ tmap) {
  __shared__ int cnt[8], cur[8];
  int tid = threadIdx.x, lane = tid & 63;
  if (tid < 8) cnt[tid] = 0;
  __syncthreads();
  for (int i = tid; i < 16384; i += 256) {
    int tok = i >> 1, j = i & 1;
    int ee = (e01p[tok] >> (8 * j)) & 255;
#pragma unroll
    for (int x = 0; x < 8; ++x) {
      unsigned long long m = __ballot(ee == x);
      if (m != 0ull && lane == (__ffsll((long long)m) - 1)) atomicAdd(&cnt[x], __popcll(m));
    }
  }
  __syncthreads();
  if (tid == 0) {
    int s = 0;
#pragma unroll
    for (int x = 0; x < 8; ++x) {
      cur[x] = s; eoff[x] = s; counts[x] = cnt[x]; s += cnt[x];
    }
  }
  __syncthreads();
  for (int i = tid; i < 272; i += 256) tmap[i] = -1;
  __syncthreads();
  if (tid == 0) {
    int ntiles = 0, tstart[8];
#pragma unroll
    for (int e = 0; e < 8; ++e) { tstart[e] = ntiles; ntiles += (cnt[e] + 63) >> 6; }
    int q = ntiles >> 3, r = ntiles & 7;
    for (int e = 0; e < 8; ++e) {
      int nt = (cnt[e] + 63) >> 6;
      for (int t = 0; t < nt; ++t) {
        int k = tstart[e] + t;
        int c, o;
        if (k < r * (q + 1)) { c = k / (q + 1); o = k - c * (q + 1); }
        else { int k2 = k - r * (q + 1); c = r + k2 / q; o = k2 - (k2 / q) * q; }
        tmap[8 * o + c] = (e << 16) | t;
      }
    }
  }
  __syncthreads();
  for (int i = tid; i < 16384; i += 256) {
    int tok = i >> 1, j = i & 1;
    int ee = (e01p[tok] >> (8 * j)) & 255;
    unsigned wp = w01p[tok];
    unsigned short us = (unsigned short)(j ? (wp >> 16) : (wp & 0xFFFFu));
    float w = __half2float(__ushort_as_half(us));
    int pos = 0;
#pragma unroll
    for (int x = 0; x < 8; ++x) {
      unsigned long long m = __ballot(ee == x);
      if (m == 0ull) continue;
      int leader = __ffsll((long long)m) - 1;
      int bb = 0;
      if (lane == leader) bb = atomicAdd(&cur[x], __popcll(m));
      bb = __shfl(bb, leader);
      if (ee == x) pos = bb + __popcll(m & ((1ull << lane) - 1ull));
    }
    list[pos] = tok;
    wlist[pos] = w;
    tokpos[i] = pos;
  }
}

// ---------------------------------------------------------------------------
// K7 v3.1: fused MoE FFN (r8 structure; unroll 4->8 on weight-load loops)
// ---------------------------------------------------------------------------
#define HS_OFF 65536

__global__ __launch_bounds__(512, 2) void k_ffn(
    const float* __restrict__ xmoe, const int* __restrict__ list,
    const float* __restrict__ wlist, const int* __restrict__ counts,
    const int* __restrict__ eoff, const int* __restrict__ tmap,
    const unsigned short* __restrict__ W1Pk, const float* __restrict__ b1g,
    const unsigned short* __restrict__ W2Pk, const float* __restrict__ b2g,
    unsigned short* __restrict__ Yb) {
  int mp = tmap[blockIdx.x];
  if (mp < 0) return;
  int e = mp >> 16, tile = mp & 0xFFFF;
  int cnt = counts[e];
  int base = eoff[e] + tile * 64;
  int valid = cnt - tile * 64;
  if (valid > 64) valid = 64;
  __shared__ __align__(16) char smem[131072];
  __shared__ int toks[64];
  __shared__ float wts[64];
  int tid = threadIdx.x;
  int w = tid >> 6, l = tid & 63;
  int l31 = l & 31, hi = l >> 5;
  if (tid < 64) {
    int idx = tile * 64 + tid;
    bool v = idx < cnt;
    toks[tid] = list[eoff[e] + (v ? idx : 0)];
    wts[tid] = v ? wlist[eoff[e] + idx] : 0.f;
  }
  __syncthreads();
#pragma unroll
  for (int s = 0; s < 8; ++s) {
    int sl = s * 512 + tid;
    int ent = sl >> 6, ll = sl & 63;
    int ks = ent >> 1, t2 = ent & 1;
    int tok = toks[t2 * 32 + (ll & 31)];
    const float* src = xmoe + (size_t)tok * 512 + ks * 16 + (ll >> 5) * 8;
    float4 v0 = *(const float4*)src;
    float4 v1 = *(const float4*)(src + 4);
    u32x4 u;
    u.x = (unsigned)f2bf(v0.x) | ((unsigned)f2bf(v0.y) << 16);
    u.y = (unsigned)f2bf(v0.z) | ((unsigned)f2bf(v0.w) << 16);
    u.z = (unsigned)f2bf(v1.x) | ((unsigned)f2bf(v1.y) << 16);
    u.w = (unsigned)f2bf(v1.z) | ((unsigned)f2bf(v1.w) << 16);
    *(u32x4*)(smem + ent * 1024 + ll * 16) = u;
  }
  f32x16 acc00, acc01, acc10, acc11;
#pragma unroll
  for (int i = 0; i < 16; ++i) { acc00[i] = 0.f; acc01[i] = 0.f; acc10[i] = 0.f; acc11[i] = 0.f; }
  __syncthreads();

  const size_t dstE1 = (size_t)64 * 32 * 512;
  const size_t dstE2 = (size_t)16 * 128 * 512;
  for (int it = 0; it < 4; ++it) {
    f32x16 z00, z01, z10, z11;
#pragma unroll
    for (int i = 0; i < 16; ++i) { z00[i] = 0.f; z01[i] = 0.f; z10[i] = 0.f; z11[i] = 0.f; }
    const unsigned short* w1a =
        W1Pk + (size_t)e * dstE1 + ((size_t)(it * 16 + w * 2) * 32) * 512 + l * 8;
    const unsigned short* w1b = w1a + (size_t)32 * 512;
#pragma unroll 8
    for (int ks = 0; ks < 32; ++ks) {
      bf16x8 a0 = *(const bf16x8*)(w1a + (size_t)ks * 512);
      bf16x8 a1 = *(const bf16x8*)(w1b + (size_t)ks * 512);
      bf16x8 b0 = ld_frag(smem + (ks * 2 + 0) * 1024 + l * 16);
      bf16x8 b1 = ld_frag(smem + (ks * 2 + 1) * 1024 + l * 16);
      z00 = __builtin_amdgcn_mfma_f32_32x32x16_bf16(a0, b0, z00, 0, 0, 0);
      z01 = __builtin_amdgcn_mfma_f32_32x32x16_bf16(a0, b1, z01, 0, 0, 0);
      z10 = __builtin_amdgcn_mfma_f32_32x32x16_bf16(a1, b0, z10, 0, 0, 0);
      z11 = __builtin_amdgcn_mfma_f32_32x32x16_bf16(a1, b1, z11, 0, 0, 0);
    }
#define GELU_STORE(Z, JF, T2)                                                   \
  {                                                                             \
    _Pragma("unroll") for (int rq = 0; rq < 4; ++rq) {                          \
      int fb = (w * 2 + (JF)) * 32 + 8 * rq + 4 * hi;                           \
      float4 bv = *(const float4*)(b1g + e * 2048 + it * 512 + fb);             \
      float g0 = gelu_tanh(Z[4 * rq + 0] + bv.x);                               \
      float g1 = gelu_tanh(Z[4 * rq + 1] + bv.y);                               \
      float g2 = gelu_tanh(Z[4 * rq + 2] + bv.z);                               \
      float g3 = gelu_tanh(Z[4 * rq + 3] + bv.w);                               \
      u32x2 p;                                                                  \
      p.x = (unsigned)f2bf(g0) | ((unsigned)f2bf(g1) << 16);                    \
      p.y = (unsigned)f2bf(g2) | ((unsigned)f2bf(g3) << 16);                    \
      int ent = ((w * 2 + (JF)) * 2 + (rq >> 1)) * 2 + (T2);                    \
      int lanep = l31 + 32 * (rq & 1);                                          \
      *(u32x2*)(smem + HS_OFF + ent * 1024 + lanep * 16 + hi * 8) = p;          \
    }                                                                           \
  }
    GELU_STORE(z00, 0, 0)
    GELU_STORE(z01, 0, 1)
    GELU_STORE(z10, 1, 0)
    GELU_STORE(z11, 1, 1)
    __syncthreads();
    const unsigned short* w2a =
        W2Pk + (size_t)e * dstE2 + ((size_t)(w * 2) * 128 + it * 32) * 512 + l * 8;
    const unsigned short* w2b = w2a + (size_t)128 * 512;
#pragma unroll 8
    for (int fs = 0; fs < 32; ++fs) {
      bf16x8 a0 = *(const bf16x8*)(w2a + (size_t)fs * 512);
      bf16x8 a1 = *(const bf16x8*)(w2b + (size_t)fs * 512);
      bf16x8 h0 = ld_frag(smem + HS_OFF + (fs * 2 + 0) * 1024 + l * 16);
      bf16x8 h1 = ld_frag(smem + HS_OFF + (fs * 2 + 1) * 1024 + l * 16);
      acc00 = __builtin_amdgcn_mfma_f32_32x32x16_bf16(a0, h0, acc00, 0, 0, 0);
      acc01 = __builtin_amdgcn_mfma_f32_32x32x16_bf16(a0, h1, acc01, 0, 0, 0);
      acc10 = __builtin_amdgcn_mfma_f32_32x32x16_bf16(a1, h0, acc10, 0, 0, 0);
      acc11 = __builtin_amdgcn_mfma_f32_32x32x16_bf16(a1, h1, acc11, 0, 0, 0);
    }
    __syncthreads();
  }
#define EPI_STORE(ACC, JC, T2)                                                  \
  {                                                                             \
    _Pragma("unroll") for (int rq = 0; rq < 4; ++rq) {                          \
      int c0 = (w * 2 + (JC)) * 32 + 8 * rq + 4 * hi;                           \
      float4 b2v = *(const float4*)(b2g + e * 512 + c0);                        \
      int tok = (T2)*32 + l31;                                                  \
      float wt = wts[tok];                                                      \
      u32x2 p;                                                                  \
      p.x = (unsigned)f2bf((ACC[4 * rq + 0] + b2v.x) * wt) |                    \
            ((unsigned)f2bf((ACC[4 * rq + 1] + b2v.y) * wt) << 16);             \
      p.y = (unsigned)f2bf((ACC[4 * rq + 2] + b2v.z) * wt) |                    \
            ((unsigned)f2bf((ACC[4 * rq + 3] + b2v.w) * wt) << 16);             \
      *(u32x2*)(smem + tok * 1024 + ((c0 * 2) ^ ((tok & 7) << 4))) = p;         \
    }                                                                           \
  }
  EPI_STORE(acc00, 0, 0)
  EPI_STORE(acc01, 0, 1)
  EPI_STORE(acc10, 1, 0)
  EPI_STORE(acc11, 1, 1)
  __syncthreads();
#pragma unroll
  for (int s = 0; s < 8; ++s) {
    int i = tid + s * 512;
    int row = i >> 6, g = i & 63;
    if (row < valid) {
      u32x4 v = *(u32x4*)(smem + row * 1024 + ((g * 16) ^ ((row & 7) << 4)));
      *(u32x4*)(Yb + (size_t)(base + row) * 512 + g * 8) = v;
    }
  }
}

// ---------------------------------------------------------------------------
// K8: head bf16 MFMA GEMM (unchanged)
// ---------------------------------------------------------------------------
__global__ __launch_bounds__(256) void k_head(const unsigned short* __restrict__ Yb,
                                              const int* __restrict__ tokpos,
                                              const unsigned short* __restrict__ headPk,
                                              const float* __restrict__ headB,
                                              float* __restrict__ out) {
  __shared__ __align__(16) char As[16384];
  __shared__ int tp[256];
  int tid = threadIdx.x;
  int w = tid >> 6, l = tid & 63;
  int l31 = l & 31, hi = l >> 5;
  int mg = w & 1, ng = w >> 1;
  int bm = blockIdx.x * 128, by = blockIdx.y;
  tp[tid] = tokpos[bm * 2 + tid];
  f32x16 acc00, acc01, acc10, acc11;
#pragma unroll
  for (int i = 0; i < 16; ++i) { acc00[i] = 0.f; acc01[i] = 0.f; acc10[i] = 0.f; acc11[i] = 0.f; }
  int nblk0 = by * 4 + ng * 2;
  __syncthreads();
  for (int kb = 0; kb < 8; ++kb) {
#pragma unroll
    for (int s = 0; s < 4; ++s) {
      int i = tid + s * 256;
      int row = i >> 3, g = i & 7;
      int p1 = tp[row * 2], p2 = tp[row * 2 + 1];
      u32x4 va = *(const u32x4*)(Yb + (size_t)p1 * 512 + kb * 64 + g * 8);
      u32x4 vb = *(const u32x4*)(Yb + (size_t)p2 * 512 + kb * 64 + g * 8);
      u32x4 o;
      o.x = (unsigned)f2bf(bflo(va.x) + bflo(vb.x)) | ((unsigned)f2bf(bfhi(va.x) + bfhi(vb.x)) << 16);
      o.y = (unsigned)f2bf(bflo(va.y) + bflo(vb.y)) | ((unsigned)f2bf(bfhi(va.y) + bfhi(vb.y)) << 16);
      o.z = (unsigned)f2bf(bflo(va.z) + bflo(vb.z)) | ((unsigned)f2bf(bfhi(va.z) + bfhi(vb.z)) << 16);
      o.w = (unsigned)f2bf(bflo(va.w) + bflo(vb.w)) | ((unsigned)f2bf(bfhi(va.w) + bfhi(vb.w)) << 16);
      *(u32x4*)(As + row * 128 + ((g * 16) ^ ((row & 7) << 4))) = o;
    }
    __syncthreads();
#pragma unroll
    for (int ks = 0; ks < 4; ++ks) {
      int r0 = mg * 64 + l31, r1 = r0 + 32;
      int kbyte = ks * 32 + hi * 16;
      bf16x8 a0 = ld_frag(As + r0 * 128 + (kbyte ^ ((r0 & 7) << 4)));
      bf16x8 a1 = ld_frag(As + r1 * 128 + (kbyte ^ ((r1 & 7) << 4)));
      const unsigned short* hp = headPk + ((size_t)nblk0 * 32 + kb * 4 + ks) * 512 + l * 8;
      bf16x8 b0 = *(const bf16x8*)hp;
      bf16x8 b1 = *(const bf16x8*)(hp + 32 * 512);
      acc00 = __builtin_amdgcn_mfma_f32_32x32x16_bf16(a0, b0, acc00, 0, 0, 0);
      acc01 = __builtin_amdgcn_mfma_f32_32x32x16_bf16(a0, b1, acc01, 0, 0, 0);
      acc10 = __builtin_amdgcn_mfma_f32_32x32x16_bf16(a1, b0, acc10, 0, 0, 0);
      acc11 = __builtin_amdgcn_mfma_f32_32x32x16_bf16(a1, b1, acc11, 0, 0, 0);
    }
    __syncthreads();
  }
#pragma unroll
  for (int mf = 0; mf < 2; ++mf) {
#pragma unroll
    for (int nf = 0; nf < 2; ++nf) {
      int nc = by * 128 + ng * 64 + nf * 32 + l31;
      float hb = headB[nc];
#pragma unroll
      for (int r = 0; r < 16; ++r) {
        int m = bm + mg * 64 + mf * 32 + (r & 3) + 8 * (r >> 2) + 4 * hi;
        float v;
        if (mf == 0) v = (nf == 0) ? acc00[r] : acc01[r];
        else         v = (nf == 0) ? acc10[r] : acc11[r];
        out[(size_t)m * 256 + nc] = v + hb;
      }
    }
  }
}

extern "C" void kernel_launch(void* const* d_in, const int* in_sizes, int n_in,
                              void* d_out, int out_size, void* d_ws, size_t ws_size,
                              hipStream_t stream) {
  (void)in_sizes; (void)n_in; (void)out_size; (void)ws_size;
  const int* seq     = (const int*)d_in[0];
  const float* emb   = (const float*)d_in[1];
  const float* phi_w = (const float*)d_in[2];
  const float* phi_b = (const float*)d_in[3];
  const float* amp_w = (const float*)d_in[4];
  const float* amp_b = (const float*)d_in[5];
  const float* gate_w = (const float*)d_in[6];
  const float* gate_b = (const float*)d_in[7];
  const float* w1 = (const float*)d_in[8];
  const float* b1 = (const float*)d_in[9];
  const float* w2 = (const float*)d_in[10];
  const float* b2 = (const float*)d_in[11];
  const float* head_w = (const float*)d_in[12];
  const float* head_b = (const float*)d_in[13];
  float* out = (float*)d_out;

  char* ws = (char*)d_ws;
  const size_t BUF = 16777216;
  float* X    = (float*)(ws);                         // X -> xmoe (in place)
  float* COSb = (float*)(ws + BUF);                   // cos -> Yb (bf16)
  float* SINb = (float*)(ws + 2 * BUF);               // sin -> W1Pk (bf16)
  float* SIGb = (float*)(ws + 3 * BUF);               // sig -> W2Pk (bf16)
  unsigned short* Yb   = (unsigned short*)COSb;
  unsigned short* W1Pk = (unsigned short*)SINb;
  unsigned short* W2Pk = (unsigned short*)SIGb;
  char* sm = ws + 4 * BUF;
  int*      e01p   = (int*)(sm);                      // 32KB
  unsigned* w01p   = (unsigned*)(sm + 32768);         // 32KB
  int*      list   = (int*)(sm + 65536);              // 64KB
  float*    wlist  = (float*)(sm + 131072);           // 64KB
  int*      tokpos = (int*)(sm + 196608);             // 64KB
  int*      counts = (int*)(sm + 262144);
  int*      eoff   = (int*)(sm + 262144 + 64);
  unsigned short* headPk = (unsigned short*)(sm + 266240);  // 256KB
  int*      tmap   = (int*)(sm + 266240 + 262144);          // 272 ints

  k_embed<<<4096, 256, 0, stream>>>(seq, emb, X);
  k_pack_b<<<dim3(8, 1, 1), 256, 0, stream>>>(head_w, 256, 0, headPk, 0, 32);
  k_phi<<<dim3(64, 8), 256, 0, stream>>>(X, phi_w, phi_b, amp_w, amp_b, COSb, SINb, SIGb);
  k_scan<<<32, 64, 0, stream>>>(COSb, SINb, SIGb, X, out + 2097152);
  k_pack_b<<<dim3(64, 1, 8), 256, 0, stream>>>(w1, 2048, (size_t)512 * 2048, W1Pk,
                                               (size_t)64 * 32 * 512, 32);
  k_pack_b<<<dim3(16, 4, 8), 256, 0, stream>>>(w2, 512, (size_t)2048 * 512, W2Pk,
                                               (size_t)16 * 128 * 512, 128);
  k_gate<<<256, 256, 0, stream>>>(X, gate_w, gate_b, e01p, w01p);
  k_build<<<1, 256, 0, stream>>>(e01p, w01p, list, wlist, counts, eoff, tokpos, tmap);
  k_ffn<<<272, 512, 0, stream>>>(X, list, wlist, counts, eoff, tmap,
                                 W1Pk, b1, W2Pk, b2, Yb);
  k_head<<<dim3(64, 2), 256, 0, stream>>>(Yb, tokpos, headPk, head_b, out);
}

// Round 10
// 579.792 us; speedup vs baseline: 1.2876x; 1.1476x over previous
//
#include <hip/hip_runtime.h>
#include <hip/hip_fp16.h>
#include <math.h>

// ---------------------------------------------------------------------------
// SovereignLeviathanV2  round 10 = round 9 with k_ffn on 96-token tiles:
//  - weight traffic/block amortized over 1.5x tokens (1.05GB -> 0.70GB total)
//  - <=178 tiles -> single dispatch round on 256 CUs
//  - 8 waves: GEMM1 f-split 32f/wave (strip 256f, z=3xf32x16);
//    GEMM2 c-split 64c/wave (acc=6xf32x16); 3 token-frags
//  - LDS: Xs 96KB + Hs 48KB = 147KB, frag-packed lane-linear (conflict-free)
// Everything else byte-identical to the passing round-9 kernel.
// ---------------------------------------------------------------------------

#define PI_F 3.14159265358979323846f
#define HARM_F 1.04719755119659774615f
#define INV_HARM_F 0.95492965855137201461f
#define TOL_F 0.15f

typedef float f32x16 __attribute__((ext_vector_type(16)));
typedef __bf16 bf16x8 __attribute__((ext_vector_type(8)));
typedef unsigned int u32x4 __attribute__((ext_vector_type(4)));
typedef unsigned int u32x2 __attribute__((ext_vector_type(2)));

__device__ __forceinline__ float gelu_tanh(float x) {
  float x3 = x * x * x;
  return 0.5f * x * (1.f + tanhf(0.79788456080286535588f * (x + 0.044715f * x3)));
}
__device__ __forceinline__ unsigned short f2bf(float x) {
  unsigned u = __float_as_uint(x);
  unsigned r = (u + 0x7FFFu + ((u >> 16) & 1u)) >> 16;
  return (unsigned short)r;
}
__device__ __forceinline__ float bflo(unsigned u) { return __uint_as_float(u << 16); }
__device__ __forceinline__ float bfhi(unsigned u) { return __uint_as_float(u & 0xFFFF0000u); }
__device__ __forceinline__ bf16x8 ld_frag(const void* p) {
  u32x4 v = *(const u32x4*)p;
  return __builtin_bit_cast(bf16x8, v);
}

__device__ __forceinline__ float tanh_fast(float z) {
  float zc = fminf(10.f, fmaxf(-10.f, z));
  float e2 = __expf(zc + zc);
  return (e2 - 1.f) / (e2 + 1.f);
}
__device__ __forceinline__ float sigmoid_fast(float z) {
  return 1.f / (1.f + __expf(-z));
}
__device__ __forceinline__ void sincos_poly(float a, float* sn, float* cs) {
  float q = rintf(a * 0.63661977236758134f);
  int iq = (int)q;
  float t = fmaf(-q, 1.57079637050628662f, a);
  t = fmaf(q, 4.37113883e-8f, t);
  float t2 = t * t;
  float sp = t * fmaf(t2, fmaf(t2, fmaf(t2, -1.9515296e-4f, 8.3321609e-3f),
                               -1.6666654e-1f), 1.f);
  float cp = fmaf(t2 * t2,
                  fmaf(t2, fmaf(t2, 2.4433158e-5f, -1.3887316e-3f), 4.1666646e-2f),
                  fmaf(t2, -0.5f, 1.f));
  int m = iq & 3;
  bool swap = (m & 1) != 0;
  float ss = swap ? cp : sp;
  float cc = swap ? sp : cp;
  *sn = (m & 2) ? -ss : ss;
  *cs = ((m + 1) & 2) ? -cc : cc;
}

// K1: X[n][c] = emb[seq[n]][c]
__global__ void k_embed(const int* __restrict__ seq, const float* __restrict__ emb,
                        float* __restrict__ X) {
  int i = blockIdx.x * 256 + threadIdx.x;
  int n = i >> 7, c4 = i & 127;
  int tok = seq[n];
  ((float4*)X)[(size_t)n * 128 + c4] = ((const float4*)emb)[(size_t)tok * 128 + c4];
}

// ---------------------------------------------------------------------------
// Generic B-operand frag pack (unchanged)
// ---------------------------------------------------------------------------
__global__ __launch_bounds__(256) void k_pack_b(const float* __restrict__ src, int ld,
                                                size_t srcE, unsigned short* __restrict__ dst,
                                                size_t dstE, int fragKtot) {
  __shared__ float Ls[512 * 33];
  int nb = blockIdx.x, kseg = blockIdx.y, e = blockIdx.z;
  const float* s = src + (size_t)e * srcE + (size_t)kseg * 512 * ld + nb * 32;
  unsigned short* d = dst + (size_t)e * dstE + ((size_t)(nb * fragKtot + kseg * 32)) * 512;
  int tid = threadIdx.x;
#pragma unroll
  for (int q = 0; q < 16; ++q) {
    int i = tid + q * 256;
    int row = i >> 3, c4 = i & 7;
    float4 v = *(const float4*)(s + (size_t)row * ld + c4 * 4);
    Ls[row * 33 + c4 * 4 + 0] = v.x;
    Ls[row * 33 + c4 * 4 + 1] = v.y;
    Ls[row * 33 + c4 * 4 + 2] = v.z;
    Ls[row * 33 + c4 * 4 + 3] = v.w;
  }
  __syncthreads();
#pragma unroll
  for (int q = 0; q < 8; ++q) {
    int i = tid + q * 256;
    int ks = i >> 6, l = i & 63;
    int col = l & 31, kb = (l >> 5) * 8 + ks * 16;
    u32x4 o;
    o.x = (unsigned)f2bf(Ls[(kb + 0) * 33 + col]) | ((unsigned)f2bf(Ls[(kb + 1) * 33 + col]) << 16);
    o.y = (unsigned)f2bf(Ls[(kb + 2) * 33 + col]) | ((unsigned)f2bf(Ls[(kb + 3) * 33 + col]) << 16);
    o.z = (unsigned)f2bf(Ls[(kb + 4) * 33 + col]) | ((unsigned)f2bf(Ls[(kb + 5) * 33 + col]) << 16);
    o.w = (unsigned)f2bf(Ls[(kb + 6) * 33 + col]) | ((unsigned)f2bf(Ls[(kb + 7) * 33 + col]) << 16);
    *(u32x4*)(d + (size_t)ks * 512 + l * 8) = o;
  }
}

// ---------------------------------------------------------------------------
// K2: fused phi+amp fp32 GEMM (unchanged from round 9, call-free epilogue)
// ---------------------------------------------------------------------------
__global__ __launch_bounds__(256, 2) void k_phi(const float* __restrict__ A,
                                                const float* __restrict__ phiW,
                                                const float* __restrict__ phiB,
                                                const float* __restrict__ ampW,
                                                const float* __restrict__ ampB,
                                                float* __restrict__ cosO,
                                                float* __restrict__ sinO,
                                                float* __restrict__ sigO) {
  __shared__ float As[2][16 * 132];
  __shared__ float Bs[2][16 * 132];
  int tid = threadIdx.x;
  int tx = tid & 15, ty = tid >> 4;
  int bm = blockIdx.x * 128;
  int by = blockIdx.y;
  const float* Bsrc = (by < 4) ? phiW : ampW;
  const float* bias = (by < 4) ? phiB : ampB;
  int cb = (by & 3) * 128;
  float acc[8][8];
#pragma unroll
  for (int r = 0; r < 8; ++r)
#pragma unroll
    for (int c = 0; c < 8; ++c) acc[r][c] = 0.f;

#define STAGE_PHI(BUF, KT)                                                     \
  {                                                                            \
    _Pragma("unroll") for (int s = 0; s < 2; ++s) {                            \
      int i = tid + s * 256;                                                   \
      int row = i >> 2, kq = i & 3;                                            \
      float4 v = *(const float4*)(A + (size_t)(bm + row) * 512 + (KT)*16 + kq * 4); \
      As[BUF][(kq * 4 + 0) * 132 + row] = v.x;                                 \
      As[BUF][(kq * 4 + 1) * 132 + row] = v.y;                                 \
      As[BUF][(kq * 4 + 2) * 132 + row] = v.z;                                 \
      As[BUF][(kq * 4 + 3) * 132 + row] = v.w;                                 \
    }                                                                          \
    _Pragma("unroll") for (int s = 0; s < 2; ++s) {                            \
      int i = tid + s * 256;                                                   \
      int kk = i >> 5, g = i & 31;                                             \
      float4 v = *(const float4*)(Bsrc + (size_t)((KT)*16 + kk) * 512 + cb + g * 4); \
      *(float4*)(&Bs[BUF][kk * 132 + g * 4]) = v;                              \
    }                                                                          \
  }

  STAGE_PHI(0, 0);
  for (int kt = 0; kt < 32; ++kt) {
    __syncthreads();
    if (kt + 1 < 32) {
      if ((kt & 1) == 0) STAGE_PHI(1, kt + 1) else STAGE_PHI(0, kt + 1)
    }
    const float* Ab = As[kt & 1];
    const float* Bb = Bs[kt & 1];
#pragma unroll
    for (int kk = 0; kk < 16; ++kk) {
      float4 a0 = *(const float4*)(&Ab[kk * 132 + ty * 4]);
      float4 a1 = *(const float4*)(&Ab[kk * 132 + 64 + ty * 4]);
      float4 b0 = *(const float4*)(&Bb[kk * 132 + tx * 4]);
      float4 b1 = *(const float4*)(&Bb[kk * 132 + 64 + tx * 4]);
      float ar[8] = {a0.x, a0.y, a0.z, a0.w, a1.x, a1.y, a1.z, a1.w};
      float br[8] = {b0.x, b0.y, b0.z, b0.w, b1.x, b1.y, b1.z, b1.w};
#pragma unroll
      for (int r = 0; r < 8; ++r)
#pragma unroll
        for (int c = 0; c < 8; ++c) acc[r][c] = fmaf(ar[r], br[c], acc[r][c]);
    }
  }
#pragma unroll
  for (int rh = 0; rh < 2; ++rh) {
#pragma unroll
    for (int rr = 0; rr < 4; ++rr) {
      int r = rh * 4 + rr;
      int m = bm + rh * 64 + ty * 4 + rr;
      if (by < 4) {
#pragma unroll
        for (int ch = 0; ch < 2; ++ch) {
          float o0[4], o1[4];
#pragma unroll
          for (int cc = 0; cc < 4; ++cc) {
            float z = acc[r][ch * 4 + cc] + bias[cb + ch * 64 + tx * 4 + cc];
            float a = tanh_fast(z) * PI_F;
            float nr = rintf(a * INV_HARM_F) * HARM_F;
            if (fabsf(a - nr) < TOL_F) a = nr;
            float sn, cs;
            sincos_poly(a, &sn, &cs);
            o0[cc] = cs;
            o1[cc] = sn;
          }
          float* cp = cosO + (size_t)m * 512 + cb + ch * 64 + tx * 4;
          float* sp = sinO + (size_t)m * 512 + cb + ch * 64 + tx * 4;
          *(float4*)cp = make_float4(o0[0], o0[1], o0[2], o0[3]);
          *(float4*)sp = make_float4(o1[0], o1[1], o1[2], o1[3]);
        }
      } else {
#pragma unroll
        for (int ch = 0; ch < 2; ++ch) {
          float o0[4];
#pragma unroll
          for (int cc = 0; cc < 4; ++cc) {
            float z = acc[r][ch * 4 + cc] + bias[cb + ch * 64 + tx * 4 + cc];
            o0[cc] = sigmoid_fast(z);
          }
          float* gp = sigO + (size_t)m * 512 + cb + ch * 64 + tx * 4;
          *(float4*)gp = make_float4(o0[0], o0[1], o0[2], o0[3]);
        }
      }
    }
  }
}

// K3: toroidal scan (unchanged)
__global__ void k_scan(const float* __restrict__ cosb, const float* __restrict__ sinb,
                       const float* __restrict__ sigb, float* __restrict__ xmoe,
                       float* __restrict__ nstate) {
  int gid = blockIdx.x * 64 + threadIdx.x;
  size_t b = gid >> 9, c = gid & 511;
  size_t base = (b * 2048) * 512 + c;
  float state = 0.f;
  float C0[8], S0[8], G0[8], C1[8], S1[8], G1[8];
  float C2[8], S2[8], G2[8], C3[8], S3[8], G3[8];
#define LOADB(CB, SB, GB, blk)                                                  \
  {                                                                             \
    int bb = (blk) < 255 ? (blk) : 255;                                         \
    size_t o = base + (size_t)bb * 8 * 512;                                     \
    _Pragma("unroll") for (int j = 0; j < 8; ++j) {                             \
      size_t oo = o + (size_t)j * 512;                                          \
      CB[j] = cosb[oo]; SB[j] = sinb[oo]; GB[j] = sigb[oo];                     \
    }                                                                           \
  }
#define COMPB(CB, SB, GB, blk)                                                  \
  {                                                                             \
    size_t o = base + (size_t)(blk)*8 * 512;                                    \
    _Pragma("unroll") for (int j = 0; j < 8; ++j) {                             \
      float st = fmaf(SB[j], state, -SB[j]);                                    \
      st = fmaf(CB[j], state, st);                                              \
      st = fminf(1.f, fmaxf(-1.f, st));                                         \
      state = st;                                                               \
      xmoe[o + (size_t)j * 512] = GB[j] * st;                                   \
    }                                                                           \
  }
  LOADB(C0, S0, G0, 0);
  LOADB(C1, S1, G1, 1);
  LOADB(C2, S2, G2, 2);
  for (int i = 0; i < 64; ++i) {
    LOADB(C3, S3, G3, 4 * i + 3);
    COMPB(C0, S0, G0, 4 * i);
    LOADB(C0, S0, G0, 4 * i + 4);
    COMPB(C1, S1, G1, 4 * i + 1);
    LOADB(C1, S1, G1, 4 * i + 5);
    COMPB(C2, S2, G2, 4 * i + 2);
    LOADB(C2, S2, G2, 4 * i + 6);
    COMPB(C3, S3, G3, 4 * i + 3);
  }
  nstate[gid] = state;
}

// K4: gate logits + softmax + top2 (unchanged)
__global__ __launch_bounds__(256) void k_gate(const float* __restrict__ xmoe,
                                              const float* __restrict__ gw_g,
                                              const float* __restrict__ gb,
                                              int* __restrict__ e01p,
                                              unsigned* __restrict__ w01p) {
  __shared__ float gw[4096];
  int tid = threadIdx.x;
  for (int i = tid; i < 4096; i += 256) gw[i] = gw_g[i];
  __syncthreads();
  int tok = blockIdx.x * 32 + (tid >> 3);
  int e = tid & 7;
  float acc = gb[e];
  const float4* xr = (const float4*)(xmoe + (size_t)tok * 512);
  for (int k4 = 0; k4 < 128; ++k4) {
    float4 x = xr[k4];
    acc += x.x * gw[(k4 * 4 + 0) * 8 + e];
    acc += x.y * gw[(k4 * 4 + 1) * 8 + e];
    acc += x.z * gw[(k4 * 4 + 2) * 8 + e];
    acc += x.w * gw[(k4 * 4 + 3) * 8 + e];
  }
  float m = acc;
  m = fmaxf(m, __shfl_xor(m, 1));
  m = fmaxf(m, __shfl_xor(m, 2));
  m = fmaxf(m, __shfl_xor(m, 4));
  float p = expf(acc - m);
  float ss = p;
  ss += __shfl_xor(ss, 1); ss += __shfl_xor(ss, 2); ss += __shfl_xor(ss, 4);
  p /= ss;
  float v1 = p; int i1 = e;
  {
    float ov; int oi;
    ov = __shfl_xor(v1, 1); oi = __shfl_xor(i1, 1);
    if (ov > v1 || (ov == v1 && oi < i1)) { v1 = ov; i1 = oi; }
    ov = __shfl_xor(v1, 2); oi = __shfl_xor(i1, 2);
    if (ov > v1 || (ov == v1 && oi < i1)) { v1 = ov; i1 = oi; }
    ov = __shfl_xor(v1, 4); oi = __shfl_xor(i1, 4);
    if (ov > v1 || (ov == v1 && oi < i1)) { v1 = ov; i1 = oi; }
  }
  float v2 = (e == i1) ? -1.f : p; int i2 = e;
  {
    float ov; int oi;
    ov = __shfl_xor(v2, 1); oi = __shfl_xor(i2, 1);
    if (ov > v2 || (ov == v2 && oi < i2)) { v2 = ov; i2 = oi; }
    ov = __shfl_xor(v2, 2); oi = __shfl_xor(i2, 2);
    if (ov > v2 || (ov == v2 && oi < i2)) { v2 = ov; i2 = oi; }
    ov = __shfl_xor(v2, 4); oi = __shfl_xor(i2, 4);
    if (ov > v2 || (ov == v2 && oi < i2)) { v2 = ov; i2 = oi; }
  }
  if (e == 0) {
    float s2 = v1 + v2;
    __half h1 = __float2half(v1 / s2), h2 = __float2half(v2 / s2);
    e01p[tok] = i1 | (i2 << 8);
    w01p[tok] = (unsigned)__half_as_ushort(h1) | ((unsigned)__half_as_ushort(h2) << 16);
  }
}

// K6: counts -> eoff -> scatter -> tmap (tile size 96 now)
__global__ void k_build(const int* __restrict__ e01p, const unsigned* __restrict__ w01p,
                        int* __restrict__ list, float* __restrict__ wlist,
                        int* __restrict__ counts, int* __restrict__ eoff,
                        int* __restrict__ tokpos, int* __restrict__ tmap) {
  __shared__ int cnt[8], cur[8];
  int tid = threadIdx.x, lane = tid & 63;
  if (tid < 8) cnt[tid] = 0;
  __syncthreads();
  for (int i = tid; i < 16384; i += 256) {
    int tok = i >> 1, j = i & 1;
    int ee = (e01p[tok] >> (8 * j)) & 255;
#pragma unroll
    for (int x = 0; x < 8; ++x) {
      unsigned long long m = __ballot(ee == x);
      if (m != 0ull && lane == (__ffsll((long long)m) - 1)) atomicAdd(&cnt[x], __popcll(m));
    }
  }
  __syncthreads();
  if (tid == 0) {
    int s = 0;
#pragma unroll
    for (int x = 0; x < 8; ++x) {
      cur[x] = s; eoff[x] = s; counts[x] = cnt[x]; s += cnt[x];
    }
  }
  __syncthreads();
  for (int i = tid; i < 272; i += 256) tmap[i] = -1;
  __syncthreads();
  if (tid == 0) {
    int ntiles = 0, tstart[8];
#pragma unroll
    for (int e = 0; e < 8; ++e) { tstart[e] = ntiles; ntiles += (cnt[e] + 95) / 96; }
    int q = ntiles >> 3, r = ntiles & 7;
    for (int e = 0; e < 8; ++e) {
      int nt = (cnt[e] + 95) / 96;
      for (int t = 0; t < nt; ++t) {
        int k = tstart[e] + t;
        int c, o;
        if (k < r * (q + 1)) { c = k / (q + 1); o = k - c * (q + 1); }
        else { int k2 = k - r * (q + 1); c = r + k2 / q; o = k2 - (k2 / q) * q; }
        tmap[8 * o + c] = (e << 16) | t;
      }
    }
  }
  __syncthreads();
  for (int i = tid; i < 16384; i += 256) {
    int tok = i >> 1, j = i & 1;
    int ee = (e01p[tok] >> (8 * j)) & 255;
    unsigned wp = w01p[tok];
    unsigned short us = (unsigned short)(j ? (wp >> 16) : (wp & 0xFFFFu));
    float w = __half2float(__ushort_as_half(us));
    int pos = 0;
#pragma unroll
    for (int x = 0; x < 8; ++x) {
      unsigned long long m = __ballot(ee == x);
      if (m == 0ull) continue;
      int leader = __ffsll((long long)m) - 1;
      int bb = 0;
      if (lane == leader) bb = atomicAdd(&cur[x], __popcll(m));
      bb = __shfl(bb, leader);
      if (ee == x) pos = bb + __popcll(m & ((1ull << lane) - 1ull));
    }
    list[pos] = tok;
    wlist[pos] = w;
    tokpos[i] = pos;
  }
}

// ---------------------------------------------------------------------------
// K7 v4: fused MoE FFN, 96-token tiles. Block = tmap tile, 512 thr / 8 waves.
// F-strips of 256 (8 its). GEMM1: wave w = 32f (ftile it*8+w), z = 3 tok-frags.
// GEMM2: wave w = 64c (ctiles w*2,w*2+1), acc = 6 f32x16. Frag-packed LDS:
// Xs[ks*3+t3] 96KB, Hs[fs*3+t3] 48KB, lane-linear (conflict-free).
// ---------------------------------------------------------------------------
#define HS_OFF 98304

__global__ __launch_bounds__(512, 2) void k_ffn(
    const float* __restrict__ xmoe, const int* __restrict__ list,
    const float* __restrict__ wlist, const int* __restrict__ counts,
    const int* __restrict__ eoff, const int* __restrict__ tmap,
    const unsigned short* __restrict__ W1Pk, const float* __restrict__ b1g,
    const unsigned short* __restrict__ W2Pk, const float* __restrict__ b2g,
    unsigned short* __restrict__ Yb) {
  int mp = tmap[blockIdx.x];
  if (mp < 0) return;
  int e = mp >> 16, tile = mp & 0xFFFF;
  int cnt = counts[e];
  int base = eoff[e] + tile * 96;
  int valid = cnt - tile * 96;
  if (valid > 96) valid = 96;
  __shared__ __align__(16) char smem[147456];  // Xs 96KB | Hs 48KB
  __shared__ int toks[96];
  __shared__ float wts[96];
  int tid = threadIdx.x;
  int w = tid >> 6, l = tid & 63;
  int l31 = l & 31, hi = l >> 5;
  if (tid < 96) {
    int idx = tile * 96 + tid;
    bool v = idx < cnt;
    toks[tid] = list[eoff[e] + (v ? idx : 0)];
    wts[tid] = v ? wlist[eoff[e] + idx] : 0.f;
  }
  __syncthreads();
  // stage Xs_packed: 96 entries (ks*3+t3) x 64 lanes x 16B
#pragma unroll
  for (int s = 0; s < 12; ++s) {
    int sl = s * 512 + tid;
    int ent = sl >> 6, ll = sl & 63;
    int ks = ent / 3, t3 = ent - ks * 3;
    int tok = toks[t3 * 32 + (ll & 31)];
    const float* src = xmoe + (size_t)tok * 512 + ks * 16 + (ll >> 5) * 8;
    float4 v0 = *(const float4*)src;
    float4 v1 = *(const float4*)(src + 4);
    u32x4 u;
    u.x = (unsigned)f2bf(v0.x) | ((unsigned)f2bf(v0.y) << 16);
    u.y = (unsigned)f2bf(v0.z) | ((unsigned)f2bf(v0.w) << 16);
    u.z = (unsigned)f2bf(v1.x) | ((unsigned)f2bf(v1.y) << 16);
    u.w = (unsigned)f2bf(v1.z) | ((unsigned)f2bf(v1.w) << 16);
    *(u32x4*)(smem + ent * 1024 + ll * 16) = u;
  }
  f32x16 acc00, acc01, acc02, acc10, acc11, acc12;
#pragma unroll
  for (int i = 0; i < 16; ++i) {
    acc00[i] = 0.f; acc01[i] = 0.f; acc02[i] = 0.f;
    acc10[i] = 0.f; acc11[i] = 0.f; acc12[i] = 0.f;
  }
  __syncthreads();

  const size_t dstE1 = (size_t)64 * 32 * 512;
  const size_t dstE2 = (size_t)16 * 128 * 512;
  for (int it = 0; it < 8; ++it) {
    // ---- GEMM1: ftile it*8 + w (32 f), 96 tokens ----
    f32x16 z0, z1, z2;
#pragma unroll
    for (int i = 0; i < 16; ++i) { z0[i] = 0.f; z1[i] = 0.f; z2[i] = 0.f; }
    const unsigned short* w1p =
        W1Pk + (size_t)e * dstE1 + ((size_t)(it * 8 + w) * 32) * 512 + l * 8;
#pragma unroll 8
    for (int ks = 0; ks < 32; ++ks) {
      bf16x8 a = *(const bf16x8*)(w1p + (size_t)ks * 512);
      bf16x8 b0 = ld_frag(smem + (ks * 3 + 0) * 1024 + l * 16);
      bf16x8 b1 = ld_frag(smem + (ks * 3 + 1) * 1024 + l * 16);
      bf16x8 b2 = ld_frag(smem + (ks * 3 + 2) * 1024 + l * 16);
      z0 = __builtin_amdgcn_mfma_f32_32x32x16_bf16(a, b0, z0, 0, 0, 0);
      z1 = __builtin_amdgcn_mfma_f32_32x32x16_bf16(a, b1, z1, 0, 0, 0);
      z2 = __builtin_amdgcn_mfma_f32_32x32x16_bf16(a, b2, z2, 0, 0, 0);
    }
    // bias + gelu -> Hs_packed (entry = fs*3 + t3, fs = w*2 + (rq>>1))
#define GELU_STORE(Z, T3)                                                       \
  {                                                                             \
    _Pragma("unroll") for (int rq = 0; rq < 4; ++rq) {                          \
      int fb = w * 32 + 8 * rq + 4 * hi;                                        \
      float4 bv = *(const float4*)(b1g + e * 2048 + it * 256 + fb);             \
      float g0 = gelu_tanh(Z[4 * rq + 0] + bv.x);                               \
      float g1 = gelu_tanh(Z[4 * rq + 1] + bv.y);                               \
      float g2 = gelu_tanh(Z[4 * rq + 2] + bv.z);                               \
      float g3 = gelu_tanh(Z[4 * rq + 3] + bv.w);                               \
      u32x2 p;                                                                  \
      p.x = (unsigned)f2bf(g0) | ((unsigned)f2bf(g1) << 16);                    \
      p.y = (unsigned)f2bf(g2) | ((unsigned)f2bf(g3) << 16);                    \
      int ent = (w * 2 + (rq >> 1)) * 3 + (T3);                                 \
      int lanep = l31 + 32 * (rq & 1);                                          \
      *(u32x2*)(smem + HS_OFF + ent * 1024 + lanep * 16 + hi * 8) = p;          \
    }                                                                           \
  }
    GELU_STORE(z0, 0)
    GELU_STORE(z1, 1)
    GELU_STORE(z2, 2)
    __syncthreads();
    // ---- GEMM2: ctiles w*2 + {0,1}, K = strip 256 (16 k-entries) ----
    const unsigned short* w2a =
        W2Pk + (size_t)e * dstE2 + ((size_t)(w * 2) * 128 + it * 16) * 512 + l * 8;
    const unsigned short* w2b = w2a + (size_t)128 * 512;
#pragma unroll 8
    for (int fs = 0; fs < 16; ++fs) {
      bf16x8 a0 = *(const bf16x8*)(w2a + (size_t)fs * 512);
      bf16x8 a1 = *(const bf16x8*)(w2b + (size_t)fs * 512);
      bf16x8 h0 = ld_frag(smem + HS_OFF + (fs * 3 + 0) * 1024 + l * 16);
      bf16x8 h1 = ld_frag(smem + HS_OFF + (fs * 3 + 1) * 1024 + l * 16);
      bf16x8 h2 = ld_frag(smem + HS_OFF + (fs * 3 + 2) * 1024 + l * 16);
      acc00 = __builtin_amdgcn_mfma_f32_32x32x16_bf16(a0, h0, acc00, 0, 0, 0);
      acc01 = __builtin_amdgcn_mfma_f32_32x32x16_bf16(a0, h1, acc01, 0, 0, 0);
      acc02 = __builtin_amdgcn_mfma_f32_32x32x16_bf16(a0, h2, acc02, 0, 0, 0);
      acc10 = __builtin_amdgcn_mfma_f32_32x32x16_bf16(a1, h0, acc10, 0, 0, 0);
      acc11 = __builtin_amdgcn_mfma_f32_32x32x16_bf16(a1, h1, acc11, 0, 0, 0);
      acc12 = __builtin_amdgcn_mfma_f32_32x32x16_bf16(a1, h2, acc12, 0, 0, 0);
    }
    __syncthreads();
  }
  // epilogue: (acc + b2) * wt -> bf16 -> LDS bounce (Xs area) [tok][c]
#define EPI_STORE(ACC, JC, T3)                                                  \
  {                                                                             \
    _Pragma("unroll") for (int rq = 0; rq < 4; ++rq) {                          \
      int c0 = (w * 2 + (JC)) * 32 + 8 * rq + 4 * hi;                           \
      float4 b2v = *(const float4*)(b2g + e * 512 + c0);                        \
      int tok = (T3)*32 + l31;                                                  \
      float wt = wts[tok];                                                      \
      u32x2 p;                                                                  \
      p.x = (unsigned)f2bf((ACC[4 * rq + 0] + b2v.x) * wt) |                    \
            ((unsigned)f2bf((ACC[4 * rq + 1] + b2v.y) * wt) << 16);             \
      p.y = (unsigned)f2bf((ACC[4 * rq + 2] + b2v.z) * wt) |                    \
            ((unsigned)f2bf((ACC[4 * rq + 3] + b2v.w) * wt) << 16);             \
      *(u32x2*)(smem + tok * 1024 + ((c0 * 2) ^ ((tok & 7) << 4))) = p;         \
    }                                                                           \
  }
  EPI_STORE(acc00, 0, 0)
  EPI_STORE(acc01, 0, 1)
  EPI_STORE(acc02, 0, 2)
  EPI_STORE(acc10, 1, 0)
  EPI_STORE(acc11, 1, 1)
  EPI_STORE(acc12, 1, 2)
  __syncthreads();
#pragma unroll
  for (int s = 0; s < 12; ++s) {
    int i = tid + s * 512;
    int row = i >> 6, g = i & 63;
    if (row < valid) {
      u32x4 v = *(u32x4*)(smem + row * 1024 + ((g * 16) ^ ((row & 7) << 4)));
      *(u32x4*)(Yb + (size_t)(base + row) * 512 + g * 8) = v;
    }
  }
}

// ---------------------------------------------------------------------------
// K8: head bf16 MFMA GEMM (unchanged)
// ---------------------------------------------------------------------------
__global__ __launch_bounds__(256) void k_head(const unsigned short* __restrict__ Yb,
                                              const int* __restrict__ tokpos,
                                              const unsigned short* __restrict__ headPk,
                                              const float* __restrict__ headB,
                                              float* __restrict__ out) {
  __shared__ __align__(16) char As[16384];
  __shared__ int tp[256];
  int tid = threadIdx.x;
  int w = tid >> 6, l = tid & 63;
  int l31 = l & 31, hi = l >> 5;
  int mg = w & 1, ng = w >> 1;
  int bm = blockIdx.x * 128, by = blockIdx.y;
  tp[tid] = tokpos[bm * 2 + tid];
  f32x16 acc00, acc01, acc10, acc11;
#pragma unroll
  for (int i = 0; i < 16; ++i) { acc00[i] = 0.f; acc01[i] = 0.f; acc10[i] = 0.f; acc11[i] = 0.f; }
  int nblk0 = by * 4 + ng * 2;
  __syncthreads();
  for (int kb = 0; kb < 8; ++kb) {
#pragma unroll
    for (int s = 0; s < 4; ++s) {
      int i = tid + s * 256;
      int row = i >> 3, g = i & 7;
      int p1 = tp[row * 2], p2 = tp[row * 2 + 1];
      u32x4 va = *(const u32x4*)(Yb + (size_t)p1 * 512 + kb * 64 + g * 8);
      u32x4 vb = *(const u32x4*)(Yb + (size_t)p2 * 512 + kb * 64 + g * 8);
      u32x4 o;
      o.x = (unsigned)f2bf(bflo(va.x) + bflo(vb.x)) | ((unsigned)f2bf(bfhi(va.x) + bfhi(vb.x)) << 16);
      o.y = (unsigned)f2bf(bflo(va.y) + bflo(vb.y)) | ((unsigned)f2bf(bfhi(va.y) + bfhi(vb.y)) << 16);
      o.z = (unsigned)f2bf(bflo(va.z) + bflo(vb.z)) | ((unsigned)f2bf(bfhi(va.z) + bfhi(vb.z)) << 16);
      o.w = (unsigned)f2bf(bflo(va.w) + bflo(vb.w)) | ((unsigned)f2bf(bfhi(va.w) + bfhi(vb.w)) << 16);
      *(u32x4*)(As + row * 128 + ((g * 16) ^ ((row & 7) << 4))) = o;
    }
    __syncthreads();
#pragma unroll
    for (int ks = 0; ks < 4; ++ks) {
      int r0 = mg * 64 + l31, r1 = r0 + 32;
      int kbyte = ks * 32 + hi * 16;
      bf16x8 a0 = ld_frag(As + r0 * 128 + (kbyte ^ ((r0 & 7) << 4)));
      bf16x8 a1 = ld_frag(As + r1 * 128 + (kbyte ^ ((r1 & 7) << 4)));
      const unsigned short* hp = headPk + ((size_t)nblk0 * 32 + kb * 4 + ks) * 512 + l * 8;
      bf16x8 b0 = *(const bf16x8*)hp;
      bf16x8 b1 = *(const bf16x8*)(hp + 32 * 512);
      acc00 = __builtin_amdgcn_mfma_f32_32x32x16_bf16(a0, b0, acc00, 0, 0, 0);
      acc01 = __builtin_amdgcn_mfma_f32_32x32x16_bf16(a0, b1, acc01, 0, 0, 0);
      acc10 = __builtin_amdgcn_mfma_f32_32x32x16_bf16(a1, b0, acc10, 0, 0, 0);
      acc11 = __builtin_amdgcn_mfma_f32_32x32x16_bf16(a1, b1, acc11, 0, 0, 0);
    }
    __syncthreads();
  }
#pragma unroll
  for (int mf = 0; mf < 2; ++mf) {
#pragma unroll
    for (int nf = 0; nf < 2; ++nf) {
      int nc = by * 128 + ng * 64 + nf * 32 + l31;
      float hb = headB[nc];
#pragma unroll
      for (int r = 0; r < 16; ++r) {
        int m = bm + mg * 64 + mf * 32 + (r & 3) + 8 * (r >> 2) + 4 * hi;
        float v;
        if (mf == 0) v = (nf == 0) ? acc00[r] : acc01[r];
        else         v = (nf == 0) ? acc10[r] : acc11[r];
        out[(size_t)m * 256 + nc] = v + hb;
      }
    }
  }
}

extern "C" void kernel_launch(void* const* d_in, const int* in_sizes, int n_in,
                              void* d_out, int out_size, void* d_ws, size_t ws_size,
                              hipStream_t stream) {
  (void)in_sizes; (void)n_in; (void)out_size; (void)ws_size;
  const int* seq     = (const int*)d_in[0];
  const float* emb   = (const float*)d_in[1];
  const float* phi_w = (const float*)d_in[2];
  const float* phi_b = (const float*)d_in[3];
  const float* amp_w = (const float*)d_in[4];
  const float* amp_b = (const float*)d_in[5];
  const float* gate_w = (const float*)d_in[6];
  const float* gate_b = (const float*)d_in[7];
  const float* w1 = (const float*)d_in[8];
  const float* b1 = (const float*)d_in[9];
  const float* w2 = (const float*)d_in[10];
  const float* b2 = (const float*)d_in[11];
  const float* head_w = (const float*)d_in[12];
  const float* head_b = (const float*)d_in[13];
  float* out = (float*)d_out;

  char* ws = (char*)d_ws;
  const size_t BUF = 16777216;
  float* X    = (float*)(ws);                         // X -> xmoe (in place)
  float* COSb = (float*)(ws + BUF);                   // cos -> Yb (bf16)
  float* SINb = (float*)(ws + 2 * BUF);               // sin -> W1Pk (bf16)
  float* SIGb = (float*)(ws + 3 * BUF);               // sig -> W2Pk (bf16)
  unsigned short* Yb   = (unsigned short*)COSb;
  unsigned short* W1Pk = (unsigned short*)SINb;
  unsigned short* W2Pk = (unsigned short*)SIGb;
  char* sm = ws + 4 * BUF;
  int*      e01p   = (int*)(sm);                      // 32KB
  unsigned* w01p   = (unsigned*)(sm + 32768);         // 32KB
  int*      list   = (int*)(sm + 65536);              // 64KB
  float*    wlist  = (float*)(sm + 131072);           // 64KB
  int*      tokpos = (int*)(sm + 196608);             // 64KB
  int*      counts = (int*)(sm + 262144);
  int*      eoff   = (int*)(sm + 262144 + 64);
  unsigned short* headPk = (unsigned short*)(sm + 266240);  // 256KB
  int*      tmap   = (int*)(sm + 266240 + 262144);          // 272 ints

  k_embed<<<4096, 256, 0, stream>>>(seq, emb, X);
  k_pack_b<<<dim3(8, 1, 1), 256, 0, stream>>>(head_w, 256, 0, headPk, 0, 32);
  k_phi<<<dim3(64, 8), 256, 0, stream>>>(X, phi_w, phi_b, amp_w, amp_b, COSb, SINb, SIGb);
  k_scan<<<32, 64, 0, stream>>>(COSb, SINb, SIGb, X, out + 2097152);
  k_pack_b<<<dim3(64, 1, 8), 256, 0, stream>>>(w1, 2048, (size_t)512 * 2048, W1Pk,
                                               (size_t)64 * 32 * 512, 32);
  k_pack_b<<<dim3(16, 4, 8), 256, 0, stream>>>(w2, 512, (size_t)2048 * 512, W2Pk,
                                               (size_t)16 * 128 * 512, 128);
  k_gate<<<256, 256, 0, stream>>>(X, gate_w, gate_b, e01p, w01p);
  k_build<<<1, 256, 0, stream>>>(e01p, w01p, list, wlist, counts, eoff, tokpos, tmap);
  // 96-tok tiles: <=178 real tiles, single dispatch round
  k_ffn<<<192, 512, 0, stream>>>(X, list, wlist, counts, eoff, tmap,
                                 W1Pk, b1, W2Pk, b2, Yb);
  k_head<<<dim3(64, 2), 256, 0, stream>>>(Yb, tokpos, headPk, head_b, out);
}

// Round 11
// 450.583 us; speedup vs baseline: 1.6568x; 1.2868x over previous
//
#include <hip/hip_runtime.h>
#include <hip/hip_fp16.h>
#include <math.h>

// ---------------------------------------------------------------------------
// SovereignLeviathanV2  round 11 = round 10 with k_scan v3 (producer-consumer):
//  - 32 blocks x 256 thr (4 waves): wave0 = serial-chain compute (64 chains),
//    waves 1-3 = loaders for cos/sin/sig staging 64-step chunks into a
//    double-buffered 96KB LDS ring (16 float4 in flight per lane).
//  - recurrence folded: s' = clip(fmaf(cos+sin, s, -sin)) -> 1-FMA chain.
// Everything else byte-identical to the passing round-10 kernel.
// ---------------------------------------------------------------------------

#define PI_F 3.14159265358979323846f
#define HARM_F 1.04719755119659774615f
#define INV_HARM_F 0.95492965855137201461f
#define TOL_F 0.15f

typedef float f32x16 __attribute__((ext_vector_type(16)));
typedef __bf16 bf16x8 __attribute__((ext_vector_type(8)));
typedef unsigned int u32x4 __attribute__((ext_vector_type(4)));
typedef unsigned int u32x2 __attribute__((ext_vector_type(2)));

__device__ __forceinline__ float gelu_tanh(float x) {
  float x3 = x * x * x;
  return 0.5f * x * (1.f + tanhf(0.79788456080286535588f * (x + 0.044715f * x3)));
}
__device__ __forceinline__ unsigned short f2bf(float x) {
  unsigned u = __float_as_uint(x);
  unsigned r = (u + 0x7FFFu + ((u >> 16) & 1u)) >> 16;
  return (unsigned short)r;
}
__device__ __forceinline__ float bflo(unsigned u) { return __uint_as_float(u << 16); }
__device__ __forceinline__ float bfhi(unsigned u) { return __uint_as_float(u & 0xFFFF0000u); }
__device__ __forceinline__ bf16x8 ld_frag(const void* p) {
  u32x4 v = *(const u32x4*)p;
  return __builtin_bit_cast(bf16x8, v);
}

__device__ __forceinline__ float tanh_fast(float z) {
  float zc = fminf(10.f, fmaxf(-10.f, z));
  float e2 = __expf(zc + zc);
  return (e2 - 1.f) / (e2 + 1.f);
}
__device__ __forceinline__ float sigmoid_fast(float z) {
  return 1.f / (1.f + __expf(-z));
}
__device__ __forceinline__ void sincos_poly(float a, float* sn, float* cs) {
  float q = rintf(a * 0.63661977236758134f);
  int iq = (int)q;
  float t = fmaf(-q, 1.57079637050628662f, a);
  t = fmaf(q, 4.37113883e-8f, t);
  float t2 = t * t;
  float sp = t * fmaf(t2, fmaf(t2, fmaf(t2, -1.9515296e-4f, 8.3321609e-3f),
                               -1.6666654e-1f), 1.f);
  float cp = fmaf(t2 * t2,
                  fmaf(t2, fmaf(t2, 2.4433158e-5f, -1.3887316e-3f), 4.1666646e-2f),
                  fmaf(t2, -0.5f, 1.f));
  int m = iq & 3;
  bool swap = (m & 1) != 0;
  float ss = swap ? cp : sp;
  float cc = swap ? sp : cp;
  *sn = (m & 2) ? -ss : ss;
  *cs = ((m + 1) & 2) ? -cc : cc;
}

// K1: X[n][c] = emb[seq[n]][c]
__global__ void k_embed(const int* __restrict__ seq, const float* __restrict__ emb,
                        float* __restrict__ X) {
  int i = blockIdx.x * 256 + threadIdx.x;
  int n = i >> 7, c4 = i & 127;
  int tok = seq[n];
  ((float4*)X)[(size_t)n * 128 + c4] = ((const float4*)emb)[(size_t)tok * 128 + c4];
}

// ---------------------------------------------------------------------------
// Generic B-operand frag pack (unchanged)
// ---------------------------------------------------------------------------
__global__ __launch_bounds__(256) void k_pack_b(const float* __restrict__ src, int ld,
                                                size_t srcE, unsigned short* __restrict__ dst,
                                                size_t dstE, int fragKtot) {
  __shared__ float Ls[512 * 33];
  int nb = blockIdx.x, kseg = blockIdx.y, e = blockIdx.z;
  const float* s = src + (size_t)e * srcE + (size_t)kseg * 512 * ld + nb * 32;
  unsigned short* d = dst + (size_t)e * dstE + ((size_t)(nb * fragKtot + kseg * 32)) * 512;
  int tid = threadIdx.x;
#pragma unroll
  for (int q = 0; q < 16; ++q) {
    int i = tid + q * 256;
    int row = i >> 3, c4 = i & 7;
    float4 v = *(const float4*)(s + (size_t)row * ld + c4 * 4);
    Ls[row * 33 + c4 * 4 + 0] = v.x;
    Ls[row * 33 + c4 * 4 + 1] = v.y;
    Ls[row * 33 + c4 * 4 + 2] = v.z;
    Ls[row * 33 + c4 * 4 + 3] = v.w;
  }
  __syncthreads();
#pragma unroll
  for (int q = 0; q < 8; ++q) {
    int i = tid + q * 256;
    int ks = i >> 6, l = i & 63;
    int col = l & 31, kb = (l >> 5) * 8 + ks * 16;
    u32x4 o;
    o.x = (unsigned)f2bf(Ls[(kb + 0) * 33 + col]) | ((unsigned)f2bf(Ls[(kb + 1) * 33 + col]) << 16);
    o.y = (unsigned)f2bf(Ls[(kb + 2) * 33 + col]) | ((unsigned)f2bf(Ls[(kb + 3) * 33 + col]) << 16);
    o.z = (unsigned)f2bf(Ls[(kb + 4) * 33 + col]) | ((unsigned)f2bf(Ls[(kb + 5) * 33 + col]) << 16);
    o.w = (unsigned)f2bf(Ls[(kb + 6) * 33 + col]) | ((unsigned)f2bf(Ls[(kb + 7) * 33 + col]) << 16);
    *(u32x4*)(d + (size_t)ks * 512 + l * 8) = o;
  }
}

// ---------------------------------------------------------------------------
// K2: fused phi+amp fp32 GEMM (unchanged, call-free epilogue)
// ---------------------------------------------------------------------------
__global__ __launch_bounds__(256, 2) void k_phi(const float* __restrict__ A,
                                                const float* __restrict__ phiW,
                                                const float* __restrict__ phiB,
                                                const float* __restrict__ ampW,
                                                const float* __restrict__ ampB,
                                                float* __restrict__ cosO,
                                                float* __restrict__ sinO,
                                                float* __restrict__ sigO) {
  __shared__ float As[2][16 * 132];
  __shared__ float Bs[2][16 * 132];
  int tid = threadIdx.x;
  int tx = tid & 15, ty = tid >> 4;
  int bm = blockIdx.x * 128;
  int by = blockIdx.y;
  const float* Bsrc = (by < 4) ? phiW : ampW;
  const float* bias = (by < 4) ? phiB : ampB;
  int cb = (by & 3) * 128;
  float acc[8][8];
#pragma unroll
  for (int r = 0; r < 8; ++r)
#pragma unroll
    for (int c = 0; c < 8; ++c) acc[r][c] = 0.f;

#define STAGE_PHI(BUF, KT)                                                     \
  {                                                                            \
    _Pragma("unroll") for (int s = 0; s < 2; ++s) {                            \
      int i = tid + s * 256;                                                   \
      int row = i >> 2, kq = i & 3;                                            \
      float4 v = *(const float4*)(A + (size_t)(bm + row) * 512 + (KT)*16 + kq * 4); \
      As[BUF][(kq * 4 + 0) * 132 + row] = v.x;                                 \
      As[BUF][(kq * 4 + 1) * 132 + row] = v.y;                                 \
      As[BUF][(kq * 4 + 2) * 132 + row] = v.z;                                 \
      As[BUF][(kq * 4 + 3) * 132 + row] = v.w;                                 \
    }                                                                          \
    _Pragma("unroll") for (int s = 0; s < 2; ++s) {                            \
      int i = tid + s * 256;                                                   \
      int kk = i >> 5, g = i & 31;                                             \
      float4 v = *(const float4*)(Bsrc + (size_t)((KT)*16 + kk) * 512 + cb + g * 4); \
      *(float4*)(&Bs[BUF][kk * 132 + g * 4]) = v;                              \
    }                                                                          \
  }

  STAGE_PHI(0, 0);
  for (int kt = 0; kt < 32; ++kt) {
    __syncthreads();
    if (kt + 1 < 32) {
      if ((kt & 1) == 0) STAGE_PHI(1, kt + 1) else STAGE_PHI(0, kt + 1)
    }
    const float* Ab = As[kt & 1];
    const float* Bb = Bs[kt & 1];
#pragma unroll
    for (int kk = 0; kk < 16; ++kk) {
      float4 a0 = *(const float4*)(&Ab[kk * 132 + ty * 4]);
      float4 a1 = *(const float4*)(&Ab[kk * 132 + 64 + ty * 4]);
      float4 b0 = *(const float4*)(&Bb[kk * 132 + tx * 4]);
      float4 b1 = *(const float4*)(&Bb[kk * 132 + 64 + tx * 4]);
      float ar[8] = {a0.x, a0.y, a0.z, a0.w, a1.x, a1.y, a1.z, a1.w};
      float br[8] = {b0.x, b0.y, b0.z, b0.w, b1.x, b1.y, b1.z, b1.w};
#pragma unroll
      for (int r = 0; r < 8; ++r)
#pragma unroll
        for (int c = 0; c < 8; ++c) acc[r][c] = fmaf(ar[r], br[c], acc[r][c]);
    }
  }
#pragma unroll
  for (int rh = 0; rh < 2; ++rh) {
#pragma unroll
    for (int rr = 0; rr < 4; ++rr) {
      int r = rh * 4 + rr;
      int m = bm + rh * 64 + ty * 4 + rr;
      if (by < 4) {
#pragma unroll
        for (int ch = 0; ch < 2; ++ch) {
          float o0[4], o1[4];
#pragma unroll
          for (int cc = 0; cc < 4; ++cc) {
            float z = acc[r][ch * 4 + cc] + bias[cb + ch * 64 + tx * 4 + cc];
            float a = tanh_fast(z) * PI_F;
            float nr = rintf(a * INV_HARM_F) * HARM_F;
            if (fabsf(a - nr) < TOL_F) a = nr;
            float sn, cs;
            sincos_poly(a, &sn, &cs);
            o0[cc] = cs;
            o1[cc] = sn;
          }
          float* cp = cosO + (size_t)m * 512 + cb + ch * 64 + tx * 4;
          float* sp = sinO + (size_t)m * 512 + cb + ch * 64 + tx * 4;
          *(float4*)cp = make_float4(o0[0], o0[1], o0[2], o0[3]);
          *(float4*)sp = make_float4(o1[0], o1[1], o1[2], o1[3]);
        }
      } else {
#pragma unroll
        for (int ch = 0; ch < 2; ++ch) {
          float o0[4];
#pragma unroll
          for (int cc = 0; cc < 4; ++cc) {
            float z = acc[r][ch * 4 + cc] + bias[cb + ch * 64 + tx * 4 + cc];
            o0[cc] = sigmoid_fast(z);
          }
          float* gp = sigO + (size_t)m * 512 + cb + ch * 64 + tx * 4;
          *(float4*)gp = make_float4(o0[0], o0[1], o0[2], o0[3]);
        }
      }
    }
  }
}

// ---------------------------------------------------------------------------
// K3 v3: producer-consumer toroidal scan. 32 blocks x 256 thr (4 waves).
// wave0 computes 64 chains (b = blk>>3, c0 = (blk&7)*64); waves 1-3 stage
// cos/sin/sig 64-step chunks into double-buffered LDS (2x3x16KB = 96KB).
// Recurrence: s' = clip(fmaf(cos+sin, s, -sin)); out = sig * s'.
// ---------------------------------------------------------------------------
__global__ __launch_bounds__(256, 1) void k_scan(const float* __restrict__ cosb,
                                                 const float* __restrict__ sinb,
                                                 const float* __restrict__ sigb,
                                                 float* __restrict__ xmoe,
                                                 float* __restrict__ nstate) {
  __shared__ float lds[2][3][64 * 64];
  int tid = threadIdx.x;
  int wv = tid >> 6, l = tid & 63;
  int b = blockIdx.x >> 3;
  int c0 = (blockIdx.x & 7) << 6;
  size_t base = ((size_t)b * 2048) * 512 + c0;  // + t*512 + c

#define SCAN_STAGE(SRC, K, BUF)                                                \
  {                                                                            \
    float4 tmp[16];                                                            \
    size_t sb = base + ((size_t)(K) * 64 + tq) * 512 + cq * 4;                 \
    _Pragma("unroll") for (int t4 = 0; t4 < 16; ++t4)                          \
      tmp[t4] = *(const float4*)((SRC) + sb + (size_t)t4 * 4 * 512);           \
    _Pragma("unroll") for (int t4 = 0; t4 < 16; ++t4)                          \
      *(float4*)(&lds[BUF][wv - 1][(t4 * 4 + tq) * 64 + cq * 4]) = tmp[t4];    \
  }

  if (wv > 0) {
    const float* src = (wv == 1) ? cosb : (wv == 2) ? sinb : sigb;
    int tq = l >> 4, cq = l & 15;
    SCAN_STAGE(src, 0, 0);
    __syncthreads();
    for (int k = 0; k < 32; ++k) {
      if (k + 1 < 32) {
        if (((k + 1) & 1) == 0) SCAN_STAGE(src, k + 1, 0)
        else                    SCAN_STAGE(src, k + 1, 1)
      }
      __syncthreads();
    }
  } else {
    __syncthreads();  // chunk 0 staged
    float state = 0.f;
    for (int k = 0; k < 32; ++k) {
      const float* bufC = &lds[k & 1][0][0];
      const float* bufS = &lds[k & 1][1][0];
      const float* bufG = &lds[k & 1][2][0];
      size_t outb = base + (size_t)k * 64 * 512 + l;
#pragma unroll
      for (int tt = 0; tt < 64; ++tt) {
        float pc = bufC[tt * 64 + l];
        float ps = bufS[tt * 64 + l];
        float pg = bufG[tt * 64 + l];
        float st = fmaf(pc + ps, state, -ps);
        st = fminf(1.f, fmaxf(-1.f, st));
        state = st;
        xmoe[outb + (size_t)tt * 512] = pg * st;
      }
      __syncthreads();
    }
    nstate[(size_t)b * 512 + c0 + l] = state;
  }
}

// K4: gate logits + softmax + top2 (unchanged)
__global__ __launch_bounds__(256) void k_gate(const float* __restrict__ xmoe,
                                              const float* __restrict__ gw_g,
                                              const float* __restrict__ gb,
                                              int* __restrict__ e01p,
                                              unsigned* __restrict__ w01p) {
  __shared__ float gw[4096];
  int tid = threadIdx.x;
  for (int i = tid; i < 4096; i += 256) gw[i] = gw_g[i];
  __syncthreads();
  int tok = blockIdx.x * 32 + (tid >> 3);
  int e = tid & 7;
  float acc = gb[e];
  const float4* xr = (const float4*)(xmoe + (size_t)tok * 512);
  for (int k4 = 0; k4 < 128; ++k4) {
    float4 x = xr[k4];
    acc += x.x * gw[(k4 * 4 + 0) * 8 + e];
    acc += x.y * gw[(k4 * 4 + 1) * 8 + e];
    acc += x.z * gw[(k4 * 4 + 2) * 8 + e];
    acc += x.w * gw[(k4 * 4 + 3) * 8 + e];
  }
  float m = acc;
  m = fmaxf(m, __shfl_xor(m, 1));
  m = fmaxf(m, __shfl_xor(m, 2));
  m = fmaxf(m, __shfl_xor(m, 4));
  float p = expf(acc - m);
  float ss = p;
  ss += __shfl_xor(ss, 1); ss += __shfl_xor(ss, 2); ss += __shfl_xor(ss, 4);
  p /= ss;
  float v1 = p; int i1 = e;
  {
    float ov; int oi;
    ov = __shfl_xor(v1, 1); oi = __shfl_xor(i1, 1);
    if (ov > v1 || (ov == v1 && oi < i1)) { v1 = ov; i1 = oi; }
    ov = __shfl_xor(v1, 2); oi = __shfl_xor(i1, 2);
    if (ov > v1 || (ov == v1 && oi < i1)) { v1 = ov; i1 = oi; }
    ov = __shfl_xor(v1, 4); oi = __shfl_xor(i1, 4);
    if (ov > v1 || (ov == v1 && oi < i1)) { v1 = ov; i1 = oi; }
  }
  float v2 = (e == i1) ? -1.f : p; int i2 = e;
  {
    float ov; int oi;
    ov = __shfl_xor(v2, 1); oi = __shfl_xor(i2, 1);
    if (ov > v2 || (ov == v2 && oi < i2)) { v2 = ov; i2 = oi; }
    ov = __shfl_xor(v2, 2); oi = __shfl_xor(i2, 2);
    if (ov > v2 || (ov == v2 && oi < i2)) { v2 = ov; i2 = oi; }
    ov = __shfl_xor(v2, 4); oi = __shfl_xor(i2, 4);
    if (ov > v2 || (ov == v2 && oi < i2)) { v2 = ov; i2 = oi; }
  }
  if (e == 0) {
    float s2 = v1 + v2;
    __half h1 = __float2half(v1 / s2), h2 = __float2half(v2 / s2);
    e01p[tok] = i1 | (i2 << 8);
    w01p[tok] = (unsigned)__half_as_ushort(h1) | ((unsigned)__half_as_ushort(h2) << 16);
  }
}

// K6: counts -> eoff -> scatter -> tmap (unchanged, 96-tok tiles)
__global__ void k_build(const int* __restrict__ e01p, const unsigned* __restrict__ w01p,
                        int* __restrict__ list, float* __restrict__ wlist,
                        int* __restrict__ counts, int* __restrict__ eoff,
                        int* __restrict__ tokpos, int* __restrict__ tmap) {
  __shared__ int cnt[8], cur[8];
  int tid = threadIdx.x, lane = tid & 63;
  if (tid < 8) cnt[tid] = 0;
  __syncthreads();
  for (int i = tid; i < 16384; i += 256) {
    int tok = i >> 1, j = i & 1;
    int ee = (e01p[tok] >> (8 * j)) & 255;
#pragma unroll
    for (int x = 0; x < 8; ++x) {
      unsigned long long m = __ballot(ee == x);
      if (m != 0ull && lane == (__ffsll((long long)m) - 1)) atomicAdd(&cnt[x], __popcll(m));
    }
  }
  __syncthreads();
  if (tid == 0) {
    int s = 0;
#pragma unroll
    for (int x = 0; x < 8; ++x) {
      cur[x] = s; eoff[x] = s; counts[x] = cnt[x]; s += cnt[x];
    }
  }
  __syncthreads();
  for (int i = tid; i < 272; i += 256) tmap[i] = -1;
  __syncthreads();
  if (tid == 0) {
    int ntiles = 0, tstart[8];
#pragma unroll
    for (int e = 0; e < 8; ++e) { tstart[e] = ntiles; ntiles += (cnt[e] + 95) / 96; }
    int q = ntiles >> 3, r = ntiles & 7;
    for (int e = 0; e < 8; ++e) {
      int nt = (cnt[e] + 95) / 96;
      for (int t = 0; t < nt; ++t) {
        int k = tstart[e] + t;
        int c, o;
        if (k < r * (q + 1)) { c = k / (q + 1); o = k - c * (q + 1); }
        else { int k2 = k - r * (q + 1); c = r + k2 / q; o = k2 - (k2 / q) * q; }
        tmap[8 * o + c] = (e << 16) | t;
      }
    }
  }
  __syncthreads();
  for (int i = tid; i < 16384; i += 256) {
    int tok = i >> 1, j = i & 1;
    int ee = (e01p[tok] >> (8 * j)) & 255;
    unsigned wp = w01p[tok];
    unsigned short us = (unsigned short)(j ? (wp >> 16) : (wp & 0xFFFFu));
    float w = __half2float(__ushort_as_half(us));
    int pos = 0;
#pragma unroll
    for (int x = 0; x < 8; ++x) {
      unsigned long long m = __ballot(ee == x);
      if (m == 0ull) continue;
      int leader = __ffsll((long long)m) - 1;
      int bb = 0;
      if (lane == leader) bb = atomicAdd(&cur[x], __popcll(m));
      bb = __shfl(bb, leader);
      if (ee == x) pos = bb + __popcll(m & ((1ull << lane) - 1ull));
    }
    list[pos] = tok;
    wlist[pos] = w;
    tokpos[i] = pos;
  }
}

// ---------------------------------------------------------------------------
// K7 v4: fused MoE FFN, 96-token tiles (unchanged from round 10)
// ---------------------------------------------------------------------------
#define HS_OFF 98304

__global__ __launch_bounds__(512, 2) void k_ffn(
    const float* __restrict__ xmoe, const int* __restrict__ list,
    const float* __restrict__ wlist, const int* __restrict__ counts,
    const int* __restrict__ eoff, const int* __restrict__ tmap,
    const unsigned short* __restrict__ W1Pk, const float* __restrict__ b1g,
    const unsigned short* __restrict__ W2Pk, const float* __restrict__ b2g,
    unsigned short* __restrict__ Yb) {
  int mp = tmap[blockIdx.x];
  if (mp < 0) return;
  int e = mp >> 16, tile = mp & 0xFFFF;
  int cnt = counts[e];
  int base = eoff[e] + tile * 96;
  int valid = cnt - tile * 96;
  if (valid > 96) valid = 96;
  __shared__ __align__(16) char smem[147456];  // Xs 96KB | Hs 48KB
  __shared__ int toks[96];
  __shared__ float wts[96];
  int tid = threadIdx.x;
  int w = tid >> 6, l = tid & 63;
  int l31 = l & 31, hi = l >> 5;
  if (tid < 96) {
    int idx = tile * 96 + tid;
    bool v = idx < cnt;
    toks[tid] = list[eoff[e] + (v ? idx : 0)];
    wts[tid] = v ? wlist[eoff[e] + idx] : 0.f;
  }
  __syncthreads();
#pragma unroll
  for (int s = 0; s < 12; ++s) {
    int sl = s * 512 + tid;
    int ent = sl >> 6, ll = sl & 63;
    int ks = ent / 3, t3 = ent - ks * 3;
    int tok = toks[t3 * 32 + (ll & 31)];
    const float* src = xmoe + (size_t)tok * 512 + ks * 16 + (ll >> 5) * 8;
    float4 v0 = *(const float4*)src;
    float4 v1 = *(const float4*)(src + 4);
    u32x4 u;
    u.x = (unsigned)f2bf(v0.x) | ((unsigned)f2bf(v0.y) << 16);
    u.y = (unsigned)f2bf(v0.z) | ((unsigned)f2bf(v0.w) << 16);
    u.z = (unsigned)f2bf(v1.x) | ((unsigned)f2bf(v1.y) << 16);
    u.w = (unsigned)f2bf(v1.z) | ((unsigned)f2bf(v1.w) << 16);
    *(u32x4*)(smem + ent * 1024 + ll * 16) = u;
  }
  f32x16 acc00, acc01, acc02, acc10, acc11, acc12;
#pragma unroll
  for (int i = 0; i < 16; ++i) {
    acc00[i] = 0.f; acc01[i] = 0.f; acc02[i] = 0.f;
    acc10[i] = 0.f; acc11[i] = 0.f; acc12[i] = 0.f;
  }
  __syncthreads();

  const size_t dstE1 = (size_t)64 * 32 * 512;
  const size_t dstE2 = (size_t)16 * 128 * 512;
  for (int it = 0; it < 8; ++it) {
    f32x16 z0, z1, z2;
#pragma unroll
    for (int i = 0; i < 16; ++i) { z0[i] = 0.f; z1[i] = 0.f; z2[i] = 0.f; }
    const unsigned short* w1p =
        W1Pk + (size_t)e * dstE1 + ((size_t)(it * 8 + w) * 32) * 512 + l * 8;
#pragma unroll 8
    for (int ks = 0; ks < 32; ++ks) {
      bf16x8 a = *(const bf16x8*)(w1p + (size_t)ks * 512);
      bf16x8 b0 = ld_frag(smem + (ks * 3 + 0) * 1024 + l * 16);
      bf16x8 b1 = ld_frag(smem + (ks * 3 + 1) * 1024 + l * 16);
      bf16x8 b2 = ld_frag(smem + (ks * 3 + 2) * 1024 + l * 16);
      z0 = __builtin_amdgcn_mfma_f32_32x32x16_bf16(a, b0, z0, 0, 0, 0);
      z1 = __builtin_amdgcn_mfma_f32_32x32x16_bf16(a, b1, z1, 0, 0, 0);
      z2 = __builtin_amdgcn_mfma_f32_32x32x16_bf16(a, b2, z2, 0, 0, 0);
    }
#define GELU_STORE(Z, T3)                                                       \
  {                                                                             \
    _Pragma("unroll") for (int rq = 0; rq < 4; ++rq) {                          \
      int fb = w * 32 + 8 * rq + 4 * hi;                                        \
      float4 bv = *(const float4*)(b1g + e * 2048 + it * 256 + fb);             \
      float g0 = gelu_tanh(Z[4 * rq + 0] + bv.x);                               \
      float g1 = gelu_tanh(Z[4 * rq + 1] + bv.y);                               \
      float g2 = gelu_tanh(Z[4 * rq + 2] + bv.z);                               \
      float g3 = gelu_tanh(Z[4 * rq + 3] + bv.w);                               \
      u32x2 p;                                                                  \
      p.x = (unsigned)f2bf(g0) | ((unsigned)f2bf(g1) << 16);                    \
      p.y = (unsigned)f2bf(g2) | ((unsigned)f2bf(g3) << 16);                    \
      int ent = (w * 2 + (rq >> 1)) * 3 + (T3);                                 \
      int lanep = l31 + 32 * (rq & 1);                                          \
      *(u32x2*)(smem + HS_OFF + ent * 1024 + lanep * 16 + hi * 8) = p;          \
    }                                                                           \
  }
    GELU_STORE(z0, 0)
    GELU_STORE(z1, 1)
    GELU_STORE(z2, 2)
    __syncthreads();
    const unsigned short* w2a =
        W2Pk + (size_t)e * dstE2 + ((size_t)(w * 2) * 128 + it * 16) * 512 + l * 8;
    const unsigned short* w2b = w2a + (size_t)128 * 512;
#pragma unroll 8
    for (int fs = 0; fs < 16; ++fs) {
      bf16x8 a0 = *(const bf16x8*)(w2a + (size_t)fs * 512);
      bf16x8 a1 = *(const bf16x8*)(w2b + (size_t)fs * 512);
      bf16x8 h0 = ld_frag(smem + HS_OFF + (fs * 3 + 0) * 1024 + l * 16);
      bf16x8 h1 = ld_frag(smem + HS_OFF + (fs * 3 + 1) * 1024 + l * 16);
      bf16x8 h2 = ld_frag(smem + HS_OFF + (fs * 3 + 2) * 1024 + l * 16);
      acc00 = __builtin_amdgcn_mfma_f32_32x32x16_bf16(a0, h0, acc00, 0, 0, 0);
      acc01 = __builtin_amdgcn_mfma_f32_32x32x16_bf16(a0, h1, acc01, 0, 0, 0);
      acc02 = __builtin_amdgcn_mfma_f32_32x32x16_bf16(a0, h2, acc02, 0, 0, 0);
      acc10 = __builtin_amdgcn_mfma_f32_32x32x16_bf16(a1, h0, acc10, 0, 0, 0);
      acc11 = __builtin_amdgcn_mfma_f32_32x32x16_bf16(a1, h1, acc11, 0, 0, 0);
      acc12 = __builtin_amdgcn_mfma_f32_32x32x16_bf16(a1, h2, acc12, 0, 0, 0);
    }
    __syncthreads();
  }
#define EPI_STORE(ACC, JC, T3)                                                  \
  {                                                                             \
    _Pragma("unroll") for (int rq = 0; rq < 4; ++rq) {                          \
      int c0 = (w * 2 + (JC)) * 32 + 8 * rq + 4 * hi;                           \
      float4 b2v = *(const float4*)(b2g + e * 512 + c0);                        \
      int tok = (T3)*32 + l31;                                                  \
      float wt = wts[tok];                                                      \
      u32x2 p;                                                                  \
      p.x = (unsigned)f2bf((ACC[4 * rq + 0] + b2v.x) * wt) |                    \
            ((unsigned)f2bf((ACC[4 * rq + 1] + b2v.y) * wt) << 16);             \
      p.y = (unsigned)f2bf((ACC[4 * rq + 2] + b2v.z) * wt) |                    \
            ((unsigned)f2bf((ACC[4 * rq + 3] + b2v.w) * wt) << 16);             \
      *(u32x2*)(smem + tok * 1024 + ((c0 * 2) ^ ((tok & 7) << 4))) = p;         \
    }                                                                           \
  }
  EPI_STORE(acc00, 0, 0)
  EPI_STORE(acc01, 0, 1)
  EPI_STORE(acc02, 0, 2)
  EPI_STORE(acc10, 1, 0)
  EPI_STORE(acc11, 1, 1)
  EPI_STORE(acc12, 1, 2)
  __syncthreads();
#pragma unroll
  for (int s = 0; s < 12; ++s) {
    int i = tid + s * 512;
    int row = i >> 6, g = i & 63;
    if (row < valid) {
      u32x4 v = *(u32x4*)(smem + row * 1024 + ((g * 16) ^ ((row & 7) << 4)));
      *(u32x4*)(Yb + (size_t)(base + row) * 512 + g * 8) = v;
    }
  }
}

// ---------------------------------------------------------------------------
// K8: head bf16 MFMA GEMM (unchanged)
// ---------------------------------------------------------------------------
__global__ __launch_bounds__(256) void k_head(const unsigned short* __restrict__ Yb,
                                              const int* __restrict__ tokpos,
                                              const unsigned short* __restrict__ headPk,
                                              const float* __restrict__ headB,
                                              float* __restrict__ out) {
  __shared__ __align__(16) char As[16384];
  __shared__ int tp[256];
  int tid = threadIdx.x;
  int w = tid >> 6, l = tid & 63;
  int l31 = l & 31, hi = l >> 5;
  int mg = w & 1, ng = w >> 1;
  int bm = blockIdx.x * 128, by = blockIdx.y;
  tp[tid] = tokpos[bm * 2 + tid];
  f32x16 acc00, acc01, acc10, acc11;
#pragma unroll
  for (int i = 0; i < 16; ++i) { acc00[i] = 0.f; acc01[i] = 0.f; acc10[i] = 0.f; acc11[i] = 0.f; }
  int nblk0 = by * 4 + ng * 2;
  __syncthreads();
  for (int kb = 0; kb < 8; ++kb) {
#pragma unroll
    for (int s = 0; s < 4; ++s) {
      int i = tid + s * 256;
      int row = i >> 3, g = i & 7;
      int p1 = tp[row * 2], p2 = tp[row * 2 + 1];
      u32x4 va = *(const u32x4*)(Yb + (size_t)p1 * 512 + kb * 64 + g * 8);
      u32x4 vb = *(const u32x4*)(Yb + (size_t)p2 * 512 + kb * 64 + g * 8);
      u32x4 o;
      o.x = (unsigned)f2bf(bflo(va.x) + bflo(vb.x)) | ((unsigned)f2bf(bfhi(va.x) + bfhi(vb.x)) << 16);
      o.y = (unsigned)f2bf(bflo(va.y) + bflo(vb.y)) | ((unsigned)f2bf(bfhi(va.y) + bfhi(vb.y)) << 16);
      o.z = (unsigned)f2bf(bflo(va.z) + bflo(vb.z)) | ((unsigned)f2bf(bfhi(va.z) + bfhi(vb.z)) << 16);
      o.w = (unsigned)f2bf(bflo(va.w) + bflo(vb.w)) | ((unsigned)f2bf(bfhi(va.w) + bfhi(vb.w)) << 16);
      *(u32x4*)(As + row * 128 + ((g * 16) ^ ((row & 7) << 4))) = o;
    }
    __syncthreads();
#pragma unroll
    for (int ks = 0; ks < 4; ++ks) {
      int r0 = mg * 64 + l31, r1 = r0 + 32;
      int kbyte = ks * 32 + hi * 16;
      bf16x8 a0 = ld_frag(As + r0 * 128 + (kbyte ^ ((r0 & 7) << 4)));
      bf16x8 a1 = ld_frag(As + r1 * 128 + (kbyte ^ ((r1 & 7) << 4)));
      const unsigned short* hp = headPk + ((size_t)nblk0 * 32 + kb * 4 + ks) * 512 + l * 8;
      bf16x8 b0 = *(const bf16x8*)hp;
      bf16x8 b1 = *(const bf16x8*)(hp + 32 * 512);
      acc00 = __builtin_amdgcn_mfma_f32_32x32x16_bf16(a0, b0, acc00, 0, 0, 0);
      acc01 = __builtin_amdgcn_mfma_f32_32x32x16_bf16(a0, b1, acc01, 0, 0, 0);
      acc10 = __builtin_amdgcn_mfma_f32_32x32x16_bf16(a1, b0, acc10, 0, 0, 0);
      acc11 = __builtin_amdgcn_mfma_f32_32x32x16_bf16(a1, b1, acc11, 0, 0, 0);
    }
    __syncthreads();
  }
#pragma unroll
  for (int mf = 0; mf < 2; ++mf) {
#pragma unroll
    for (int nf = 0; nf < 2; ++nf) {
      int nc = by * 128 + ng * 64 + nf * 32 + l31;
      float hb = headB[nc];
#pragma unroll
      for (int r = 0; r < 16; ++r) {
        int m = bm + mg * 64 + mf * 32 + (r & 3) + 8 * (r >> 2) + 4 * hi;
        float v;
        if (mf == 0) v = (nf == 0) ? acc00[r] : acc01[r];
        else         v = (nf == 0) ? acc10[r] : acc11[r];
        out[(size_t)m * 256 + nc] = v + hb;
      }
    }
  }
}

extern "C" void kernel_launch(void* const* d_in, const int* in_sizes, int n_in,
                              void* d_out, int out_size, void* d_ws, size_t ws_size,
                              hipStream_t stream) {
  (void)in_sizes; (void)n_in; (void)out_size; (void)ws_size;
  const int* seq     = (const int*)d_in[0];
  const float* emb   = (const float*)d_in[1];
  const float* phi_w = (const float*)d_in[2];
  const float* phi_b = (const float*)d_in[3];
  const float* amp_w = (const float*)d_in[4];
  const float* amp_b = (const float*)d_in[5];
  const float* gate_w = (const float*)d_in[6];
  const float* gate_b = (const float*)d_in[7];
  const float* w1 = (const float*)d_in[8];
  const float* b1 = (const float*)d_in[9];
  const float* w2 = (const float*)d_in[10];
  const float* b2 = (const float*)d_in[11];
  const float* head_w = (const float*)d_in[12];
  const float* head_b = (const float*)d_in[13];
  float* out = (float*)d_out;

  char* ws = (char*)d_ws;
  const size_t BUF = 16777216;
  float* X    = (float*)(ws);                         // X -> xmoe (in place)
  float* COSb = (float*)(ws + BUF);                   // cos -> Yb (bf16)
  float* SINb = (float*)(ws + 2 * BUF);               // sin -> W1Pk (bf16)
  float* SIGb = (float*)(ws + 3 * BUF);               // sig -> W2Pk (bf16)
  unsigned short* Yb   = (unsigned short*)COSb;
  unsigned short* W1Pk = (unsigned short*)SINb;
  unsigned short* W2Pk = (unsigned short*)SIGb;
  char* sm = ws + 4 * BUF;
  int*      e01p   = (int*)(sm);                      // 32KB
  unsigned* w01p   = (unsigned*)(sm + 32768);         // 32KB
  int*      list   = (int*)(sm + 65536);              // 64KB
  float*    wlist  = (float*)(sm + 131072);           // 64KB
  int*      tokpos = (int*)(sm + 196608);             // 64KB
  int*      counts = (int*)(sm + 262144);
  int*      eoff   = (int*)(sm + 262144 + 64);
  unsigned short* headPk = (unsigned short*)(sm + 266240);  // 256KB
  int*      tmap   = (int*)(sm + 266240 + 262144);          // 272 ints

  k_embed<<<4096, 256, 0, stream>>>(seq, emb, X);
  k_pack_b<<<dim3(8, 1, 1), 256, 0, stream>>>(head_w, 256, 0, headPk, 0, 32);
  k_phi<<<dim3(64, 8), 256, 0, stream>>>(X, phi_w, phi_b, amp_w, amp_b, COSb, SINb, SIGb);
  k_scan<<<32, 256, 0, stream>>>(COSb, SINb, SIGb, X, out + 2097152);
  k_pack_b<<<dim3(64, 1, 8), 256, 0, stream>>>(w1, 2048, (size_t)512 * 2048, W1Pk,
                                               (size_t)64 * 32 * 512, 32);
  k_pack_b<<<dim3(16, 4, 8), 256, 0, stream>>>(w2, 512, (size_t)2048 * 512, W2Pk,
                                               (size_t)16 * 128 * 512, 128);
  k_gate<<<256, 256, 0, stream>>>(X, gate_w, gate_b, e01p, w01p);
  k_build<<<1, 256, 0, stream>>>(e01p, w01p, list, wlist, counts, eoff, tokpos, tmap);
  k_ffn<<<192, 512, 0, stream>>>(X, list, wlist, counts, eoff, tmap,
                                 W1Pk, b1, W2Pk, b2, Yb);
  k_head<<<dim3(64, 2), 256, 0, stream>>>(Yb, tokpos, headPk, head_b, out);
}

// Round 12
// 393.787 us; speedup vs baseline: 1.8958x; 1.1442x over previous
//
#include <hip/hip_runtime.h>
#include <hip/hip_fp16.h>
#include <math.h>

// ---------------------------------------------------------------------------
// SovereignLeviathanV2  round 12 = round 11 with:
//  - k_phi v5: bf16x3 split-precision MFMA (z = XhiWhi + XloWhi + XhiWlo;
//    error ~2^-18 == fp32-grade, tesla-gate safe). Mirrors the validated
//    k_head frag pattern; W staged+split into 16KB dbuf LDS; X pre-packed.
//  - k_embed2: emits frag-packed Xhi/Xlo bf16 into the X region (8+8MB,
//    no workspace growth; scan overwrites with xmoe as before).
//  - gelu_tanh: tanhf -> __expf-based inline (k_ffn VALU shave).
// Everything else byte-identical to the passing round-11 kernel.
// ---------------------------------------------------------------------------

#define PI_F 3.14159265358979323846f
#define HARM_F 1.04719755119659774615f
#define INV_HARM_F 0.95492965855137201461f
#define TOL_F 0.15f

typedef float f32x16 __attribute__((ext_vector_type(16)));
typedef __bf16 bf16x8 __attribute__((ext_vector_type(8)));
typedef unsigned int u32x4 __attribute__((ext_vector_type(4)));
typedef unsigned int u32x2 __attribute__((ext_vector_type(2)));

__device__ __forceinline__ float bflo(unsigned u) { return __uint_as_float(u << 16); }
__device__ __forceinline__ float bfhi(unsigned u) { return __uint_as_float(u & 0xFFFF0000u); }
__device__ __forceinline__ unsigned short f2bf(float x) {
  unsigned u = __float_as_uint(x);
  unsigned r = (u + 0x7FFFu + ((u >> 16) & 1u)) >> 16;
  return (unsigned short)r;
}
__device__ __forceinline__ bf16x8 ld_frag(const void* p) {
  u32x4 v = *(const u32x4*)p;
  return __builtin_bit_cast(bf16x8, v);
}
__device__ __forceinline__ float tanh_fast(float z) {
  float zc = fminf(10.f, fmaxf(-10.f, z));
  float e2 = __expf(zc + zc);
  return (e2 - 1.f) / (e2 + 1.f);
}
__device__ __forceinline__ float sigmoid_fast(float z) {
  return 1.f / (1.f + __expf(-z));
}
__device__ __forceinline__ float gelu_tanh(float x) {
  float x3 = x * x * x;
  float t = 0.79788456080286535588f * (x + 0.044715f * x3);
  return 0.5f * x * (1.f + tanh_fast(t));
}
__device__ __forceinline__ void sincos_poly(float a, float* sn, float* cs) {
  float q = rintf(a * 0.63661977236758134f);
  int iq = (int)q;
  float t = fmaf(-q, 1.57079637050628662f, a);
  t = fmaf(q, 4.37113883e-8f, t);
  float t2 = t * t;
  float sp = t * fmaf(t2, fmaf(t2, fmaf(t2, -1.9515296e-4f, 8.3321609e-3f),
                               -1.6666654e-1f), 1.f);
  float cp = fmaf(t2 * t2,
                  fmaf(t2, fmaf(t2, 2.4433158e-5f, -1.3887316e-3f), 4.1666646e-2f),
                  fmaf(t2, -0.5f, 1.f));
  int m = iq & 3;
  bool swap = (m & 1) != 0;
  float ss = swap ? cp : sp;
  float cc = swap ? sp : cp;
  *sn = (m & 2) ? -ss : ss;
  *cs = ((m + 1) & 2) ? -cc : cc;
}

// K1 v2: frag-packed Xhi/Xlo. Entry ent = tb*32+ks: lane l holds
// X[tok=tb*32+(l&31)][k=ks*16+(l>>5)*8+j] as bf16 hi + bf16 residual lo.
__global__ void k_embed2(const int* __restrict__ seq, const float* __restrict__ emb,
                         unsigned short* __restrict__ XhiP,
                         unsigned short* __restrict__ XloP) {
  int gid = blockIdx.x * 256 + threadIdx.x;  // 0..524287
  int ent = gid >> 6, l = gid & 63;
  int tb = ent >> 5, ks = ent & 31;
  int tok = tb * 32 + (l & 31);
  int k0 = ks * 16 + (l >> 5) * 8;
  const float* src = emb + (size_t)seq[tok] * 512 + k0;
  float4 v0 = *(const float4*)src;
  float4 v1 = *(const float4*)(src + 4);
  float vv[8] = {v0.x, v0.y, v0.z, v0.w, v1.x, v1.y, v1.z, v1.w};
  unsigned h[8], lo[8];
#pragma unroll
  for (int j = 0; j < 8; ++j) {
    h[j] = f2bf(vv[j]);
    lo[j] = f2bf(vv[j] - bflo(h[j]));
  }
  u32x4 H, L;
  H.x = h[0] | (h[1] << 16);  H.y = h[2] | (h[3] << 16);
  H.z = h[4] | (h[5] << 16);  H.w = h[6] | (h[7] << 16);
  L.x = lo[0] | (lo[1] << 16); L.y = lo[2] | (lo[3] << 16);
  L.z = lo[4] | (lo[5] << 16); L.w = lo[6] | (lo[7] << 16);
  *(u32x4*)(XhiP + (size_t)ent * 512 + l * 8) = H;
  *(u32x4*)(XloP + (size_t)ent * 512 + l * 8) = L;
}

// ---------------------------------------------------------------------------
// Generic B-operand frag pack (unchanged)
// ---------------------------------------------------------------------------
__global__ __launch_bounds__(256) void k_pack_b(const float* __restrict__ src, int ld,
                                                size_t srcE, unsigned short* __restrict__ dst,
                                                size_t dstE, int fragKtot) {
  __shared__ float Ls[512 * 33];
  int nb = blockIdx.x, kseg = blockIdx.y, e = blockIdx.z;
  const float* s = src + (size_t)e * srcE + (size_t)kseg * 512 * ld + nb * 32;
  unsigned short* d = dst + (size_t)e * dstE + ((size_t)(nb * fragKtot + kseg * 32)) * 512;
  int tid = threadIdx.x;
#pragma unroll
  for (int q = 0; q < 16; ++q) {
    int i = tid + q * 256;
    int row = i >> 3, c4 = i & 7;
    float4 v = *(const float4*)(s + (size_t)row * ld + c4 * 4);
    Ls[row * 33 + c4 * 4 + 0] = v.x;
    Ls[row * 33 + c4 * 4 + 1] = v.y;
    Ls[row * 33 + c4 * 4 + 2] = v.z;
    Ls[row * 33 + c4 * 4 + 3] = v.w;
  }
  __syncthreads();
#pragma unroll
  for (int q = 0; q < 8; ++q) {
    int i = tid + q * 256;
    int ks = i >> 6, l = i & 63;
    int col = l & 31, kb = (l >> 5) * 8 + ks * 16;
    u32x4 o;
    o.x = (unsigned)f2bf(Ls[(kb + 0) * 33 + col]) | ((unsigned)f2bf(Ls[(kb + 1) * 33 + col]) << 16);
    o.y = (unsigned)f2bf(Ls[(kb + 2) * 33 + col]) | ((unsigned)f2bf(Ls[(kb + 3) * 33 + col]) << 16);
    o.z = (unsigned)f2bf(Ls[(kb + 4) * 33 + col]) | ((unsigned)f2bf(Ls[(kb + 5) * 33 + col]) << 16);
    o.w = (unsigned)f2bf(Ls[(kb + 6) * 33 + col]) | ((unsigned)f2bf(Ls[(kb + 7) * 33 + col]) << 16);
    *(u32x4*)(d + (size_t)ks * 512 + l * 8) = o;
  }
}

// ---------------------------------------------------------------------------
// K2 v5: bf16x3 MFMA phi+amp GEMM. Block = (128 tokens, 128 cols), 256 thr /
// 4 waves. Wave w = token-frag tb = blk*4+w; per ks: stage W hi/lo (dbuf LDS,
// wave w stages nb=w), 12 MFMA (4 nb x {HH, LH, HL}). Output rows = tokens
// (k_head-validated layout) -> coalesced epilogue stores.
// ---------------------------------------------------------------------------
__global__ __launch_bounds__(256, 3) void k_phi(
    const unsigned short* __restrict__ XhiP, const unsigned short* __restrict__ XloP,
    const float* __restrict__ phiW, const float* __restrict__ phiB,
    const float* __restrict__ ampW, const float* __restrict__ ampB,
    float* __restrict__ cosO, float* __restrict__ sinO, float* __restrict__ sigO) {
  __shared__ __align__(16) char wlds[2][8][1024];  // [buf][nb*2+hi/lo][64 lanes x 16B]
  int tid = threadIdx.x;
  int w = tid >> 6, l = tid & 63;
  int l31 = l & 31, hi = l >> 5;
  int by = blockIdx.y;
  const float* Bsrc = (by < 4) ? phiW : ampW;
  const float* bias = (by < 4) ? phiB : ampB;
  int cb = (by & 3) * 128;

#define STAGE_W(KS, BUF)                                                        \
  {                                                                             \
    const float* wsrc = Bsrc + (size_t)((KS)*16 + hi * 8) * 512 + cb + w * 32 + l31; \
    float v0 = wsrc[0],    v1 = wsrc[512],  v2 = wsrc[1024], v3 = wsrc[1536];   \
    float v4 = wsrc[2048], v5 = wsrc[2560], v6 = wsrc[3072], v7 = wsrc[3584];   \
    unsigned h0 = f2bf(v0), h1 = f2bf(v1), h2 = f2bf(v2), h3 = f2bf(v3);        \
    unsigned h4 = f2bf(v4), h5 = f2bf(v5), h6 = f2bf(v6), h7 = f2bf(v7);        \
    u32x4 H, L;                                                                 \
    H.x = h0 | (h1 << 16); H.y = h2 | (h3 << 16);                               \
    H.z = h4 | (h5 << 16); H.w = h6 | (h7 << 16);                               \
    L.x = (unsigned)f2bf(v0 - bflo(h0)) | ((unsigned)f2bf(v1 - bflo(h1)) << 16); \
    L.y = (unsigned)f2bf(v2 - bflo(h2)) | ((unsigned)f2bf(v3 - bflo(h3)) << 16); \
    L.z = (unsigned)f2bf(v4 - bflo(h4)) | ((unsigned)f2bf(v5 - bflo(h5)) << 16); \
    L.w = (unsigned)f2bf(v6 - bflo(h6)) | ((unsigned)f2bf(v7 - bflo(h7)) << 16); \
    *(u32x4*)(&wlds[BUF][w * 2 + 0][l * 16]) = H;                               \
    *(u32x4*)(&wlds[BUF][w * 2 + 1][l * 16]) = L;                               \
  }

  int tb = blockIdx.x * 4 + w;
  const unsigned short* xh_base = XhiP + ((size_t)tb * 32) * 512 + l * 8;
  const unsigned short* xl_base = XloP + ((size_t)tb * 32) * 512 + l * 8;
  f32x16 a0, a1, a2, a3;
#pragma unroll
  for (int i = 0; i < 16; ++i) { a0[i] = 0.f; a1[i] = 0.f; a2[i] = 0.f; a3[i] = 0.f; }

  STAGE_W(0, 0);
  for (int ks = 0; ks < 32; ++ks) {
    __syncthreads();
    if (ks + 1 < 32) {
      if (((ks + 1) & 1) == 0) STAGE_W(ks + 1, 0) else STAGE_W(ks + 1, 1)
    }
    bf16x8 xh = *(const bf16x8*)(xh_base + (size_t)ks * 512);
    bf16x8 xl = *(const bf16x8*)(xl_base + (size_t)ks * 512);
    const char (*wb)[1024] = wlds[ks & 1];
    bf16x8 wh0 = ld_frag(&wb[0][l * 16]), wl0 = ld_frag(&wb[1][l * 16]);
    bf16x8 wh1 = ld_frag(&wb[2][l * 16]), wl1 = ld_frag(&wb[3][l * 16]);
    bf16x8 wh2 = ld_frag(&wb[4][l * 16]), wl2 = ld_frag(&wb[5][l * 16]);
    bf16x8 wh3 = ld_frag(&wb[6][l * 16]), wl3 = ld_frag(&wb[7][l * 16]);
    a0 = __builtin_amdgcn_mfma_f32_32x32x16_bf16(xh, wh0, a0, 0, 0, 0);
    a1 = __builtin_amdgcn_mfma_f32_32x32x16_bf16(xh, wh1, a1, 0, 0, 0);
    a2 = __builtin_amdgcn_mfma_f32_32x32x16_bf16(xh, wh2, a2, 0, 0, 0);
    a3 = __builtin_amdgcn_mfma_f32_32x32x16_bf16(xh, wh3, a3, 0, 0, 0);
    a0 = __builtin_amdgcn_mfma_f32_32x32x16_bf16(xl, wh0, a0, 0, 0, 0);
    a1 = __builtin_amdgcn_mfma_f32_32x32x16_bf16(xl, wh1, a1, 0, 0, 0);
    a2 = __builtin_amdgcn_mfma_f32_32x32x16_bf16(xl, wh2, a2, 0, 0, 0);
    a3 = __builtin_amdgcn_mfma_f32_32x32x16_bf16(xl, wh3, a3, 0, 0, 0);
    a0 = __builtin_amdgcn_mfma_f32_32x32x16_bf16(xh, wl0, a0, 0, 0, 0);
    a1 = __builtin_amdgcn_mfma_f32_32x32x16_bf16(xh, wl1, a1, 0, 0, 0);
    a2 = __builtin_amdgcn_mfma_f32_32x32x16_bf16(xh, wl2, a2, 0, 0, 0);
    a3 = __builtin_amdgcn_mfma_f32_32x32x16_bf16(xh, wl3, a3, 0, 0, 0);
  }

  int tokBase = blockIdx.x * 128 + w * 32;
#define PHI_EPI(ACC, NB)                                                        \
  {                                                                             \
    int c = cb + (NB)*32 + l31;                                                 \
    float bs = bias[c];                                                         \
    if (by < 4) {                                                               \
      _Pragma("unroll") for (int r = 0; r < 16; ++r) {                          \
        int tok = tokBase + (r & 3) + 8 * (r >> 2) + 4 * hi;                    \
        float z = ACC[r] + bs;                                                  \
        float a = tanh_fast(z) * PI_F;                                          \
        float nr = rintf(a * INV_HARM_F) * HARM_F;                              \
        if (fabsf(a - nr) < TOL_F) a = nr;                                      \
        float sn, cs;                                                           \
        sincos_poly(a, &sn, &cs);                                               \
        cosO[(size_t)tok * 512 + c] = cs;                                       \
        sinO[(size_t)tok * 512 + c] = sn;                                       \
      }                                                                         \
    } else {                                                                    \
      _Pragma("unroll") for (int r = 0; r < 16; ++r) {                          \
        int tok = tokBase + (r & 3) + 8 * (r >> 2) + 4 * hi;                    \
        sigO[(size_t)tok * 512 + c] = sigmoid_fast(ACC[r] + bs);                \
      }                                                                         \
    }                                                                           \
  }
  PHI_EPI(a0, 0)
  PHI_EPI(a1, 1)
  PHI_EPI(a2, 2)
  PHI_EPI(a3, 3)
}

// ---------------------------------------------------------------------------
// K3 v3: producer-consumer toroidal scan (unchanged from round 11)
// ---------------------------------------------------------------------------
__global__ __launch_bounds__(256, 1) void k_scan(const float* __restrict__ cosb,
                                                 const float* __restrict__ sinb,
                                                 const float* __restrict__ sigb,
                                                 float* __restrict__ xmoe,
                                                 float* __restrict__ nstate) {
  __shared__ float lds[2][3][64 * 64];
  int tid = threadIdx.x;
  int wv = tid >> 6, l = tid & 63;
  int b = blockIdx.x >> 3;
  int c0 = (blockIdx.x & 7) << 6;
  size_t base = ((size_t)b * 2048) * 512 + c0;

#define SCAN_STAGE(SRC, K, BUF)                                                \
  {                                                                            \
    float4 tmp[16];                                                            \
    size_t sb = base + ((size_t)(K) * 64 + tq) * 512 + cq * 4;                 \
    _Pragma("unroll") for (int t4 = 0; t4 < 16; ++t4)                          \
      tmp[t4] = *(const float4*)((SRC) + sb + (size_t)t4 * 4 * 512);           \
    _Pragma("unroll") for (int t4 = 0; t4 < 16; ++t4)                          \
      *(float4*)(&lds[BUF][wv - 1][(t4 * 4 + tq) * 64 + cq * 4]) = tmp[t4];    \
  }

  if (wv > 0) {
    const float* src = (wv == 1) ? cosb : (wv == 2) ? sinb : sigb;
    int tq = l >> 4, cq = l & 15;
    SCAN_STAGE(src, 0, 0);
    __syncthreads();
    for (int k = 0; k < 32; ++k) {
      if (k + 1 < 32) {
        if (((k + 1) & 1) == 0) SCAN_STAGE(src, k + 1, 0)
        else                    SCAN_STAGE(src, k + 1, 1)
      }
      __syncthreads();
    }
  } else {
    __syncthreads();
    float state = 0.f;
    for (int k = 0; k < 32; ++k) {
      const float* bufC = &lds[k & 1][0][0];
      const float* bufS = &lds[k & 1][1][0];
      const float* bufG = &lds[k & 1][2][0];
      size_t outb = base + (size_t)k * 64 * 512 + l;
#pragma unroll
      for (int tt = 0; tt < 64; ++tt) {
        float pc = bufC[tt * 64 + l];
        float ps = bufS[tt * 64 + l];
        float pg = bufG[tt * 64 + l];
        float st = fmaf(pc + ps, state, -ps);
        st = fminf(1.f, fmaxf(-1.f, st));
        state = st;
        xmoe[outb + (size_t)tt * 512] = pg * st;
      }
      __syncthreads();
    }
    nstate[(size_t)b * 512 + c0 + l] = state;
  }
}

// K4: gate logits + softmax + top2 (unchanged)
__global__ __launch_bounds__(256) void k_gate(const float* __restrict__ xmoe,
                                              const float* __restrict__ gw_g,
                                              const float* __restrict__ gb,
                                              int* __restrict__ e01p,
                                              unsigned* __restrict__ w01p) {
  __shared__ float gw[4096];
  int tid = threadIdx.x;
  for (int i = tid; i < 4096; i += 256) gw[i] = gw_g[i];
  __syncthreads();
  int tok = blockIdx.x * 32 + (tid >> 3);
  int e = tid & 7;
  float acc = gb[e];
  const float4* xr = (const float4*)(xmoe + (size_t)tok * 512);
  for (int k4 = 0; k4 < 128; ++k4) {
    float4 x = xr[k4];
    acc += x.x * gw[(k4 * 4 + 0) * 8 + e];
    acc += x.y * gw[(k4 * 4 + 1) * 8 + e];
    acc += x.z * gw[(k4 * 4 + 2) * 8 + e];
    acc += x.w * gw[(k4 * 4 + 3) * 8 + e];
  }
  float m = acc;
  m = fmaxf(m, __shfl_xor(m, 1));
  m = fmaxf(m, __shfl_xor(m, 2));
  m = fmaxf(m, __shfl_xor(m, 4));
  float p = expf(acc - m);
  float ss = p;
  ss += __shfl_xor(ss, 1); ss += __shfl_xor(ss, 2); ss += __shfl_xor(ss, 4);
  p /= ss;
  float v1 = p; int i1 = e;
  {
    float ov; int oi;
    ov = __shfl_xor(v1, 1); oi = __shfl_xor(i1, 1);
    if (ov > v1 || (ov == v1 && oi < i1)) { v1 = ov; i1 = oi; }
    ov = __shfl_xor(v1, 2); oi = __shfl_xor(i1, 2);
    if (ov > v1 || (ov == v1 && oi < i1)) { v1 = ov; i1 = oi; }
    ov = __shfl_xor(v1, 4); oi = __shfl_xor(i1, 4);
    if (ov > v1 || (ov == v1 && oi < i1)) { v1 = ov; i1 = oi; }
  }
  float v2 = (e == i1) ? -1.f : p; int i2 = e;
  {
    float ov; int oi;
    ov = __shfl_xor(v2, 1); oi = __shfl_xor(i2, 1);
    if (ov > v2 || (ov == v2 && oi < i2)) { v2 = ov; i2 = oi; }
    ov = __shfl_xor(v2, 2); oi = __shfl_xor(i2, 2);
    if (ov > v2 || (ov == v2 && oi < i2)) { v2 = ov; i2 = oi; }
    ov = __shfl_xor(v2, 4); oi = __shfl_xor(i2, 4);
    if (ov > v2 || (ov == v2 && oi < i2)) { v2 = ov; i2 = oi; }
  }
  if (e == 0) {
    float s2 = v1 + v2;
    __half h1 = __float2half(v1 / s2), h2 = __float2half(v2 / s2);
    e01p[tok] = i1 | (i2 << 8);
    w01p[tok] = (unsigned)__half_as_ushort(h1) | ((unsigned)__half_as_ushort(h2) << 16);
  }
}

// K6: counts -> eoff -> scatter -> tmap (unchanged, 96-tok tiles)
__global__ void k_build(const int* __restrict__ e01p, const unsigned* __restrict__ w01p,
                        int* __restrict__ list, float* __restrict__ wlist,
                        int* __restrict__ counts, int* __restrict__ eoff,
                        int* __restrict__ tokpos, int* __restrict__ tmap) {
  __shared__ int cnt[8], cur[8];
  int tid = threadIdx.x, lane = tid & 63;
  if (tid < 8) cnt[tid] = 0;
  __syncthreads();
  for (int i = tid; i < 16384; i += 256) {
    int tok = i >> 1, j = i & 1;
    int ee = (e01p[tok] >> (8 * j)) & 255;
#pragma unroll
    for (int x = 0; x < 8; ++x) {
      unsigned long long m = __ballot(ee == x);
      if (m != 0ull && lane == (__ffsll((long long)m) - 1)) atomicAdd(&cnt[x], __popcll(m));
    }
  }
  __syncthreads();
  if (tid == 0) {
    int s = 0;
#pragma unroll
    for (int x = 0; x < 8; ++x) {
      cur[x] = s; eoff[x] = s; counts[x] = cnt[x]; s += cnt[x];
    }
  }
  __syncthreads();
  for (int i = tid; i < 272; i += 256) tmap[i] = -1;
  __syncthreads();
  if (tid == 0) {
    int ntiles = 0, tstart[8];
#pragma unroll
    for (int e = 0; e < 8; ++e) { tstart[e] = ntiles; ntiles += (cnt[e] + 95) / 96; }
    int q = ntiles >> 3, r = ntiles & 7;
    for (int e = 0; e < 8; ++e) {
      int nt = (cnt[e] + 95) / 96;
      for (int t = 0; t < nt; ++t) {
        int k = tstart[e] + t;
        int c, o;
        if (k < r * (q + 1)) { c = k / (q + 1); o = k - c * (q + 1); }
        else { int k2 = k - r * (q + 1); c = r + k2 / q; o = k2 - (k2 / q) * q; }
        tmap[8 * o + c] = (e << 16) | t;
      }
    }
  }
  __syncthreads();
  for (int i = tid; i < 16384; i += 256) {
    int tok = i >> 1, j = i & 1;
    int ee = (e01p[tok] >> (8 * j)) & 255;
    unsigned wp = w01p[tok];
    unsigned short us = (unsigned short)(j ? (wp >> 16) : (wp & 0xFFFFu));
    float w = __half2float(__ushort_as_half(us));
    int pos = 0;
#pragma unroll
    for (int x = 0; x < 8; ++x) {
      unsigned long long m = __ballot(ee == x);
      if (m == 0ull) continue;
      int leader = __ffsll((long long)m) - 1;
      int bb = 0;
      if (lane == leader) bb = atomicAdd(&cur[x], __popcll(m));
      bb = __shfl(bb, leader);
      if (ee == x) pos = bb + __popcll(m & ((1ull << lane) - 1ull));
    }
    list[pos] = tok;
    wlist[pos] = w;
    tokpos[i] = pos;
  }
}

// ---------------------------------------------------------------------------
// K7 v4: fused MoE FFN, 96-token tiles (unchanged from round 11)
// ---------------------------------------------------------------------------
#define HS_OFF 98304

__global__ __launch_bounds__(512, 2) void k_ffn(
    const float* __restrict__ xmoe, const int* __restrict__ list,
    const float* __restrict__ wlist, const int* __restrict__ counts,
    const int* __restrict__ eoff, const int* __restrict__ tmap,
    const unsigned short* __restrict__ W1Pk, const float* __restrict__ b1g,
    const unsigned short* __restrict__ W2Pk, const float* __restrict__ b2g,
    unsigned short* __restrict__ Yb) {
  int mp = tmap[blockIdx.x];
  if (mp < 0) return;
  int e = mp >> 16, tile = mp & 0xFFFF;
  int cnt = counts[e];
  int base = eoff[e] + tile * 96;
  int valid = cnt - tile * 96;
  if (valid > 96) valid = 96;
  __shared__ __align__(16) char smem[147456];  // Xs 96KB | Hs 48KB
  __shared__ int toks[96];
  __shared__ float wts[96];
  int tid = threadIdx.x;
  int w = tid >> 6, l = tid & 63;
  int l31 = l & 31, hi = l >> 5;
  if (tid < 96) {
    int idx = tile * 96 + tid;
    bool v = idx < cnt;
    toks[tid] = list[eoff[e] + (v ? idx : 0)];
    wts[tid] = v ? wlist[eoff[e] + idx] : 0.f;
  }
  __syncthreads();
#pragma unroll
  for (int s = 0; s < 12; ++s) {
    int sl = s * 512 + tid;
    int ent = sl >> 6, ll = sl & 63;
    int ks = ent / 3, t3 = ent - ks * 3;
    int tok = toks[t3 * 32 + (ll & 31)];
    const float* src = xmoe + (size_t)tok * 512 + ks * 16 + (ll >> 5) * 8;
    float4 v0 = *(const float4*)src;
    float4 v1 = *(const float4*)(src + 4);
    u32x4 u;
    u.x = (unsigned)f2bf(v0.x) | ((unsigned)f2bf(v0.y) << 16);
    u.y = (unsigned)f2bf(v0.z) | ((unsigned)f2bf(v0.w) << 16);
    u.z = (unsigned)f2bf(v1.x) | ((unsigned)f2bf(v1.y) << 16);
    u.w = (unsigned)f2bf(v1.z) | ((unsigned)f2bf(v1.w) << 16);
    *(u32x4*)(smem + ent * 1024 + ll * 16) = u;
  }
  f32x16 acc00, acc01, acc02, acc10, acc11, acc12;
#pragma unroll
  for (int i = 0; i < 16; ++i) {
    acc00[i] = 0.f; acc01[i] = 0.f; acc02[i] = 0.f;
    acc10[i] = 0.f; acc11[i] = 0.f; acc12[i] = 0.f;
  }
  __syncthreads();

  const size_t dstE1 = (size_t)64 * 32 * 512;
  const size_t dstE2 = (size_t)16 * 128 * 512;
  for (int it = 0; it < 8; ++it) {
    f32x16 z0, z1, z2;
#pragma unroll
    for (int i = 0; i < 16; ++i) { z0[i] = 0.f; z1[i] = 0.f; z2[i] = 0.f; }
    const unsigned short* w1p =
        W1Pk + (size_t)e * dstE1 + ((size_t)(it * 8 + w) * 32) * 512 + l * 8;
#pragma unroll 8
    for (int ks = 0; ks < 32; ++ks) {
      bf16x8 a = *(const bf16x8*)(w1p + (size_t)ks * 512);
      bf16x8 b0 = ld_frag(smem + (ks * 3 + 0) * 1024 + l * 16);
      bf16x8 b1 = ld_frag(smem + (ks * 3 + 1) * 1024 + l * 16);
      bf16x8 b2 = ld_frag(smem + (ks * 3 + 2) * 1024 + l * 16);
      z0 = __builtin_amdgcn_mfma_f32_32x32x16_bf16(a, b0, z0, 0, 0, 0);
      z1 = __builtin_amdgcn_mfma_f32_32x32x16_bf16(a, b1, z1, 0, 0, 0);
      z2 = __builtin_amdgcn_mfma_f32_32x32x16_bf16(a, b2, z2, 0, 0, 0);
    }
#define GELU_STORE(Z, T3)                                                       \
  {                                                                             \
    _Pragma("unroll") for (int rq = 0; rq < 4; ++rq) {                          \
      int fb = w * 32 + 8 * rq + 4 * hi;                                        \
      float4 bv = *(const float4*)(b1g + e * 2048 + it * 256 + fb);             \
      float g0 = gelu_tanh(Z[4 * rq + 0] + bv.x);                               \
      float g1 = gelu_tanh(Z[4 * rq + 1] + bv.y);                               \
      float g2 = gelu_tanh(Z[4 * rq + 2] + bv.z);                               \
      float g3 = gelu_tanh(Z[4 * rq + 3] + bv.w);                               \
      u32x2 p;                                                                  \
      p.x = (unsigned)f2bf(g0) | ((unsigned)f2bf(g1) << 16);                    \
      p.y = (unsigned)f2bf(g2) | ((unsigned)f2bf(g3) << 16);                    \
      int ent = (w * 2 + (rq >> 1)) * 3 + (T3);                                 \
      int lanep = l31 + 32 * (rq & 1);                                          \
      *(u32x2*)(smem + HS_OFF + ent * 1024 + lanep * 16 + hi * 8) = p;          \
    }                                                                           \
  }
    GELU_STORE(z0, 0)
    GELU_STORE(z1, 1)
    GELU_STORE(z2, 2)
    __syncthreads();
    const unsigned short* w2a =
        W2Pk + (size_t)e * dstE2 + ((size_t)(w * 2) * 128 + it * 16) * 512 + l * 8;
    const unsigned short* w2b = w2a + (size_t)128 * 512;
#pragma unroll 8
    for (int fs = 0; fs < 16; ++fs) {
      bf16x8 a0 = *(const bf16x8*)(w2a + (size_t)fs * 512);
      bf16x8 a1 = *(const bf16x8*)(w2b + (size_t)fs * 512);
      bf16x8 h0 = ld_frag(smem + HS_OFF + (fs * 3 + 0) * 1024 + l * 16);
      bf16x8 h1 = ld_frag(smem + HS_OFF + (fs * 3 + 1) * 1024 + l * 16);
      bf16x8 h2 = ld_frag(smem + HS_OFF + (fs * 3 + 2) * 1024 + l * 16);
      acc00 = __builtin_amdgcn_mfma_f32_32x32x16_bf16(a0, h0, acc00, 0, 0, 0);
      acc01 = __builtin_amdgcn_mfma_f32_32x32x16_bf16(a0, h1, acc01, 0, 0, 0);
      acc02 = __builtin_amdgcn_mfma_f32_32x32x16_bf16(a0, h2, acc02, 0, 0, 0);
      acc10 = __builtin_amdgcn_mfma_f32_32x32x16_bf16(a1, h0, acc10, 0, 0, 0);
      acc11 = __builtin_amdgcn_mfma_f32_32x32x16_bf16(a1, h1, acc11, 0, 0, 0);
      acc12 = __builtin_amdgcn_mfma_f32_32x32x16_bf16(a1, h2, acc12, 0, 0, 0);
    }
    __syncthreads();
  }
#define EPI_STORE(ACC, JC, T3)                                                  \
  {                                                                             \
    _Pragma("unroll") for (int rq = 0; rq < 4; ++rq) {                          \
      int c0 = (w * 2 + (JC)) * 32 + 8 * rq + 4 * hi;                           \
      float4 b2v = *(const float4*)(b2g + e * 512 + c0);                        \
      int tok = (T3)*32 + l31;                                                  \
      float wt = wts[tok];                                                      \
      u32x2 p;                                                                  \
      p.x = (unsigned)f2bf((ACC[4 * rq + 0] + b2v.x) * wt) |                    \
            ((unsigned)f2bf((ACC[4 * rq + 1] + b2v.y) * wt) << 16);             \
      p.y = (unsigned)f2bf((ACC[4 * rq + 2] + b2v.z) * wt) |                    \
            ((unsigned)f2bf((ACC[4 * rq + 3] + b2v.w) * wt) << 16);             \
      *(u32x2*)(smem + tok * 1024 + ((c0 * 2) ^ ((tok & 7) << 4))) = p;         \
    }                                                                           \
  }
  EPI_STORE(acc00, 0, 0)
  EPI_STORE(acc01, 0, 1)
  EPI_STORE(acc02, 0, 2)
  EPI_STORE(acc10, 1, 0)
  EPI_STORE(acc11, 1, 1)
  EPI_STORE(acc12, 1, 2)
  __syncthreads();
#pragma unroll
  for (int s = 0; s < 12; ++s) {
    int i = tid + s * 512;
    int row = i >> 6, g = i & 63;
    if (row < valid) {
      u32x4 v = *(u32x4*)(smem + row * 1024 + ((g * 16) ^ ((row & 7) << 4)));
      *(u32x4*)(Yb + (size_t)(base + row) * 512 + g * 8) = v;
    }
  }
}

// ---------------------------------------------------------------------------
// K8: head bf16 MFMA GEMM (unchanged)
// ---------------------------------------------------------------------------
__global__ __launch_bounds__(256) void k_head(const unsigned short* __restrict__ Yb,
                                              const int* __restrict__ tokpos,
                                              const unsigned short* __restrict__ headPk,
                                              const float* __restrict__ headB,
                                              float* __restrict__ out) {
  __shared__ __align__(16) char As[16384];
  __shared__ int tp[256];
  int tid = threadIdx.x;
  int w = tid >> 6, l = tid & 63;
  int l31 = l & 31, hi = l >> 5;
  int mg = w & 1, ng = w >> 1;
  int bm = blockIdx.x * 128, by = blockIdx.y;
  tp[tid] = tokpos[bm * 2 + tid];
  f32x16 acc00, acc01, acc10, acc11;
#pragma unroll
  for (int i = 0; i < 16; ++i) { acc00[i] = 0.f; acc01[i] = 0.f; acc10[i] = 0.f; acc11[i] = 0.f; }
  int nblk0 = by * 4 + ng * 2;
  __syncthreads();
  for (int kb = 0; kb < 8; ++kb) {
#pragma unroll
    for (int s = 0; s < 4; ++s) {
      int i = tid + s * 256;
      int row = i >> 3, g = i & 7;
      int p1 = tp[row * 2], p2 = tp[row * 2 + 1];
      u32x4 va = *(const u32x4*)(Yb + (size_t)p1 * 512 + kb * 64 + g * 8);
      u32x4 vb = *(const u32x4*)(Yb + (size_t)p2 * 512 + kb * 64 + g * 8);
      u32x4 o;
      o.x = (unsigned)f2bf(bflo(va.x) + bflo(vb.x)) | ((unsigned)f2bf(bfhi(va.x) + bfhi(vb.x)) << 16);
      o.y = (unsigned)f2bf(bflo(va.y) + bflo(vb.y)) | ((unsigned)f2bf(bfhi(va.y) + bfhi(vb.y)) << 16);
      o.z = (unsigned)f2bf(bflo(va.z) + bflo(vb.z)) | ((unsigned)f2bf(bfhi(va.z) + bfhi(vb.z)) << 16);
      o.w = (unsigned)f2bf(bflo(va.w) + bflo(vb.w)) | ((unsigned)f2bf(bfhi(va.w) + bfhi(vb.w)) << 16);
      *(u32x4*)(As + row * 128 + ((g * 16) ^ ((row & 7) << 4))) = o;
    }
    __syncthreads();
#pragma unroll
    for (int ks = 0; ks < 4; ++ks) {
      int r0 = mg * 64 + l31, r1 = r0 + 32;
      int kbyte = ks * 32 + hi * 16;
      bf16x8 a0 = ld_frag(As + r0 * 128 + (kbyte ^ ((r0 & 7) << 4)));
      bf16x8 a1 = ld_frag(As + r1 * 128 + (kbyte ^ ((r1 & 7) << 4)));
      const unsigned short* hp = headPk + ((size_t)nblk0 * 32 + kb * 4 + ks) * 512 + l * 8;
      bf16x8 b0 = *(const bf16x8*)hp;
      bf16x8 b1 = *(const bf16x8*)(hp + 32 * 512);
      acc00 = __builtin_amdgcn_mfma_f32_32x32x16_bf16(a0, b0, acc00, 0, 0, 0);
      acc01 = __builtin_amdgcn_mfma_f32_32x32x16_bf16(a0, b1, acc01, 0, 0, 0);
      acc10 = __builtin_amdgcn_mfma_f32_32x32x16_bf16(a1, b0, acc10, 0, 0, 0);
      acc11 = __builtin_amdgcn_mfma_f32_32x32x16_bf16(a1, b1, acc11, 0, 0, 0);
    }
    __syncthreads();
  }
#pragma unroll
  for (int mf = 0; mf < 2; ++mf) {
#pragma unroll
    for (int nf = 0; nf < 2; ++nf) {
      int nc = by * 128 + ng * 64 + nf * 32 + l31;
      float hb = headB[nc];
#pragma unroll
      for (int r = 0; r < 16; ++r) {
        int m = bm + mg * 64 + mf * 32 + (r & 3) + 8 * (r >> 2) + 4 * hi;
        float v;
        if (mf == 0) v = (nf == 0) ? acc00[r] : acc01[r];
        else         v = (nf == 0) ? acc10[r] : acc11[r];
        out[(size_t)m * 256 + nc] = v + hb;
      }
    }
  }
}

extern "C" void kernel_launch(void* const* d_in, const int* in_sizes, int n_in,
                              void* d_out, int out_size, void* d_ws, size_t ws_size,
                              hipStream_t stream) {
  (void)in_sizes; (void)n_in; (void)out_size; (void)ws_size;
  const int* seq     = (const int*)d_in[0];
  const float* emb   = (const float*)d_in[1];
  const float* phi_w = (const float*)d_in[2];
  const float* phi_b = (const float*)d_in[3];
  const float* amp_w = (const float*)d_in[4];
  const float* amp_b = (const float*)d_in[5];
  const float* gate_w = (const float*)d_in[6];
  const float* gate_b = (const float*)d_in[7];
  const float* w1 = (const float*)d_in[8];
  const float* b1 = (const float*)d_in[9];
  const float* w2 = (const float*)d_in[10];
  const float* b2 = (const float*)d_in[11];
  const float* head_w = (const float*)d_in[12];
  const float* head_b = (const float*)d_in[13];
  float* out = (float*)d_out;

  char* ws = (char*)d_ws;
  const size_t BUF = 16777216;
  float* X    = (float*)(ws);                         // Xhi|Xlo -> xmoe (in place)
  float* COSb = (float*)(ws + BUF);                   // cos -> Yb (bf16)
  float* SINb = (float*)(ws + 2 * BUF);               // sin -> W1Pk (bf16)
  float* SIGb = (float*)(ws + 3 * BUF);               // sig -> W2Pk (bf16)
  unsigned short* XhiP = (unsigned short*)X;          // 8MB
  unsigned short* XloP = XhiP + (size_t)8192 * 512;   // 8MB
  unsigned short* Yb   = (unsigned short*)COSb;
  unsigned short* W1Pk = (unsigned short*)SINb;
  unsigned short* W2Pk = (unsigned short*)SIGb;
  char* sm = ws + 4 * BUF;
  int*      e01p   = (int*)(sm);                      // 32KB
  unsigned* w01p   = (unsigned*)(sm + 32768);         // 32KB
  int*      list   = (int*)(sm + 65536);              // 64KB
  float*    wlist  = (float*)(sm + 131072);           // 64KB
  int*      tokpos = (int*)(sm + 196608);             // 64KB
  int*      counts = (int*)(sm + 262144);
  int*      eoff   = (int*)(sm + 262144 + 64);
  unsigned short* headPk = (unsigned short*)(sm + 266240);  // 256KB
  int*      tmap   = (int*)(sm + 266240 + 262144);          // 272 ints

  k_embed2<<<2048, 256, 0, stream>>>(seq, emb, XhiP, XloP);
  k_pack_b<<<dim3(8, 1, 1), 256, 0, stream>>>(head_w, 256, 0, headPk, 0, 32);
  k_phi<<<dim3(64, 8), 256, 0, stream>>>(XhiP, XloP, phi_w, phi_b, amp_w, amp_b,
                                         COSb, SINb, SIGb);
  k_scan<<<32, 256, 0, stream>>>(COSb, SINb, SIGb, X, out + 2097152);
  k_pack_b<<<dim3(64, 1, 8), 256, 0, stream>>>(w1, 2048, (size_t)512 * 2048, W1Pk,
                                               (size_t)64 * 32 * 512, 32);
  k_pack_b<<<dim3(16, 4, 8), 256, 0, stream>>>(w2, 512, (size_t)2048 * 512, W2Pk,
                                               (size_t)16 * 128 * 512, 128);
  k_gate<<<256, 256, 0, stream>>>(X, gate_w, gate_b, e01p, w01p);
  k_build<<<1, 256, 0, stream>>>(e01p, w01p, list, wlist, counts, eoff, tokpos, tmap);
  k_ffn<<<192, 512, 0, stream>>>(X, list, wlist, counts, eoff, tmap,
                                 W1Pk, b1, W2Pk, b2, Yb);
  k_head<<<dim3(64, 2), 256, 0, stream>>>(Yb, tokpos, headPk, head_b, out);
}